// Round 3
// baseline (2355.363 us; speedup 1.0000x reference)
//
#include <hip/hip_runtime.h>
#include <hip/hip_bf16.h>
#include <math.h>

// ---------------------------------------------------------------------------
// Linear_Transformer on MI355X (gfx950). fp32 I/O (per reference dtypes),
// bf16 MFMA internals, fp32 residual stream.
// Round 3: round 2 read fp32 inputs as bf16 -> garbage -> exp overflow -> NaN.
// All inputs are now const float*, output float*. Weights quantized to bf16
// in the transpose kernel; activations quantized at GEMM staging; residual h
// and all accumulation fp32.
// ---------------------------------------------------------------------------

typedef __hip_bfloat16 bf16;
typedef __attribute__((ext_vector_type(8))) short short8;   // 8 bf16 (MFMA A/B frag)
typedef __attribute__((ext_vector_type(4))) float floatx4;  // MFMA C/D frag

#define SEQ   4096
#define NBAT  8
#define DM    512
#define DINP  128
#define DFF   2048
#define NREAL 3000
#define GROUPROWS 8192        // 2 batches per group
#define NGROUP 4

#define MFMA16(a,b,c) __builtin_amdgcn_mfma_f32_16x16x32_bf16((a),(b),(c),0,0,0)

// ---------------- workspace arena (bytes), total 125,245,440 ----------------
#define OFF_H     0L            // h fp32 [32768][512]            67,108,864
#define OFF_LNG   67108864L     // LN out bf16 [8192][512]         8,388,608
#define OFF_Q     75497472L     // q bf16 [8192][512]; ff1g overlays Q..ATT
#define OFF_K     83886080L
#define OFF_V     92274688L
#define OFF_ATT   100663296L
#define OFF_QP    109051904L    // qp bf16 [6][4096][128]          6,291,456
#define OFF_CTXP  115343360L    // ctx partials f32 [6][8][16384]  3,145,728
#define OFF_CTXT  118489088L    // ctxT bf16 [6][16384]              196,608
#define OFF_KML   118685696L    // k col stats f32 [6][256]            6,144
#define OFF_WT    118691840L    // transposed bf16 weights         6,553,600
#define WT_W1     0L
#define WT_WQ     131072L
#define WT_WK     655360L
#define WT_WV     1179648L
#define WT_WO     1703936L
#define WT_WF1    2228224L
#define WT_WF2    4325376L
#define WT_W2     6422528L
#define WS_NEED   125245440L

// ---------------------------------------------------------------------------
__global__ __launch_bounds__(256) void beacon(float* __restrict__ out, long n) {
  long i = (long)blockIdx.x * 256 + threadIdx.x;
  if (i < n) out[i] = 10000.f;
}

// ---------------------------------------------------------------------------
// Weight transpose fp32 -> bf16, zero-pad N: Wt[n][k] = n<N ? (bf16)W[k][n] : 0
// ---------------------------------------------------------------------------
__global__ __launch_bounds__(256) void transpose_pad(const float* __restrict__ W,
                                                     bf16* __restrict__ Wt,
                                                     int K, int N) {
  __shared__ float t[64][65];
  int k0 = blockIdx.x * 64, n0 = blockIdx.y * 64;
  int r = threadIdx.x >> 2, c = (threadIdx.x & 3) * 16;
#pragma unroll
  for (int i = 0; i < 16; i++) {
    int n = n0 + c + i;
    t[r][c + i] = (n < N) ? W[(long)(k0 + r) * N + n] : 0.f;
  }
  __syncthreads();
#pragma unroll
  for (int i = 0; i < 16; i++)
    Wt[(long)(n0 + r) * K + k0 + c + i] = (bf16)t[c + i][r];
}

// ---------------------------------------------------------------------------
// pack 8 consecutive floats into 8 bf16 (uint4)
// ---------------------------------------------------------------------------
__device__ inline uint4 pack8(const float* p) {
  union { bf16 h[8]; uint4 u; } r;
  float4 a = *(const float4*)p;
  float4 b = *(const float4*)(p + 4);
  r.h[0] = (bf16)a.x; r.h[1] = (bf16)a.y; r.h[2] = (bf16)a.z; r.h[3] = (bf16)a.w;
  r.h[4] = (bf16)b.x; r.h[5] = (bf16)b.y; r.h[6] = (bf16)b.z; r.h[7] = (bf16)b.w;
  return r.u;
}

// ---------------------------------------------------------------------------
// Generic MFMA GEMM: C[M x N] = epi(A[M x K] @ Bt[N x K]^T + bias)
// 128x128 tile, BK=32, 256 threads (4 waves, 2x2), z-batched.
// AMODE: 0 bf16 A
//        1 A is fp32 x (8,3000,128), zero rows padded to (8,4096,128)
//        2 A is fp32 (convert in staging)
// EPI:   0 tanh->Cf(f32)  1 bf16->Cb  2 Cf+=  4 gelu->Cb
//        5 row-remap (b,t<3000), c<64 -> Cf (fp32 d_out)
// ---------------------------------------------------------------------------
__global__ __launch_bounds__(256) void gemm_bt(
    const void* __restrict__ Avoid, const bf16* __restrict__ Bt,
    const float* __restrict__ bias, float* __restrict__ Cf, bf16* __restrict__ Cb,
    int K, int lda, int ldb, int ldc, int EPI, int AMODE,
    long aBatch, long bBatch, int zdiv, long cOuter, long cInner) {
  __shared__ __align__(16) bf16 As[128 * 32];
  __shared__ __align__(16) bf16 Bs[128 * 32];
  const int tid = threadIdx.x;
  const int bz = blockIdx.z;
  const bf16* A = (const bf16*)Avoid + (AMODE == 0 ? (long)bz * aBatch : 0);
  const float* Af = (const float*)Avoid;
  Bt += (long)bz * bBatch;
  const long cOff = (long)(bz / zdiv) * cOuter + (long)(bz % zdiv) * cInner;
  const int row0 = blockIdx.y * 128;
  const int col0 = blockIdx.x * 128;
  const int lane = tid & 63, wid = tid >> 6;
  const int wm = (wid & 1) * 64, wn = (wid >> 1) * 64;
  const int lr = lane & 15, lk = (lane >> 4) * 8;

  const int srow = tid >> 2;         // 0..63
  const int skcol = (tid & 3) * 8;   // 0,8,16,24
  const long r0 = row0 + srow, r1 = r0 + 64;
  const bf16* pB = Bt + (long)(col0 + srow) * ldb + skcol;
  const int ldsOff = srow * 32 + skcol;

  const bf16* pA0 = nullptr; const bf16* pA1 = nullptr;
  const float* pF0 = nullptr; const float* pF1 = nullptr;
  bool v0 = true, v1 = true;
  if (AMODE == 0) {
    pA0 = A + r0 * lda + skcol;
    pA1 = A + r1 * lda + skcol;
  } else if (AMODE == 1) {
    int t0 = (int)(r0 & (SEQ - 1)), t1 = (int)(r1 & (SEQ - 1));
    v0 = t0 < NREAL; v1 = t1 < NREAL;
    if (!v0) t0 = 0;
    if (!v1) t1 = 0;
    pF0 = Af + ((r0 >> 12) * NREAL + t0) * DINP + skcol;
    pF1 = Af + ((r1 >> 12) * NREAL + t1) * DINP + skcol;
  } else {
    pF0 = Af + r0 * lda + skcol;
    pF1 = Af + r1 * lda + skcol;
  }

  floatx4 acc[4][4];
#pragma unroll
  for (int i = 0; i < 4; i++)
#pragma unroll
    for (int j = 0; j < 4; j++) acc[i][j] = {0.f, 0.f, 0.f, 0.f};

  for (int k0 = 0; k0 < K; k0 += 32) {
    uint4 b0 = *(const uint4*)(pB);
    uint4 b1 = *(const uint4*)(pB + (long)64 * ldb);
    pB += 32;
    uint4 a0 = {0, 0, 0, 0}, a1 = {0, 0, 0, 0};
    if (AMODE == 0) {
      a0 = *(const uint4*)(pA0);
      a1 = *(const uint4*)(pA1);
      pA0 += 32; pA1 += 32;
    } else {
      if (v0) a0 = pack8(pF0);
      if (v1) a1 = pack8(pF1);
      pF0 += 32; pF1 += 32;
    }
    __syncthreads();
    *(uint4*)(&As[ldsOff]) = a0;
    *(uint4*)(&As[ldsOff + 64 * 32]) = a1;
    *(uint4*)(&Bs[ldsOff]) = b0;
    *(uint4*)(&Bs[ldsOff + 64 * 32]) = b1;
    __syncthreads();
    short8 af[4], bfr[4];
#pragma unroll
    for (int mt = 0; mt < 4; mt++) af[mt] = *(const short8*)(&As[(wm + mt * 16 + lr) * 32 + lk]);
#pragma unroll
    for (int nt = 0; nt < 4; nt++) bfr[nt] = *(const short8*)(&Bs[(wn + nt * 16 + lr) * 32 + lk]);
#pragma unroll
    for (int mt = 0; mt < 4; mt++)
#pragma unroll
      for (int nt = 0; nt < 4; nt++)
        acc[mt][nt] = MFMA16(af[mt], bfr[nt], acc[mt][nt]);
  }

  // D element (mt,nt,reg): row=(lane>>4)*4+reg, col=lane&15 within 16x16 tile
#pragma unroll
  for (int nt = 0; nt < 4; nt++) {
    int c = col0 + wn + nt * 16 + lr;
    float bv = 0.f;
    if (bias) {
      if (EPI == 5) { if (c < 64) bv = bias[c]; }
      else bv = bias[c];
    }
#pragma unroll
    for (int mt = 0; mt < 4; mt++) {
      long rb = row0 + wm + mt * 16 + (lane >> 4) * 4;
#pragma unroll
      for (int reg = 0; reg < 4; reg++) {
        float v = acc[mt][nt][reg] + bv;
        long ri = rb + reg;
        long idx = cOff + ri * (long)ldc + c;
        if (EPI == 0) Cf[idx] = tanhf(v);
        else if (EPI == 1) Cb[idx] = (bf16)v;
        else if (EPI == 2) Cf[idx] += v;
        else if (EPI == 4) { float g = 0.5f * v * (1.f + erff(v * 0.70710678118654752f)); Cb[idx] = (bf16)g; }
        else if (EPI == 5) {
          int bb = (int)(ri >> 12); int tt = (int)(ri & (SEQ - 1));
          if (tt < NREAL && c < 64) Cf[((long)bb * NREAL + tt) * 64 + c] = v;
        }
      }
    }
  }
}

// ---------------------------------------------------------------------------
// LayerNorm over 512 fp32 -> bf16. One wave per row, 4 rows per block.
// ---------------------------------------------------------------------------
__global__ __launch_bounds__(256) void ln_kernel(const float* __restrict__ h,
                                                 const float* __restrict__ g,
                                                 const float* __restrict__ bta,
                                                 bf16* __restrict__ out) {
  int wid = threadIdx.x >> 6, lane = threadIdx.x & 63;
  long row = (long)blockIdx.x * 4 + wid;
  const float* src = h + row * DM + lane * 8;
  float4 a = *(const float4*)(src);
  float4 b = *(const float4*)(src + 4);
  float x[8] = {a.x, a.y, a.z, a.w, b.x, b.y, b.z, b.w};
  float s = 0.f, sq = 0.f;
#pragma unroll
  for (int i = 0; i < 8; i++) { s += x[i]; sq += x[i] * x[i]; }
#pragma unroll
  for (int m = 32; m >= 1; m >>= 1) { s += __shfl_xor(s, m, 64); sq += __shfl_xor(sq, m, 64); }
  float mu = s * (1.f / DM);
  float var = sq * (1.f / DM) - mu * mu;
  float rstd = rsqrtf(var + 1e-5f);
  const float* gp = g + lane * 8;
  const float* bp = bta + lane * 8;
  bf16* dst = out + row * DM + lane * 8;
#pragma unroll
  for (int i = 0; i < 8; i++)
    dst[i] = (bf16)((x[i] - mu) * rstd * gp[i] + bp[i]);
}

// ---------------------------------------------------------------------------
// Local attention, head 0 (channels 0..127). Grid (2 halves, 32 windows,
// 2 local batches), 256 thr. Each wave: 16 query rows. 12 key-chunks of 32
// (windows w-1,w,w+1); OOB chunks skipped (== reference -inf mask).
// ---------------------------------------------------------------------------
__global__ __launch_bounds__(256) void local_attn(const bf16* __restrict__ q,
                                                  const bf16* __restrict__ k,
                                                  const bf16* __restrict__ v,
                                                  bf16* __restrict__ att) {
  int half = blockIdx.x, w = blockIdx.y, b = blockIdx.z;
  int tid = threadIdx.x, wid = tid >> 6, lane = tid & 63;
  int lr = lane & 15, lq4 = lane >> 4;
  __shared__ __align__(16) bf16 Ks[32 * 128];   // [j][d]
  __shared__ __align__(16) bf16 Vts[128 * 32];  // [d][j]
  __shared__ __align__(16) bf16 Ps[4][16 * 32]; // per-wave P scratch

  int t0 = w * 128 + half * 64 + wid * 16;
  long qbase = ((long)b * SEQ + t0 + lr) * DM;
  short8 qf[4];
#pragma unroll
  for (int ks = 0; ks < 4; ks++) qf[ks] = *(const short8*)(q + qbase + ks * 32 + lq4 * 8);

  floatx4 Oacc[8];
#pragma unroll
  for (int i = 0; i < 8; i++) Oacc[i] = {0.f, 0.f, 0.f, 0.f};
  float rs[4] = {0.f, 0.f, 0.f, 0.f};

  int keystart = w * 128 - 128;
  for (int ch = 0; ch < 12; ch++) {
    int kb = keystart + ch * 32;
    if (kb < 0 || kb >= SEQ) continue;  // uniform per block
    {
      int j = tid >> 3, d = (tid & 7) * 16;
      const bf16* ksrc = k + ((long)b * SEQ + kb + j) * DM + d;
      *(uint4*)(&Ks[j * 128 + d]) = *(const uint4*)(ksrc);
      *(uint4*)(&Ks[j * 128 + d + 8]) = *(const uint4*)(ksrc + 8);
      const bf16* vsrc = v + ((long)b * SEQ + kb + j) * DM + d;
#pragma unroll
      for (int e = 0; e < 16; e++) Vts[(d + e) * 32 + j] = vsrc[e];
    }
    __syncthreads();
    floatx4 s0 = {0.f, 0.f, 0.f, 0.f}, s1 = {0.f, 0.f, 0.f, 0.f};
#pragma unroll
    for (int ks = 0; ks < 4; ks++) {
      short8 kf0 = *(const short8*)(&Ks[(0 + lr) * 128 + ks * 32 + lq4 * 8]);
      short8 kf1 = *(const short8*)(&Ks[(16 + lr) * 128 + ks * 32 + lq4 * 8]);
      s0 = MFMA16(qf[ks], kf0, s0);
      s1 = MFMA16(qf[ks], kf1, s1);
    }
#pragma unroll
    for (int reg = 0; reg < 4; reg++) {
      float e0 = __expf(s0[reg] * 0.08838834764831845f);
      float e1 = __expf(s1[reg] * 0.08838834764831845f);
      rs[reg] += e0 + e1;
      Ps[wid][(lq4 * 4 + reg) * 32 + lr] = (bf16)e0;
      Ps[wid][(lq4 * 4 + reg) * 32 + 16 + lr] = (bf16)e1;
    }
    __syncthreads();
    short8 pf = *(const short8*)(&Ps[wid][lr * 32 + lq4 * 8]);
#pragma unroll
    for (int nt = 0; nt < 8; nt++) {
      short8 vf = *(const short8*)(&Vts[(nt * 16 + lr) * 32 + lq4 * 8]);
      Oacc[nt] = MFMA16(pf, vf, Oacc[nt]);
    }
    __syncthreads();
  }
#pragma unroll
  for (int m = 1; m < 16; m <<= 1)
#pragma unroll
    for (int reg = 0; reg < 4; reg++) rs[reg] += __shfl_xor(rs[reg], m, 64);
  long obase = ((long)b * SEQ + t0 + lq4 * 4) * DM;
#pragma unroll
  for (int nt = 0; nt < 8; nt++)
#pragma unroll
    for (int reg = 0; reg < 4; reg++)
      att[obase + (long)reg * DM + nt * 16 + lr] = (bf16)(Oacc[nt][reg] / rs[reg]);
}

// ---------------------------------------------------------------------------
// Linear-attn q-softmax: qp[z6][t][128] = softmax(q_head)*d^-0.5, z6=lb*3+h2
// ---------------------------------------------------------------------------
__global__ __launch_bounds__(256) void qp_softmax(const bf16* __restrict__ q, bf16* __restrict__ qp) {
  int wid = threadIdx.x >> 6, lane = threadIdx.x & 63;
  long task = (long)blockIdx.x * 4 + wid;  // < 24576
  int tt = (int)(task & (SEQ - 1));
  int z6 = (int)(task >> 12);
  int lb = z6 / 3, h2 = z6 % 3;
  const bf16* src = q + ((long)lb * SEQ + tt) * DM + (h2 + 1) * 128 + lane * 2;
  float x0 = (float)src[0], x1 = (float)src[1];
  float m = fmaxf(x0, x1);
#pragma unroll
  for (int s = 32; s >= 1; s >>= 1) m = fmaxf(m, __shfl_xor(m, s, 64));
  float e0 = __expf(x0 - m), e1 = __expf(x1 - m);
  float sm = e0 + e1;
#pragma unroll
  for (int s = 32; s >= 1; s >>= 1) sm += __shfl_xor(sm, s, 64);
  float inv = 0.08838834764831845f / sm;
  bf16* dst = qp + task * 128 + lane * 2;
  dst[0] = (bf16)(e0 * inv);
  dst[1] = (bf16)(e1 * inv);
}

// ---------------------------------------------------------------------------
// k column stats (softmax over sequence incl. zero pad rows): m,l per (z6,d)
// ---------------------------------------------------------------------------
__global__ __launch_bounds__(128) void kstats(const bf16* __restrict__ k, float* __restrict__ kml) {
  int z = blockIdx.x;   // [0,6)
  int lb = z / 3, h2 = z % 3, ch = (h2 + 1) * 128;
  int d = threadIdx.x;
  const bf16* base = k + (long)lb * SEQ * DM + ch + d;
  float m[4] = {-1e30f, -1e30f, -1e30f, -1e30f};
  float l[4] = {0.f, 0.f, 0.f, 0.f};
  for (int t = 0; t < SEQ; t += 4) {
#pragma unroll
    for (int u = 0; u < 4; u++) {
      float x = (float)base[(long)(t + u) * DM];
      float nm = fmaxf(m[u], x);
      l[u] = l[u] * __expf(m[u] - nm) + __expf(x - nm);
      m[u] = nm;
    }
  }
  float M = fmaxf(fmaxf(m[0], m[1]), fmaxf(m[2], m[3]));
  float L = 0.f;
#pragma unroll
  for (int u = 0; u < 4; u++) L += l[u] * __expf(m[u] - M);
  kml[z * 256 + d] = M;
  kml[z * 256 + 128 + d] = L;
}

// ---------------------------------------------------------------------------
// ctx partials: part[z6][chunk][e*128+d] = sum_{t in 512-chunk} v[t][e]*k'[t][d]
// Grid (8 chunks, 6 z), 256 thr; thread owns 4 e x 16 d.
// ---------------------------------------------------------------------------
__global__ __launch_bounds__(256) void ctx_partial(const bf16* __restrict__ k,
                                                   const bf16* __restrict__ v,
                                                   const float* __restrict__ kml,
                                                   float* __restrict__ part) {
  int chunk = blockIdx.x, z = blockIdx.y;
  int lb = z / 3, h2 = z % 3, ch = (h2 + 1) * 128;
  int tid = threadIdx.x;
  __shared__ float ml2[128];
  __shared__ __align__(16) float kp[8][128];
  __shared__ __align__(16) float vs[8][128];
  if (tid < 128) {
    float m = kml[z * 256 + tid];
    float l = kml[z * 256 + 128 + tid];
    ml2[tid] = m + logf(l);
  }
  int eg = tid >> 3, dg = tid & 7;
  float acc[4][16];
#pragma unroll
  for (int i = 0; i < 4; i++)
#pragma unroll
    for (int j = 0; j < 16; j++) acc[i][j] = 0.f;
  int row0 = chunk * 512;
  int rr = (tid * 4) >> 7, dd = (tid * 4) & 127;
  for (int blk = 0; blk < 64; blk++) {
    int rbase = row0 + blk * 8;
    const bf16* kr = k + ((long)lb * SEQ + rbase + rr) * DM + ch + dd;
    const bf16* vr = v + ((long)lb * SEQ + rbase + rr) * DM + ch + dd;
    __syncthreads();
#pragma unroll
    for (int i = 0; i < 4; i++) {
      kp[rr][dd + i] = __expf((float)kr[i] - ml2[dd + i]);
      vs[rr][dd + i] = (float)vr[i];
    }
    __syncthreads();
#pragma unroll
    for (int r = 0; r < 8; r++) {
      float4 vv = *(const float4*)(&vs[r][eg * 4]);
      float ve[4] = {vv.x, vv.y, vv.z, vv.w};
      float kk[16];
#pragma unroll
      for (int jq = 0; jq < 4; jq++) {
        float4 kv = *(const float4*)(&kp[r][dg * 16 + jq * 4]);
        kk[jq * 4 + 0] = kv.x; kk[jq * 4 + 1] = kv.y; kk[jq * 4 + 2] = kv.z; kk[jq * 4 + 3] = kv.w;
      }
#pragma unroll
      for (int i = 0; i < 4; i++)
#pragma unroll
        for (int j = 0; j < 16; j++) acc[i][j] += ve[i] * kk[j];
    }
  }
  float* dst = part + ((long)z * 8 + chunk) * 16384;
#pragma unroll
  for (int i = 0; i < 4; i++)
#pragma unroll
    for (int jq = 0; jq < 4; jq++) {
      float4 o = {acc[i][jq * 4 + 0], acc[i][jq * 4 + 1], acc[i][jq * 4 + 2], acc[i][jq * 4 + 3]};
      *(float4*)(&dst[(eg * 4 + i) * 128 + dg * 16 + jq * 4]) = o;
    }
}

__global__ __launch_bounds__(256) void ctx_reduce(const float* __restrict__ part, bf16* __restrict__ ctxT) {
  long i = (long)blockIdx.x * 256 + threadIdx.x;  // < 98304
  int z = (int)(i >> 14);
  int off = (int)(i & 16383);
  float s = 0.f;
#pragma unroll
  for (int c = 0; c < 8; c++) s += part[(((long)z * 8 + c) << 14) + off];
  ctxT[i] = (bf16)s;
}

// ---------------------------------------------------------------------------
extern "C" void kernel_launch(void* const* d_in, const int* in_sizes, int n_in,
                              void* d_out, int out_size, void* d_ws, size_t ws_size,
                              hipStream_t stream) {
  float* outp = (float*)d_out;
  if (ws_size < (size_t)WS_NEED) {
    // Diagnostic: absmax ~1e4 next round means workspace < 125.2 MB.
    beacon<<<(out_size + 255) / 256, 256, 0, stream>>>(outp, out_size);
    return;
  }

  const float* x   = (const float*)d_in[0];
  const float* W1  = (const float*)d_in[1];
  const float* b1  = (const float*)d_in[2];
  const float* g1  = (const float*)d_in[3];
  const float* be1 = (const float*)d_in[4];
  const float* Wq  = (const float*)d_in[5];
  const float* Wk  = (const float*)d_in[6];
  const float* Wv  = (const float*)d_in[7];
  const float* Wo  = (const float*)d_in[8];
  const float* bo  = (const float*)d_in[9];
  const float* g2  = (const float*)d_in[10];
  const float* be2 = (const float*)d_in[11];
  const float* Wf1 = (const float*)d_in[12];
  const float* bf1 = (const float*)d_in[13];
  const float* Wf2 = (const float*)d_in[14];
  const float* bf2 = (const float*)d_in[15];
  const float* W2  = (const float*)d_in[16];
  const float* b2  = (const float*)d_in[17];

  char* ws = (char*)d_ws;
  float* h   = (float*)(ws + OFF_H);
  bf16* lnG  = (bf16*)(ws + OFF_LNG);
  bf16* qb   = (bf16*)(ws + OFF_Q);
  bf16* kb   = (bf16*)(ws + OFF_K);
  bf16* vb   = (bf16*)(ws + OFF_V);
  bf16* attb = (bf16*)(ws + OFF_ATT);
  bf16* ff1g = (bf16*)(ws + OFF_Q);    // overlays Q..ATT (33.5 MB, dead in FFN phase)
  bf16* qp   = (bf16*)(ws + OFF_QP);
  float* ctxp= (float*)(ws + OFF_CTXP);
  bf16* ctxT = (bf16*)(ws + OFF_CTXT);
  float* kml = (float*)(ws + OFF_KML);
  char* wt = ws + OFF_WT;
  bf16* w1t  = (bf16*)(wt + WT_W1);
  bf16* wqt  = (bf16*)(wt + WT_WQ);
  bf16* wkt  = (bf16*)(wt + WT_WK);
  bf16* wvt  = (bf16*)(wt + WT_WV);
  bf16* wot  = (bf16*)(wt + WT_WO);
  bf16* wf1t = (bf16*)(wt + WT_WF1);
  bf16* wf2t = (bf16*)(wt + WT_WF2);
  bf16* w2t  = (bf16*)(wt + WT_W2);

  // ---- weight transposes fp32 -> bf16 (Bt layout: [Npad][K], K-contiguous) ----
  transpose_pad<<<dim3(2, 8),  256, 0, stream>>>(W1,  w1t,  DINP, DM);
  transpose_pad<<<dim3(8, 8),  256, 0, stream>>>(Wq,  wqt,  DM,   DM);
  transpose_pad<<<dim3(8, 8),  256, 0, stream>>>(Wk,  wkt,  DM,   DM);
  transpose_pad<<<dim3(8, 8),  256, 0, stream>>>(Wv,  wvt,  DM,   DM);
  transpose_pad<<<dim3(8, 8),  256, 0, stream>>>(Wo,  wot,  DM,   DM);
  transpose_pad<<<dim3(8, 32), 256, 0, stream>>>(Wf1, wf1t, DM,   DFF);
  transpose_pad<<<dim3(32, 8), 256, 0, stream>>>(Wf2, wf2t, DFF,  DM);
  transpose_pad<<<dim3(8, 2),  256, 0, stream>>>(W2,  w2t,  DM,   64);

  // ---- h = tanh(xpad @ W1 + b1) fp32; pad rows handled in A staging ----
  gemm_bt<<<dim3(4, 256, 1), 256, 0, stream>>>(x, w1t, b1, h, nullptr,
      DINP, DINP, DINP, DM, 0, 1, 0, 0, 1, 0, 0);

  // ---- attention, 4 groups of 2 batches ----
  for (int g = 0; g < NGROUP; g++) {
    float* hg = h + (long)g * GROUPROWS * DM;
    ln_kernel<<<GROUPROWS / 4, 256, 0, stream>>>(hg, g1, be1, lnG);
    gemm_bt<<<dim3(4, 64, 1), 256, 0, stream>>>(lnG, wqt, nullptr, nullptr, qb,
        DM, DM, DM, DM, 1, 0, 0, 0, 1, 0, 0);
    gemm_bt<<<dim3(4, 64, 1), 256, 0, stream>>>(lnG, wkt, nullptr, nullptr, kb,
        DM, DM, DM, DM, 1, 0, 0, 0, 1, 0, 0);
    gemm_bt<<<dim3(4, 64, 1), 256, 0, stream>>>(lnG, wvt, nullptr, nullptr, vb,
        DM, DM, DM, DM, 1, 0, 0, 0, 1, 0, 0);

    local_attn<<<dim3(2, 32, 2), 256, 0, stream>>>(qb, kb, vb, attb);

    qp_softmax<<<6144, 256, 0, stream>>>(qb, qp);
    kstats<<<6, 128, 0, stream>>>(kb, kml);
    ctx_partial<<<dim3(8, 6), 256, 0, stream>>>(kb, vb, kml, ctxp);
    ctx_reduce<<<384, 256, 0, stream>>>(ctxp, ctxT);
    gemm_bt<<<dim3(1, 32, 6), 256, 0, stream>>>(qp, ctxT, nullptr, nullptr, attb + 128,
        128, 128, 128, DM, 1, 0,
        (long)SEQ * 128, 16384L, 3, (long)SEQ * DM, 128L);

    gemm_bt<<<dim3(4, 64, 1), 256, 0, stream>>>(attb, wot, bo, hg, nullptr,
        DM, DM, DM, DM, 2, 0, 0, 0, 1, 0, 0);
  }

  // ---- FFN, 4 groups ----
  for (int g = 0; g < NGROUP; g++) {
    float* hg = h + (long)g * GROUPROWS * DM;
    ln_kernel<<<GROUPROWS / 4, 256, 0, stream>>>(hg, g2, be2, lnG);
    gemm_bt<<<dim3(16, 64, 1), 256, 0, stream>>>(lnG, wf1t, bf1, nullptr, ff1g,
        DM, DM, DM, DFF, 4, 0, 0, 0, 1, 0, 0);
    gemm_bt<<<dim3(4, 64, 1), 256, 0, stream>>>(ff1g, wf2t, bf2, hg, nullptr,
        DFF, DFF, DFF, DM, 2, 0, 0, 0, 1, 0, 0);
  }

  // ---- out = (h @ W2 + b2)[:, :3000, :] -> d_out fp32 (h staged as bf16) ----
  gemm_bt<<<dim3(1, 256, 1), 256, 0, stream>>>(h, w2t, b2, outp, nullptr,
      DM, DM, DM, 64, 5, 2, 0, 0, 1, 0, 0);
}

// Round 4
// 1585.835 us; speedup vs baseline: 1.4853x; 1.4853x over previous
//
#include <hip/hip_runtime.h>
#include <hip/hip_bf16.h>
#include <math.h>

// ---------------------------------------------------------------------------
// Linear_Transformer on MI355X (gfx950). fp32 I/O, bf16 MFMA internals,
// fp32 residual stream.
// Round 4: (1) kstats was 845us (36% of runtime) at 6 blocks -> two-phase
// chunked version (192 blocks + combine); (2) GEMM LDS stride 32->40 bf16 to
// kill 8-way ds_read_b128 bank conflicts (SQ_LDS_BANK_CONFLICT 5.2e5);
// (3) QKV merged into one z=3 GEMM, 8 transposes merged into one kernel.
// ---------------------------------------------------------------------------

typedef __hip_bfloat16 bf16;
typedef __attribute__((ext_vector_type(8))) short short8;   // 8 bf16 (MFMA A/B frag)
typedef __attribute__((ext_vector_type(4))) float floatx4;  // MFMA C/D frag

#define SEQ   4096
#define NBAT  8
#define DM    512
#define DINP  128
#define DFF   2048
#define NREAL 3000
#define GROUPROWS 8192        // 2 batches per group
#define NGROUP 4
#define LDST  40              // LDS row stride (bf16) — 80B, conflict-free

#define MFMA16(a,b,c) __builtin_amdgcn_mfma_f32_16x16x32_bf16((a),(b),(c),0,0,0)

// ---------------- workspace arena (bytes), total 125,245,440 ----------------
#define OFF_H     0L            // h fp32 [32768][512]            67,108,864
#define OFF_LNG   67108864L     // LN out bf16 [8192][512]         8,388,608
#define OFF_Q     75497472L     // q bf16 [8192][512]; ff1g overlays Q..ATT
#define OFF_K     83886080L
#define OFF_V     92274688L
#define OFF_ATT   100663296L
#define OFF_QP    109051904L    // qp bf16 [6][4096][128]          6,291,456
#define OFF_CTXP  115343360L    // ctx partials f32 [6][8][16384]; also kstats parts
#define OFF_CTXT  118489088L    // ctxT bf16 [6][16384]              196,608
#define OFF_KML   118685696L    // k col stats f32 [6][256]            6,144
#define OFF_WT    118691840L    // transposed bf16 weights         6,553,600
#define WS_NEED   125245440L

// ---------------------------------------------------------------------------
__global__ __launch_bounds__(256) void beacon(float* __restrict__ out, long n) {
  long i = (long)blockIdx.x * 256 + threadIdx.x;
  if (i < n) out[i] = 10000.f;
}

// ---------------------------------------------------------------------------
// All 8 weight transposes in one launch. Wt[n][k] = n<N ? (bf16)W[k][n] : 0
// z selects the weight; grid (32,32,8), blocks outside (K,Npad) early-exit.
// ---------------------------------------------------------------------------
__global__ __launch_bounds__(256) void transpose8(
    const float* __restrict__ W1, const float* __restrict__ Wq,
    const float* __restrict__ Wk, const float* __restrict__ Wv,
    const float* __restrict__ Wo, const float* __restrict__ Wf1,
    const float* __restrict__ Wf2, const float* __restrict__ W2,
    bf16* __restrict__ wt) {
  const int Ks[8]   = {128, 512, 512, 512, 512, 512, 2048, 512};
  const int Ns[8]   = {512, 512, 512, 512, 512, 2048, 512, 64};
  const int Nps[8]  = {512, 512, 512, 512, 512, 2048, 512, 128};
  const long Ofs[8] = {0L, 65536L, 327680L, 589824L, 851968L, 1114112L, 2162688L, 3211264L};
  int zi = blockIdx.z;
  int K = Ks[zi], N = Ns[zi], Npad = Nps[zi];
  int k0 = blockIdx.x * 64, n0 = blockIdx.y * 64;
  if (k0 >= K || n0 >= Npad) return;
  const float* W = zi == 0 ? W1 : zi == 1 ? Wq : zi == 2 ? Wk : zi == 3 ? Wv
                 : zi == 4 ? Wo : zi == 5 ? Wf1 : zi == 6 ? Wf2 : W2;
  bf16* Wt = wt + Ofs[zi];
  __shared__ float t[64][65];
  int r = threadIdx.x >> 2, c = (threadIdx.x & 3) * 16;
#pragma unroll
  for (int i = 0; i < 16; i++) {
    int n = n0 + c + i;
    t[r][c + i] = (n < N) ? W[(long)(k0 + r) * N + n] : 0.f;
  }
  __syncthreads();
#pragma unroll
  for (int i = 0; i < 16; i++)
    Wt[(long)(n0 + r) * K + k0 + c + i] = (bf16)t[c + i][r];
}

// ---------------------------------------------------------------------------
// pack 8 consecutive floats into 8 bf16 (uint4)
// ---------------------------------------------------------------------------
__device__ inline uint4 pack8(const float* p) {
  union { bf16 h[8]; uint4 u; } r;
  float4 a = *(const float4*)p;
  float4 b = *(const float4*)(p + 4);
  r.h[0] = (bf16)a.x; r.h[1] = (bf16)a.y; r.h[2] = (bf16)a.z; r.h[3] = (bf16)a.w;
  r.h[4] = (bf16)b.x; r.h[5] = (bf16)b.y; r.h[6] = (bf16)b.z; r.h[7] = (bf16)b.w;
  return r.u;
}

// ---------------------------------------------------------------------------
// Generic MFMA GEMM: C[M x N] = epi(A[M x K] @ Bt[N x K]^T + bias)
// 128x128 tile, BK=32, 256 threads (4 waves, 2x2), z-batched.
// AMODE: 0 bf16 A   1 fp32 x (8,3000,128) zero-padded to (8,4096,128)
//        2 fp32 A (convert in staging)
// EPI:   0 tanh->Cf  1 bf16->Cb  2 Cf+=  4 gelu->Cb
//        5 row-remap (b,t<3000), c<64 -> Cf (fp32 d_out)
// ---------------------------------------------------------------------------
__global__ __launch_bounds__(256) void gemm_bt(
    const void* __restrict__ Avoid, const bf16* __restrict__ Bt,
    const float* __restrict__ bias, float* __restrict__ Cf, bf16* __restrict__ Cb,
    int K, int lda, int ldb, int ldc, int EPI, int AMODE,
    long aBatch, long bBatch, int zdiv, long cOuter, long cInner) {
  __shared__ __align__(16) bf16 As[128 * LDST];
  __shared__ __align__(16) bf16 Bs[128 * LDST];
  const int tid = threadIdx.x;
  const int bz = blockIdx.z;
  const bf16* A = (const bf16*)Avoid + (AMODE == 0 ? (long)bz * aBatch : 0);
  const float* Af = (const float*)Avoid;
  Bt += (long)bz * bBatch;
  const long cOff = (long)(bz / zdiv) * cOuter + (long)(bz % zdiv) * cInner;
  const int row0 = blockIdx.y * 128;
  const int col0 = blockIdx.x * 128;
  const int lane = tid & 63, wid = tid >> 6;
  const int wm = (wid & 1) * 64, wn = (wid >> 1) * 64;
  const int lr = lane & 15, lk = (lane >> 4) * 8;

  const int srow = tid >> 2;         // 0..63
  const int skcol = (tid & 3) * 8;   // 0,8,16,24
  const long r0 = row0 + srow, r1 = r0 + 64;
  const bf16* pB = Bt + (long)(col0 + srow) * ldb + skcol;
  const int ldsOff = srow * LDST + skcol;

  const bf16* pA0 = nullptr; const bf16* pA1 = nullptr;
  const float* pF0 = nullptr; const float* pF1 = nullptr;
  bool v0 = true, v1 = true;
  if (AMODE == 0) {
    pA0 = A + r0 * lda + skcol;
    pA1 = A + r1 * lda + skcol;
  } else if (AMODE == 1) {
    int t0 = (int)(r0 & (SEQ - 1)), t1 = (int)(r1 & (SEQ - 1));
    v0 = t0 < NREAL; v1 = t1 < NREAL;
    if (!v0) t0 = 0;
    if (!v1) t1 = 0;
    pF0 = Af + ((r0 >> 12) * NREAL + t0) * DINP + skcol;
    pF1 = Af + ((r1 >> 12) * NREAL + t1) * DINP + skcol;
  } else {
    pF0 = Af + r0 * lda + skcol;
    pF1 = Af + r1 * lda + skcol;
  }

  floatx4 acc[4][4];
#pragma unroll
  for (int i = 0; i < 4; i++)
#pragma unroll
    for (int j = 0; j < 4; j++) acc[i][j] = {0.f, 0.f, 0.f, 0.f};

  for (int k0 = 0; k0 < K; k0 += 32) {
    uint4 b0 = *(const uint4*)(pB);
    uint4 b1 = *(const uint4*)(pB + (long)64 * ldb);
    pB += 32;
    uint4 a0 = {0, 0, 0, 0}, a1 = {0, 0, 0, 0};
    if (AMODE == 0) {
      a0 = *(const uint4*)(pA0);
      a1 = *(const uint4*)(pA1);
      pA0 += 32; pA1 += 32;
    } else {
      if (v0) a0 = pack8(pF0);
      if (v1) a1 = pack8(pF1);
      pF0 += 32; pF1 += 32;
    }
    __syncthreads();
    *(uint4*)(&As[ldsOff]) = a0;
    *(uint4*)(&As[ldsOff + 64 * LDST]) = a1;
    *(uint4*)(&Bs[ldsOff]) = b0;
    *(uint4*)(&Bs[ldsOff + 64 * LDST]) = b1;
    __syncthreads();
    short8 af[4], bfr[4];
#pragma unroll
    for (int mt = 0; mt < 4; mt++) af[mt] = *(const short8*)(&As[(wm + mt * 16 + lr) * LDST + lk]);
#pragma unroll
    for (int nt = 0; nt < 4; nt++) bfr[nt] = *(const short8*)(&Bs[(wn + nt * 16 + lr) * LDST + lk]);
#pragma unroll
    for (int mt = 0; mt < 4; mt++)
#pragma unroll
      for (int nt = 0; nt < 4; nt++)
        acc[mt][nt] = MFMA16(af[mt], bfr[nt], acc[mt][nt]);
  }

  // D element (mt,nt,reg): row=(lane>>4)*4+reg, col=lane&15 within 16x16 tile
#pragma unroll
  for (int nt = 0; nt < 4; nt++) {
    int c = col0 + wn + nt * 16 + lr;
    float bv = 0.f;
    if (bias) {
      if (EPI == 5) { if (c < 64) bv = bias[c]; }
      else bv = bias[c];
    }
#pragma unroll
    for (int mt = 0; mt < 4; mt++) {
      long rb = row0 + wm + mt * 16 + (lane >> 4) * 4;
#pragma unroll
      for (int reg = 0; reg < 4; reg++) {
        float v = acc[mt][nt][reg] + bv;
        long ri = rb + reg;
        long idx = cOff + ri * (long)ldc + c;
        if (EPI == 0) Cf[idx] = tanhf(v);
        else if (EPI == 1) Cb[idx] = (bf16)v;
        else if (EPI == 2) Cf[idx] += v;
        else if (EPI == 4) { float g = 0.5f * v * (1.f + erff(v * 0.70710678118654752f)); Cb[idx] = (bf16)g; }
        else if (EPI == 5) {
          int bb = (int)(ri >> 12); int tt = (int)(ri & (SEQ - 1));
          if (tt < NREAL && c < 64) Cf[((long)bb * NREAL + tt) * 64 + c] = v;
        }
      }
    }
  }
}

// ---------------------------------------------------------------------------
// LayerNorm over 512 fp32 -> bf16. One wave per row, 4 rows per block.
// ---------------------------------------------------------------------------
__global__ __launch_bounds__(256) void ln_kernel(const float* __restrict__ h,
                                                 const float* __restrict__ g,
                                                 const float* __restrict__ bta,
                                                 bf16* __restrict__ out) {
  int wid = threadIdx.x >> 6, lane = threadIdx.x & 63;
  long row = (long)blockIdx.x * 4 + wid;
  const float* src = h + row * DM + lane * 8;
  float4 a = *(const float4*)(src);
  float4 b = *(const float4*)(src + 4);
  float x[8] = {a.x, a.y, a.z, a.w, b.x, b.y, b.z, b.w};
  float s = 0.f, sq = 0.f;
#pragma unroll
  for (int i = 0; i < 8; i++) { s += x[i]; sq += x[i] * x[i]; }
#pragma unroll
  for (int m = 32; m >= 1; m >>= 1) { s += __shfl_xor(s, m, 64); sq += __shfl_xor(sq, m, 64); }
  float mu = s * (1.f / DM);
  float var = sq * (1.f / DM) - mu * mu;
  float rstd = rsqrtf(var + 1e-5f);
  const float* gp = g + lane * 8;
  const float* bp = bta + lane * 8;
  bf16* dst = out + row * DM + lane * 8;
#pragma unroll
  for (int i = 0; i < 8; i++)
    dst[i] = (bf16)((x[i] - mu) * rstd * gp[i] + bp[i]);
}

// ---------------------------------------------------------------------------
// Local attention, head 0 (channels 0..127). Grid (2 halves, 32 windows,
// 2 local batches), 256 thr. Each wave: 16 query rows. 12 key-chunks of 32
// (windows w-1,w,w+1); OOB chunks skipped (== reference -inf mask).
// ---------------------------------------------------------------------------
__global__ __launch_bounds__(256) void local_attn(const bf16* __restrict__ q,
                                                  const bf16* __restrict__ k,
                                                  const bf16* __restrict__ v,
                                                  bf16* __restrict__ att) {
  int half = blockIdx.x, w = blockIdx.y, b = blockIdx.z;
  int tid = threadIdx.x, wid = tid >> 6, lane = tid & 63;
  int lr = lane & 15, lq4 = lane >> 4;
  __shared__ __align__(16) bf16 Ks[32 * 128];   // [j][d]
  __shared__ __align__(16) bf16 Vts[128 * 32];  // [d][j]
  __shared__ __align__(16) bf16 Ps[4][16 * 32]; // per-wave P scratch

  int t0 = w * 128 + half * 64 + wid * 16;
  long qbase = ((long)b * SEQ + t0 + lr) * DM;
  short8 qf[4];
#pragma unroll
  for (int ks = 0; ks < 4; ks++) qf[ks] = *(const short8*)(q + qbase + ks * 32 + lq4 * 8);

  floatx4 Oacc[8];
#pragma unroll
  for (int i = 0; i < 8; i++) Oacc[i] = {0.f, 0.f, 0.f, 0.f};
  float rs[4] = {0.f, 0.f, 0.f, 0.f};

  int keystart = w * 128 - 128;
  for (int ch = 0; ch < 12; ch++) {
    int kb = keystart + ch * 32;
    if (kb < 0 || kb >= SEQ) continue;  // uniform per block
    {
      int j = tid >> 3, d = (tid & 7) * 16;
      const bf16* ksrc = k + ((long)b * SEQ + kb + j) * DM + d;
      *(uint4*)(&Ks[j * 128 + d]) = *(const uint4*)(ksrc);
      *(uint4*)(&Ks[j * 128 + d + 8]) = *(const uint4*)(ksrc + 8);
      const bf16* vsrc = v + ((long)b * SEQ + kb + j) * DM + d;
#pragma unroll
      for (int e = 0; e < 16; e++) Vts[(d + e) * 32 + j] = vsrc[e];
    }
    __syncthreads();
    floatx4 s0 = {0.f, 0.f, 0.f, 0.f}, s1 = {0.f, 0.f, 0.f, 0.f};
#pragma unroll
    for (int ks = 0; ks < 4; ks++) {
      short8 kf0 = *(const short8*)(&Ks[(0 + lr) * 128 + ks * 32 + lq4 * 8]);
      short8 kf1 = *(const short8*)(&Ks[(16 + lr) * 128 + ks * 32 + lq4 * 8]);
      s0 = MFMA16(qf[ks], kf0, s0);
      s1 = MFMA16(qf[ks], kf1, s1);
    }
#pragma unroll
    for (int reg = 0; reg < 4; reg++) {
      float e0 = __expf(s0[reg] * 0.08838834764831845f);
      float e1 = __expf(s1[reg] * 0.08838834764831845f);
      rs[reg] += e0 + e1;
      Ps[wid][(lq4 * 4 + reg) * 32 + lr] = (bf16)e0;
      Ps[wid][(lq4 * 4 + reg) * 32 + 16 + lr] = (bf16)e1;
    }
    __syncthreads();
    short8 pf = *(const short8*)(&Ps[wid][lr * 32 + lq4 * 8]);
#pragma unroll
    for (int nt = 0; nt < 8; nt++) {
      short8 vf = *(const short8*)(&Vts[(nt * 16 + lr) * 32 + lq4 * 8]);
      Oacc[nt] = MFMA16(pf, vf, Oacc[nt]);
    }
    __syncthreads();
  }
#pragma unroll
  for (int m = 1; m < 16; m <<= 1)
#pragma unroll
    for (int reg = 0; reg < 4; reg++) rs[reg] += __shfl_xor(rs[reg], m, 64);
  long obase = ((long)b * SEQ + t0 + lq4 * 4) * DM;
#pragma unroll
  for (int nt = 0; nt < 8; nt++)
#pragma unroll
    for (int reg = 0; reg < 4; reg++)
      att[obase + (long)reg * DM + nt * 16 + lr] = (bf16)(Oacc[nt][reg] / rs[reg]);
}

// ---------------------------------------------------------------------------
// Linear-attn q-softmax: qp[z6][t][128] = softmax(q_head)*d^-0.5, z6=lb*3+h2
// ---------------------------------------------------------------------------
__global__ __launch_bounds__(256) void qp_softmax(const bf16* __restrict__ q, bf16* __restrict__ qp) {
  int wid = threadIdx.x >> 6, lane = threadIdx.x & 63;
  long task = (long)blockIdx.x * 4 + wid;  // < 24576
  int tt = (int)(task & (SEQ - 1));
  int z6 = (int)(task >> 12);
  int lb = z6 / 3, h2 = z6 % 3;
  const bf16* src = q + ((long)lb * SEQ + tt) * DM + (h2 + 1) * 128 + lane * 2;
  float x0 = (float)src[0], x1 = (float)src[1];
  float m = fmaxf(x0, x1);
#pragma unroll
  for (int s = 32; s >= 1; s >>= 1) m = fmaxf(m, __shfl_xor(m, s, 64));
  float e0 = __expf(x0 - m), e1 = __expf(x1 - m);
  float sm = e0 + e1;
#pragma unroll
  for (int s = 32; s >= 1; s >>= 1) sm += __shfl_xor(sm, s, 64);
  float inv = 0.08838834764831845f / sm;
  bf16* dst = qp + task * 128 + lane * 2;
  dst[0] = (bf16)(e0 * inv);
  dst[1] = (bf16)(e1 * inv);
}

// ---------------------------------------------------------------------------
// k column stats, phase 1: per-(z, 128-row chunk) column max and exp-sum.
// Grid (32 chunks, 6 z), 128 thr (one col each; coalesced 256B/row).
// part layout: m at [ (z*32+chunk)*128 + d ], l at [24576 + same].
// ---------------------------------------------------------------------------
__global__ __launch_bounds__(128) void kstats_part(const bf16* __restrict__ k,
                                                   float* __restrict__ part) {
  int chunk = blockIdx.x, z = blockIdx.y;
  int lb = z / 3, h2 = z % 3, ch = (h2 + 1) * 128;
  int d = threadIdx.x;
  const bf16* base = k + ((long)lb * SEQ + chunk * 128) * DM + ch + d;
  float m = -1e30f;
#pragma unroll 4
  for (int t = 0; t < 128; t++) m = fmaxf(m, (float)base[(long)t * DM]);
  float l = 0.f;
#pragma unroll 4
  for (int t = 0; t < 128; t++) l += __expf((float)base[(long)t * DM] - m);
  int idx = (z * 32 + chunk) * 128 + d;
  part[idx] = m;
  part[24576 + idx] = l;
}

// phase 2: combine 32 chunk stats -> kml[z*256+d]=M, +128=L
__global__ __launch_bounds__(128) void kstats_comb(const float* __restrict__ part,
                                                   float* __restrict__ kml) {
  int z = blockIdx.x, d = threadIdx.x;
  float M = -1e30f;
#pragma unroll 4
  for (int c = 0; c < 32; c++) M = fmaxf(M, part[(z * 32 + c) * 128 + d]);
  float L = 0.f;
#pragma unroll 4
  for (int c = 0; c < 32; c++) {
    int i = (z * 32 + c) * 128 + d;
    L += part[24576 + i] * __expf(part[i] - M);
  }
  kml[z * 256 + d] = M;
  kml[z * 256 + 128 + d] = L;
}

// ---------------------------------------------------------------------------
// ctx partials: part[z6][chunk][e*128+d] = sum_{t in 512-chunk} v[t][e]*k'[t][d]
// Grid (8 chunks, 6 z), 256 thr; thread owns 4 e x 16 d.
// ---------------------------------------------------------------------------
__global__ __launch_bounds__(256) void ctx_partial(const bf16* __restrict__ k,
                                                   const bf16* __restrict__ v,
                                                   const float* __restrict__ kml,
                                                   float* __restrict__ part) {
  int chunk = blockIdx.x, z = blockIdx.y;
  int lb = z / 3, h2 = z % 3, ch = (h2 + 1) * 128;
  int tid = threadIdx.x;
  __shared__ float ml2[128];
  __shared__ __align__(16) float kp[8][128];
  __shared__ __align__(16) float vs[8][128];
  if (tid < 128) {
    float m = kml[z * 256 + tid];
    float l = kml[z * 256 + 128 + tid];
    ml2[tid] = m + logf(l);
  }
  int eg = tid >> 3, dg = tid & 7;
  float acc[4][16];
#pragma unroll
  for (int i = 0; i < 4; i++)
#pragma unroll
    for (int j = 0; j < 16; j++) acc[i][j] = 0.f;
  int row0 = chunk * 512;
  int rr = (tid * 4) >> 7, dd = (tid * 4) & 127;
  for (int blk = 0; blk < 64; blk++) {
    int rbase = row0 + blk * 8;
    const bf16* kr = k + ((long)lb * SEQ + rbase + rr) * DM + ch + dd;
    const bf16* vr = v + ((long)lb * SEQ + rbase + rr) * DM + ch + dd;
    __syncthreads();
#pragma unroll
    for (int i = 0; i < 4; i++) {
      kp[rr][dd + i] = __expf((float)kr[i] - ml2[dd + i]);
      vs[rr][dd + i] = (float)vr[i];
    }
    __syncthreads();
#pragma unroll
    for (int r = 0; r < 8; r++) {
      float4 vv = *(const float4*)(&vs[r][eg * 4]);
      float ve[4] = {vv.x, vv.y, vv.z, vv.w};
      float kk[16];
#pragma unroll
      for (int jq = 0; jq < 4; jq++) {
        float4 kv = *(const float4*)(&kp[r][dg * 16 + jq * 4]);
        kk[jq * 4 + 0] = kv.x; kk[jq * 4 + 1] = kv.y; kk[jq * 4 + 2] = kv.z; kk[jq * 4 + 3] = kv.w;
      }
#pragma unroll
      for (int i = 0; i < 4; i++)
#pragma unroll
        for (int j = 0; j < 16; j++) acc[i][j] += ve[i] * kk[j];
    }
  }
  float* dst = part + ((long)z * 8 + chunk) * 16384;
#pragma unroll
  for (int i = 0; i < 4; i++)
#pragma unroll
    for (int jq = 0; jq < 4; jq++) {
      float4 o = {acc[i][jq * 4 + 0], acc[i][jq * 4 + 1], acc[i][jq * 4 + 2], acc[i][jq * 4 + 3]};
      *(float4*)(&dst[(eg * 4 + i) * 128 + dg * 16 + jq * 4]) = o;
    }
}

__global__ __launch_bounds__(256) void ctx_reduce(const float* __restrict__ part, bf16* __restrict__ ctxT) {
  long i = (long)blockIdx.x * 256 + threadIdx.x;  // < 98304
  int z = (int)(i >> 14);
  int off = (int)(i & 16383);
  float s = 0.f;
#pragma unroll
  for (int c = 0; c < 8; c++) s += part[(((long)z * 8 + c) << 14) + off];
  ctxT[i] = (bf16)s;
}

// ---------------------------------------------------------------------------
extern "C" void kernel_launch(void* const* d_in, const int* in_sizes, int n_in,
                              void* d_out, int out_size, void* d_ws, size_t ws_size,
                              hipStream_t stream) {
  float* outp = (float*)d_out;
  if (ws_size < (size_t)WS_NEED) {
    beacon<<<(out_size + 255) / 256, 256, 0, stream>>>(outp, out_size);
    return;
  }

  const float* x   = (const float*)d_in[0];
  const float* W1  = (const float*)d_in[1];
  const float* b1  = (const float*)d_in[2];
  const float* g1  = (const float*)d_in[3];
  const float* be1 = (const float*)d_in[4];
  const float* Wq  = (const float*)d_in[5];
  const float* Wk  = (const float*)d_in[6];
  const float* Wv  = (const float*)d_in[7];
  const float* Wo  = (const float*)d_in[8];
  const float* bo  = (const float*)d_in[9];
  const float* g2  = (const float*)d_in[10];
  const float* be2 = (const float*)d_in[11];
  const float* Wf1 = (const float*)d_in[12];
  const float* bf1 = (const float*)d_in[13];
  const float* Wf2 = (const float*)d_in[14];
  const float* bf2 = (const float*)d_in[15];
  const float* W2  = (const float*)d_in[16];
  const float* b2  = (const float*)d_in[17];

  char* ws = (char*)d_ws;
  float* h   = (float*)(ws + OFF_H);
  bf16* lnG  = (bf16*)(ws + OFF_LNG);
  bf16* qb   = (bf16*)(ws + OFF_Q);
  bf16* kb   = (bf16*)(ws + OFF_K);
  bf16* vb   = (bf16*)(ws + OFF_V);
  bf16* attb = (bf16*)(ws + OFF_ATT);
  bf16* ff1g = (bf16*)(ws + OFF_Q);    // overlays Q..ATT (dead in FFN phase)
  bf16* qp   = (bf16*)(ws + OFF_QP);
  float* ctxp= (float*)(ws + OFF_CTXP);  // also kstats parts (before ctx_partial)
  bf16* ctxT = (bf16*)(ws + OFF_CTXT);
  float* kml = (float*)(ws + OFF_KML);
  bf16* wt   = (bf16*)(ws + OFF_WT);
  bf16* wqt  = wt + 65536;
  bf16* wf1t = wt + 1114112;
  bf16* wf2t = wt + 2162688;
  bf16* w2t  = wt + 3211264;
  bf16* wot  = wt + 851968;

  // ---- all weight transposes (fp32 -> bf16, [Npad][K] K-contiguous) ----
  transpose8<<<dim3(32, 32, 8), 256, 0, stream>>>(W1, Wq, Wk, Wv, Wo, Wf1, Wf2, W2, wt);

  // ---- h = tanh(xpad @ W1 + b1) fp32; pad rows handled in A staging ----
  gemm_bt<<<dim3(4, 256, 1), 256, 0, stream>>>(x, wt, b1, h, nullptr,
      DINP, DINP, DINP, DM, 0, 1, 0, 0, 1, 0, 0);

  // ---- attention, 4 groups of 2 batches ----
  for (int g = 0; g < NGROUP; g++) {
    float* hg = h + (long)g * GROUPROWS * DM;
    ln_kernel<<<GROUPROWS / 4, 256, 0, stream>>>(hg, g1, be1, lnG);
    // Q,K,V in one z=3 batched launch (wq/wk/wv and qb/kb/vb are contiguous)
    gemm_bt<<<dim3(4, 64, 3), 256, 0, stream>>>(lnG, wqt, nullptr, nullptr, qb,
        DM, DM, DM, DM, 1, 0,
        0L, 262144L, 3, 0L, 4194304L);

    local_attn<<<dim3(2, 32, 2), 256, 0, stream>>>(qb, kb, vb, attb);

    qp_softmax<<<6144, 256, 0, stream>>>(qb, qp);
    kstats_part<<<dim3(32, 6), 128, 0, stream>>>(kb, ctxp);
    kstats_comb<<<6, 128, 0, stream>>>(ctxp, kml);
    ctx_partial<<<dim3(8, 6), 256, 0, stream>>>(kb, vb, kml, ctxp);
    ctx_reduce<<<384, 256, 0, stream>>>(ctxp, ctxT);
    gemm_bt<<<dim3(1, 32, 6), 256, 0, stream>>>(qp, ctxT, nullptr, nullptr, attb + 128,
        128, 128, 128, DM, 1, 0,
        (long)SEQ * 128, 16384L, 3, (long)SEQ * DM, 128L);

    gemm_bt<<<dim3(4, 64, 1), 256, 0, stream>>>(attb, wot, bo, hg, nullptr,
        DM, DM, DM, DM, 2, 0, 0, 0, 1, 0, 0);
  }

  // ---- FFN, 4 groups ----
  for (int g = 0; g < NGROUP; g++) {
    float* hg = h + (long)g * GROUPROWS * DM;
    ln_kernel<<<GROUPROWS / 4, 256, 0, stream>>>(hg, g2, be2, lnG);
    gemm_bt<<<dim3(16, 64, 1), 256, 0, stream>>>(lnG, wf1t, bf1, nullptr, ff1g,
        DM, DM, DM, DFF, 4, 0, 0, 0, 1, 0, 0);
    gemm_bt<<<dim3(4, 64, 1), 256, 0, stream>>>(ff1g, wf2t, bf2, hg, nullptr,
        DFF, DFF, DFF, DM, 2, 0, 0, 0, 1, 0, 0);
  }

  // ---- out = (h @ W2 + b2)[:, :3000, :] -> d_out fp32 (h staged as bf16) ----
  gemm_bt<<<dim3(1, 256, 1), 256, 0, stream>>>(h, w2t, b2, outp, nullptr,
      DM, DM, DM, 64, 5, 2, 0, 0, 1, 0, 0);
}

// Round 5
// 1391.685 us; speedup vs baseline: 1.6925x; 1.1395x over previous
//
#include <hip/hip_runtime.h>
#include <hip/hip_bf16.h>
#include <math.h>

// ---------------------------------------------------------------------------
// Linear_Transformer on MI355X (gfx950). fp32 I/O, bf16 MFMA internals,
// fp32 residual stream.
// Round 5: (1) ctx_partial (87us x4, 2% occupancy, MfmaUtil 0) -> MFMA
// version with exp fused into transposed LDS staging; (2) gemm_bt staging
// via __builtin_amdgcn_global_load_lds width=16 (m97 ladder step), LDS
// stride back to 32 (async scatter is base+lane*16 — padding breaks it).
// ---------------------------------------------------------------------------

typedef __hip_bfloat16 bf16;
typedef __attribute__((ext_vector_type(8))) short short8;   // 8 bf16 (MFMA A/B frag)
typedef __attribute__((ext_vector_type(4))) float floatx4;  // MFMA C/D frag

#define SEQ   4096
#define NBAT  8
#define DM    512
#define DINP  128
#define DFF   2048
#define NREAL 3000
#define GROUPROWS 8192        // 2 batches per group
#define NGROUP 4
#define CS    40              // ctx_mfma LDS stride (80B, 16B-aligned)

#define MFMA16(a,b,c) __builtin_amdgcn_mfma_f32_16x16x32_bf16((a),(b),(c),0,0,0)

// async global->LDS, 16B per lane, deposits at lds + lane*16 (CK cast pattern)
__device__ __forceinline__ void gload_lds16(const void* g, void* l) {
  auto* gp = reinterpret_cast<const __attribute__((address_space(1))) unsigned int*>(
      reinterpret_cast<uintptr_t>(g));
  auto* lp = reinterpret_cast<__attribute__((address_space(3))) unsigned int*>(
      reinterpret_cast<uintptr_t>(l));
  __builtin_amdgcn_global_load_lds(gp, lp, 16, 0, 0);
}

// ---------------- workspace arena (bytes), total 125,245,440 ----------------
#define OFF_H     0L            // h fp32 [32768][512]            67,108,864
#define OFF_LNG   67108864L     // LN out bf16 [8192][512]         8,388,608
#define OFF_Q     75497472L     // q bf16 [8192][512]; ff1g overlays Q..ATT
#define OFF_K     83886080L
#define OFF_V     92274688L
#define OFF_ATT   100663296L
#define OFF_QP    109051904L    // qp bf16 [6][4096][128]          6,291,456
#define OFF_CTXP  115343360L    // ctx partials f32 [6][8][16384]; also kstats parts
#define OFF_CTXT  118489088L    // ctxT bf16 [6][16384]              196,608
#define OFF_KML   118685696L    // k col stats f32 [6][256]            6,144
#define OFF_WT    118691840L    // transposed bf16 weights         6,553,600
#define WS_NEED   125245440L

// ---------------------------------------------------------------------------
__global__ __launch_bounds__(256) void beacon(float* __restrict__ out, long n) {
  long i = (long)blockIdx.x * 256 + threadIdx.x;
  if (i < n) out[i] = 10000.f;
}

// ---------------------------------------------------------------------------
// All 8 weight transposes in one launch. Wt[n][k] = n<N ? (bf16)W[k][n] : 0
// ---------------------------------------------------------------------------
__global__ __launch_bounds__(256) void transpose8(
    const float* __restrict__ W1, const float* __restrict__ Wq,
    const float* __restrict__ Wk, const float* __restrict__ Wv,
    const float* __restrict__ Wo, const float* __restrict__ Wf1,
    const float* __restrict__ Wf2, const float* __restrict__ W2,
    bf16* __restrict__ wt) {
  const int Ks[8]   = {128, 512, 512, 512, 512, 512, 2048, 512};
  const int Ns[8]   = {512, 512, 512, 512, 512, 2048, 512, 64};
  const int Nps[8]  = {512, 512, 512, 512, 512, 2048, 512, 128};
  const long Ofs[8] = {0L, 65536L, 327680L, 589824L, 851968L, 1114112L, 2162688L, 3211264L};
  int zi = blockIdx.z;
  int K = Ks[zi], N = Ns[zi], Npad = Nps[zi];
  int k0 = blockIdx.x * 64, n0 = blockIdx.y * 64;
  if (k0 >= K || n0 >= Npad) return;
  const float* W = zi == 0 ? W1 : zi == 1 ? Wq : zi == 2 ? Wk : zi == 3 ? Wv
                 : zi == 4 ? Wo : zi == 5 ? Wf1 : zi == 6 ? Wf2 : W2;
  bf16* Wt = wt + Ofs[zi];
  __shared__ float t[64][65];
  int r = threadIdx.x >> 2, c = (threadIdx.x & 3) * 16;
#pragma unroll
  for (int i = 0; i < 16; i++) {
    int n = n0 + c + i;
    t[r][c + i] = (n < N) ? W[(long)(k0 + r) * N + n] : 0.f;
  }
  __syncthreads();
#pragma unroll
  for (int i = 0; i < 16; i++)
    Wt[(long)(n0 + r) * K + k0 + c + i] = (bf16)t[c + i][r];
}

// ---------------------------------------------------------------------------
__device__ inline uint4 pack8(const float* p) {
  union { bf16 h[8]; uint4 u; } r;
  float4 a = *(const float4*)p;
  float4 b = *(const float4*)(p + 4);
  r.h[0] = (bf16)a.x; r.h[1] = (bf16)a.y; r.h[2] = (bf16)a.z; r.h[3] = (bf16)a.w;
  r.h[4] = (bf16)b.x; r.h[5] = (bf16)b.y; r.h[6] = (bf16)b.z; r.h[7] = (bf16)b.w;
  return r.u;
}

// ---------------------------------------------------------------------------
// Generic MFMA GEMM: C[M x N] = epi(A[M x K] @ Bt[N x K]^T + bias)
// 128x128 tile, BK=32, 256 threads (4 waves, 2x2), z-batched.
// AMODE 0: bf16 A, async global_load_lds staging for A and B.
// AMODE 1: fp32 x (8,3000,128) zero-padded rows; register staging.
// AMODE 2: fp32 A converted in register staging.
// EPI: 0 tanh->Cf  1 bf16->Cb  2 Cf+=  4 gelu->Cb  5 row-remap -> Cf (d_out)
// ---------------------------------------------------------------------------
__global__ __launch_bounds__(256) void gemm_bt(
    const void* __restrict__ Avoid, const bf16* __restrict__ Bt,
    const float* __restrict__ bias, float* __restrict__ Cf, bf16* __restrict__ Cb,
    int K, int lda, int ldb, int ldc, int EPI, int AMODE,
    long aBatch, long bBatch, int zdiv, long cOuter, long cInner) {
  __shared__ __align__(16) bf16 As[128 * 32];
  __shared__ __align__(16) bf16 Bs[128 * 32];
  const int tid = threadIdx.x;
  const int bz = blockIdx.z;
  Bt += (long)bz * bBatch;
  const long cOff = (long)(bz / zdiv) * cOuter + (long)(bz % zdiv) * cInner;
  const int row0 = blockIdx.y * 128;
  const int col0 = blockIdx.x * 128;
  const int lane = tid & 63, wid = tid >> 6;
  const int wm = (wid & 1) * 64, wn = (wid >> 1) * 64;
  const int lr = lane & 15, lk = (lane >> 4) * 8;

  floatx4 acc[4][4];
#pragma unroll
  for (int i = 0; i < 4; i++)
#pragma unroll
    for (int j = 0; j < 4; j++) acc[i][j] = {0.f, 0.f, 0.f, 0.f};

  if (AMODE == 0) {
    // ---- async staging path ----
    const bf16* A = (const bf16*)Avoid + (long)bz * aBatch;
    const bf16* pAa = A + (long)(row0 + wid * 16 + (lane >> 2)) * lda + (lane & 3) * 8;
    const bf16* pBa = Bt + (long)(col0 + wid * 16 + (lane >> 2)) * ldb + (lane & 3) * 8;
    bf16* ldsA = &As[wid * 16 * 32];
    bf16* ldsB = &Bs[wid * 16 * 32];
    const long a64 = (long)64 * lda, b64 = (long)64 * ldb;
    for (int k0 = 0; k0 < K; k0 += 32) {
      __syncthreads();
      gload_lds16(pAa, ldsA);
      gload_lds16(pAa + a64, ldsA + 64 * 32);
      gload_lds16(pBa, ldsB);
      gload_lds16(pBa + b64, ldsB + 64 * 32);
      pAa += 32; pBa += 32;
      __syncthreads();
      short8 af[4], bfr[4];
#pragma unroll
      for (int mt = 0; mt < 4; mt++) af[mt] = *(const short8*)(&As[(wm + mt * 16 + lr) * 32 + lk]);
#pragma unroll
      for (int nt = 0; nt < 4; nt++) bfr[nt] = *(const short8*)(&Bs[(wn + nt * 16 + lr) * 32 + lk]);
#pragma unroll
      for (int mt = 0; mt < 4; mt++)
#pragma unroll
        for (int nt = 0; nt < 4; nt++)
          acc[mt][nt] = MFMA16(af[mt], bfr[nt], acc[mt][nt]);
    }
  } else {
    // ---- register staging path (fp32 A sources) ----
    const float* Af = (const float*)Avoid;
    const int srow = tid >> 2;
    const int skcol = (tid & 3) * 8;
    const long r0 = row0 + srow, r1 = r0 + 64;
    const bf16* pB = Bt + (long)(col0 + srow) * ldb + skcol;
    const int ldsOff = srow * 32 + skcol;
    const float* pF0; const float* pF1;
    bool v0 = true, v1 = true;
    if (AMODE == 1) {
      int t0 = (int)(r0 & (SEQ - 1)), t1 = (int)(r1 & (SEQ - 1));
      v0 = t0 < NREAL; v1 = t1 < NREAL;
      if (!v0) t0 = 0;
      if (!v1) t1 = 0;
      pF0 = Af + ((r0 >> 12) * NREAL + t0) * DINP + skcol;
      pF1 = Af + ((r1 >> 12) * NREAL + t1) * DINP + skcol;
    } else {
      pF0 = Af + r0 * lda + skcol;
      pF1 = Af + r1 * lda + skcol;
    }
    for (int k0 = 0; k0 < K; k0 += 32) {
      uint4 b0 = *(const uint4*)(pB);
      uint4 b1 = *(const uint4*)(pB + (long)64 * ldb);
      pB += 32;
      uint4 a0 = {0, 0, 0, 0}, a1 = {0, 0, 0, 0};
      if (v0) a0 = pack8(pF0);
      if (v1) a1 = pack8(pF1);
      pF0 += 32; pF1 += 32;
      __syncthreads();
      *(uint4*)(&As[ldsOff]) = a0;
      *(uint4*)(&As[ldsOff + 64 * 32]) = a1;
      *(uint4*)(&Bs[ldsOff]) = b0;
      *(uint4*)(&Bs[ldsOff + 64 * 32]) = b1;
      __syncthreads();
      short8 af[4], bfr[4];
#pragma unroll
      for (int mt = 0; mt < 4; mt++) af[mt] = *(const short8*)(&As[(wm + mt * 16 + lr) * 32 + lk]);
#pragma unroll
      for (int nt = 0; nt < 4; nt++) bfr[nt] = *(const short8*)(&Bs[(wn + nt * 16 + lr) * 32 + lk]);
#pragma unroll
      for (int mt = 0; mt < 4; mt++)
#pragma unroll
        for (int nt = 0; nt < 4; nt++)
          acc[mt][nt] = MFMA16(af[mt], bfr[nt], acc[mt][nt]);
    }
  }

  // D element (mt,nt,reg): row=(lane>>4)*4+reg, col=lane&15 within 16x16 tile
#pragma unroll
  for (int nt = 0; nt < 4; nt++) {
    int c = col0 + wn + nt * 16 + lr;
    float bv = 0.f;
    if (bias) {
      if (EPI == 5) { if (c < 64) bv = bias[c]; }
      else bv = bias[c];
    }
#pragma unroll
    for (int mt = 0; mt < 4; mt++) {
      long rb = row0 + wm + mt * 16 + (lane >> 4) * 4;
#pragma unroll
      for (int reg = 0; reg < 4; reg++) {
        float v = acc[mt][nt][reg] + bv;
        long ri = rb + reg;
        long idx = cOff + ri * (long)ldc + c;
        if (EPI == 0) Cf[idx] = tanhf(v);
        else if (EPI == 1) Cb[idx] = (bf16)v;
        else if (EPI == 2) Cf[idx] += v;
        else if (EPI == 4) { float g = 0.5f * v * (1.f + erff(v * 0.70710678118654752f)); Cb[idx] = (bf16)g; }
        else if (EPI == 5) {
          int bb = (int)(ri >> 12); int tt = (int)(ri & (SEQ - 1));
          if (tt < NREAL && c < 64) Cf[((long)bb * NREAL + tt) * 64 + c] = v;
        }
      }
    }
  }
}

// ---------------------------------------------------------------------------
// LayerNorm over 512 fp32 -> bf16. One wave per row, 4 rows per block.
// ---------------------------------------------------------------------------
__global__ __launch_bounds__(256) void ln_kernel(const float* __restrict__ h,
                                                 const float* __restrict__ g,
                                                 const float* __restrict__ bta,
                                                 bf16* __restrict__ out) {
  int wid = threadIdx.x >> 6, lane = threadIdx.x & 63;
  long row = (long)blockIdx.x * 4 + wid;
  const float* src = h + row * DM + lane * 8;
  float4 a = *(const float4*)(src);
  float4 b = *(const float4*)(src + 4);
  float x[8] = {a.x, a.y, a.z, a.w, b.x, b.y, b.z, b.w};
  float s = 0.f, sq = 0.f;
#pragma unroll
  for (int i = 0; i < 8; i++) { s += x[i]; sq += x[i] * x[i]; }
#pragma unroll
  for (int m = 32; m >= 1; m >>= 1) { s += __shfl_xor(s, m, 64); sq += __shfl_xor(sq, m, 64); }
  float mu = s * (1.f / DM);
  float var = sq * (1.f / DM) - mu * mu;
  float rstd = rsqrtf(var + 1e-5f);
  const float* gp = g + lane * 8;
  const float* bp = bta + lane * 8;
  bf16* dst = out + row * DM + lane * 8;
#pragma unroll
  for (int i = 0; i < 8; i++)
    dst[i] = (bf16)((x[i] - mu) * rstd * gp[i] + bp[i]);
}

// ---------------------------------------------------------------------------
// Local attention, head 0. Grid (2 halves, 32 windows, 2 local batches).
// ---------------------------------------------------------------------------
__global__ __launch_bounds__(256) void local_attn(const bf16* __restrict__ q,
                                                  const bf16* __restrict__ k,
                                                  const bf16* __restrict__ v,
                                                  bf16* __restrict__ att) {
  int half = blockIdx.x, w = blockIdx.y, b = blockIdx.z;
  int tid = threadIdx.x, wid = tid >> 6, lane = tid & 63;
  int lr = lane & 15, lq4 = lane >> 4;
  __shared__ __align__(16) bf16 Ks[32 * 128];   // [j][d]
  __shared__ __align__(16) bf16 Vts[128 * 32];  // [d][j]
  __shared__ __align__(16) bf16 Ps[4][16 * 32]; // per-wave P scratch

  int t0 = w * 128 + half * 64 + wid * 16;
  long qbase = ((long)b * SEQ + t0 + lr) * DM;
  short8 qf[4];
#pragma unroll
  for (int ks = 0; ks < 4; ks++) qf[ks] = *(const short8*)(q + qbase + ks * 32 + lq4 * 8);

  floatx4 Oacc[8];
#pragma unroll
  for (int i = 0; i < 8; i++) Oacc[i] = {0.f, 0.f, 0.f, 0.f};
  float rs[4] = {0.f, 0.f, 0.f, 0.f};

  int keystart = w * 128 - 128;
  for (int ch = 0; ch < 12; ch++) {
    int kb = keystart + ch * 32;
    if (kb < 0 || kb >= SEQ) continue;  // uniform per block
    {
      int j = tid >> 3, d = (tid & 7) * 16;
      const bf16* ksrc = k + ((long)b * SEQ + kb + j) * DM + d;
      *(uint4*)(&Ks[j * 128 + d]) = *(const uint4*)(ksrc);
      *(uint4*)(&Ks[j * 128 + d + 8]) = *(const uint4*)(ksrc + 8);
      const bf16* vsrc = v + ((long)b * SEQ + kb + j) * DM + d;
#pragma unroll
      for (int e = 0; e < 16; e++) Vts[(d + e) * 32 + j] = vsrc[e];
    }
    __syncthreads();
    floatx4 s0 = {0.f, 0.f, 0.f, 0.f}, s1 = {0.f, 0.f, 0.f, 0.f};
#pragma unroll
    for (int ks = 0; ks < 4; ks++) {
      short8 kf0 = *(const short8*)(&Ks[(0 + lr) * 128 + ks * 32 + lq4 * 8]);
      short8 kf1 = *(const short8*)(&Ks[(16 + lr) * 128 + ks * 32 + lq4 * 8]);
      s0 = MFMA16(qf[ks], kf0, s0);
      s1 = MFMA16(qf[ks], kf1, s1);
    }
#pragma unroll
    for (int reg = 0; reg < 4; reg++) {
      float e0 = __expf(s0[reg] * 0.08838834764831845f);
      float e1 = __expf(s1[reg] * 0.08838834764831845f);
      rs[reg] += e0 + e1;
      Ps[wid][(lq4 * 4 + reg) * 32 + lr] = (bf16)e0;
      Ps[wid][(lq4 * 4 + reg) * 32 + 16 + lr] = (bf16)e1;
    }
    __syncthreads();
    short8 pf = *(const short8*)(&Ps[wid][lr * 32 + lq4 * 8]);
#pragma unroll
    for (int nt = 0; nt < 8; nt++) {
      short8 vf = *(const short8*)(&Vts[(nt * 16 + lr) * 32 + lq4 * 8]);
      Oacc[nt] = MFMA16(pf, vf, Oacc[nt]);
    }
    __syncthreads();
  }
#pragma unroll
  for (int m = 1; m < 16; m <<= 1)
#pragma unroll
    for (int reg = 0; reg < 4; reg++) rs[reg] += __shfl_xor(rs[reg], m, 64);
  long obase = ((long)b * SEQ + t0 + lq4 * 4) * DM;
#pragma unroll
  for (int nt = 0; nt < 8; nt++)
#pragma unroll
    for (int reg = 0; reg < 4; reg++)
      att[obase + (long)reg * DM + nt * 16 + lr] = (bf16)(Oacc[nt][reg] / rs[reg]);
}

// ---------------------------------------------------------------------------
// Linear-attn q-softmax: qp[z6][t][128] = softmax(q_head)*d^-0.5
// ---------------------------------------------------------------------------
__global__ __launch_bounds__(256) void qp_softmax(const bf16* __restrict__ q, bf16* __restrict__ qp) {
  int wid = threadIdx.x >> 6, lane = threadIdx.x & 63;
  long task = (long)blockIdx.x * 4 + wid;  // < 24576
  int tt = (int)(task & (SEQ - 1));
  int z6 = (int)(task >> 12);
  int lb = z6 / 3, h2 = z6 % 3;
  const bf16* src = q + ((long)lb * SEQ + tt) * DM + (h2 + 1) * 128 + lane * 2;
  float x0 = (float)src[0], x1 = (float)src[1];
  float m = fmaxf(x0, x1);
#pragma unroll
  for (int s = 32; s >= 1; s >>= 1) m = fmaxf(m, __shfl_xor(m, s, 64));
  float e0 = __expf(x0 - m), e1 = __expf(x1 - m);
  float sm = e0 + e1;
#pragma unroll
  for (int s = 32; s >= 1; s >>= 1) sm += __shfl_xor(sm, s, 64);
  float inv = 0.08838834764831845f / sm;
  bf16* dst = qp + task * 128 + lane * 2;
  dst[0] = (bf16)(e0 * inv);
  dst[1] = (bf16)(e1 * inv);
}

// ---------------------------------------------------------------------------
// k column stats, phase 1: per-(z, 128-row chunk) column max and exp-sum.
// ---------------------------------------------------------------------------
__global__ __launch_bounds__(128) void kstats_part(const bf16* __restrict__ k,
                                                   float* __restrict__ part) {
  int chunk = blockIdx.x, z = blockIdx.y;
  int lb = z / 3, h2 = z % 3, ch = (h2 + 1) * 128;
  int d = threadIdx.x;
  const bf16* base = k + ((long)lb * SEQ + chunk * 128) * DM + ch + d;
  float m = -1e30f;
#pragma unroll 4
  for (int t = 0; t < 128; t++) m = fmaxf(m, (float)base[(long)t * DM]);
  float l = 0.f;
#pragma unroll 4
  for (int t = 0; t < 128; t++) l += __expf((float)base[(long)t * DM] - m);
  int idx = (z * 32 + chunk) * 128 + d;
  part[idx] = m;
  part[24576 + idx] = l;
}

// phase 2: combine 32 chunk stats -> kml[z*256+d]=M, +128=L
__global__ __launch_bounds__(128) void kstats_comb(const float* __restrict__ part,
                                                   float* __restrict__ kml) {
  int z = blockIdx.x, d = threadIdx.x;
  float M = -1e30f;
#pragma unroll 4
  for (int c = 0; c < 32; c++) M = fmaxf(M, part[(z * 32 + c) * 128 + d]);
  float L = 0.f;
#pragma unroll 4
  for (int c = 0; c < 32; c++) {
    int i = (z * 32 + c) * 128 + d;
    L += part[24576 + i] * __expf(part[i] - M);
  }
  kml[z * 256 + d] = M;
  kml[z * 256 + 128 + d] = L;
}

// ---------------------------------------------------------------------------
// ctx via MFMA: part[z][chunk][e*128+d] = sum_{t in 512-chunk} v[t][e]*k'[t][d]
// k' = exp(k - M - log L), fused into transposed LDS staging.
// Grid (8 chunks, 6 z), 256 thr (4 waves, 2x2 of 64x64).
// ---------------------------------------------------------------------------
__global__ __launch_bounds__(256) void ctx_mfma(const bf16* __restrict__ k,
                                                const bf16* __restrict__ v,
                                                const float* __restrict__ kml,
                                                float* __restrict__ part) {
  int chunk = blockIdx.x, z = blockIdx.y;
  int lb = z / 3, h2 = z % 3, ch = (h2 + 1) * 128;
  int tid = threadIdx.x, lane = tid & 63, wid = tid >> 6;
  const int wm = (wid & 1) * 64, wn = (wid >> 1) * 64;
  const int lr = lane & 15, lk = (lane >> 4) * 8;
  __shared__ float ml2[128];
  __shared__ __align__(16) bf16 Vt[128 * CS];   // Vt[e][j] = v[t0+j][e]
  __shared__ __align__(16) bf16 Kt[128 * CS];   // Kt[d][j] = exp(k[t0+j][d]-ml2[d])
  if (tid < 128)
    ml2[tid] = kml[z * 256 + tid] + logf(kml[z * 256 + 128 + tid]);

  int j = tid >> 3, d0 = (tid & 7) * 16;
  const bf16* vsrc = v + ((long)lb * SEQ + chunk * 512 + j) * DM + ch + d0;
  const bf16* ksrc = k + ((long)lb * SEQ + chunk * 512 + j) * DM + ch + d0;

  floatx4 acc[4][4];
#pragma unroll
  for (int i = 0; i < 4; i++)
#pragma unroll
    for (int jj = 0; jj < 4; jj++) acc[i][jj] = {0.f, 0.f, 0.f, 0.f};

  for (int s = 0; s < 16; s++) {
    union { bf16 h[16]; uint4 u[2]; } va, ka;
    va.u[0] = *(const uint4*)(vsrc); va.u[1] = *(const uint4*)(vsrc + 8);
    ka.u[0] = *(const uint4*)(ksrc); ka.u[1] = *(const uint4*)(ksrc + 8);
    vsrc += (long)32 * DM; ksrc += (long)32 * DM;
    __syncthreads();
#pragma unroll
    for (int e = 0; e < 16; e++) {
      Vt[(d0 + e) * CS + j] = va.h[e];
      Kt[(d0 + e) * CS + j] = (bf16)__expf((float)ka.h[e] - ml2[d0 + e]);
    }
    __syncthreads();
    short8 af[4], bfr[4];
#pragma unroll
    for (int mt = 0; mt < 4; mt++) af[mt] = *(const short8*)(&Vt[(wm + mt * 16 + lr) * CS + lk]);
#pragma unroll
    for (int nt = 0; nt < 4; nt++) bfr[nt] = *(const short8*)(&Kt[(wn + nt * 16 + lr) * CS + lk]);
#pragma unroll
    for (int mt = 0; mt < 4; mt++)
#pragma unroll
      for (int nt = 0; nt < 4; nt++)
        acc[mt][nt] = MFMA16(af[mt], bfr[nt], acc[mt][nt]);
  }

  float* dst = part + ((long)z * 8 + chunk) * 16384;
#pragma unroll
  for (int nt = 0; nt < 4; nt++) {
    int c = wn + nt * 16 + lr;
#pragma unroll
    for (int mt = 0; mt < 4; mt++) {
      int rb = wm + mt * 16 + (lane >> 4) * 4;
#pragma unroll
      for (int reg = 0; reg < 4; reg++)
        dst[(rb + reg) * 128 + c] = acc[mt][nt][reg];
    }
  }
}

__global__ __launch_bounds__(256) void ctx_reduce(const float* __restrict__ part, bf16* __restrict__ ctxT) {
  long i = (long)blockIdx.x * 256 + threadIdx.x;  // < 98304
  int z = (int)(i >> 14);
  int off = (int)(i & 16383);
  float s = 0.f;
#pragma unroll
  for (int c = 0; c < 8; c++) s += part[(((long)z * 8 + c) << 14) + off];
  ctxT[i] = (bf16)s;
}

// ---------------------------------------------------------------------------
extern "C" void kernel_launch(void* const* d_in, const int* in_sizes, int n_in,
                              void* d_out, int out_size, void* d_ws, size_t ws_size,
                              hipStream_t stream) {
  float* outp = (float*)d_out;
  if (ws_size < (size_t)WS_NEED) {
    beacon<<<(out_size + 255) / 256, 256, 0, stream>>>(outp, out_size);
    return;
  }

  const float* x   = (const float*)d_in[0];
  const float* W1  = (const float*)d_in[1];
  const float* b1  = (const float*)d_in[2];
  const float* g1  = (const float*)d_in[3];
  const float* be1 = (const float*)d_in[4];
  const float* Wq  = (const float*)d_in[5];
  const float* Wk  = (const float*)d_in[6];
  const float* Wv  = (const float*)d_in[7];
  const float* Wo  = (const float*)d_in[8];
  const float* bo  = (const float*)d_in[9];
  const float* g2  = (const float*)d_in[10];
  const float* be2 = (const float*)d_in[11];
  const float* Wf1 = (const float*)d_in[12];
  const float* bf1 = (const float*)d_in[13];
  const float* Wf2 = (const float*)d_in[14];
  const float* bf2 = (const float*)d_in[15];
  const float* W2  = (const float*)d_in[16];
  const float* b2  = (const float*)d_in[17];

  char* ws = (char*)d_ws;
  float* h   = (float*)(ws + OFF_H);
  bf16* lnG  = (bf16*)(ws + OFF_LNG);
  bf16* qb   = (bf16*)(ws + OFF_Q);
  bf16* kb   = (bf16*)(ws + OFF_K);
  bf16* vb   = (bf16*)(ws + OFF_V);
  bf16* attb = (bf16*)(ws + OFF_ATT);
  bf16* ff1g = (bf16*)(ws + OFF_Q);    // overlays Q..ATT (dead in FFN phase)
  bf16* qp   = (bf16*)(ws + OFF_QP);
  float* ctxp= (float*)(ws + OFF_CTXP);  // also kstats parts (before ctx_mfma)
  bf16* ctxT = (bf16*)(ws + OFF_CTXT);
  float* kml = (float*)(ws + OFF_KML);
  bf16* wt   = (bf16*)(ws + OFF_WT);
  bf16* wqt  = wt + 65536;
  bf16* wot  = wt + 851968;
  bf16* wf1t = wt + 1114112;
  bf16* wf2t = wt + 2162688;
  bf16* w2t  = wt + 3211264;

  // ---- all weight transposes (fp32 -> bf16, [Npad][K] K-contiguous) ----
  transpose8<<<dim3(32, 32, 8), 256, 0, stream>>>(W1, Wq, Wk, Wv, Wo, Wf1, Wf2, W2, wt);

  // ---- h = tanh(xpad @ W1 + b1) fp32; pad rows handled in A staging ----
  gemm_bt<<<dim3(4, 256, 1), 256, 0, stream>>>(x, wt, b1, h, nullptr,
      DINP, DINP, DINP, DM, 0, 1, 0, 0, 1, 0, 0);

  // ---- attention, 4 groups of 2 batches ----
  for (int g = 0; g < NGROUP; g++) {
    float* hg = h + (long)g * GROUPROWS * DM;
    ln_kernel<<<GROUPROWS / 4, 256, 0, stream>>>(hg, g1, be1, lnG);
    // Q,K,V in one z=3 batched launch
    gemm_bt<<<dim3(4, 64, 3), 256, 0, stream>>>(lnG, wqt, nullptr, nullptr, qb,
        DM, DM, DM, DM, 1, 0,
        0L, 262144L, 3, 0L, 4194304L);

    local_attn<<<dim3(2, 32, 2), 256, 0, stream>>>(qb, kb, vb, attb);

    qp_softmax<<<6144, 256, 0, stream>>>(qb, qp);
    kstats_part<<<dim3(32, 6), 128, 0, stream>>>(kb, ctxp);
    kstats_comb<<<6, 128, 0, stream>>>(ctxp, kml);
    ctx_mfma<<<dim3(8, 6), 256, 0, stream>>>(kb, vb, kml, ctxp);
    ctx_reduce<<<384, 256, 0, stream>>>(ctxp, ctxT);
    gemm_bt<<<dim3(1, 32, 6), 256, 0, stream>>>(qp, ctxT, nullptr, nullptr, attb + 128,
        128, 128, 128, DM, 1, 0,
        (long)SEQ * 128, 16384L, 3, (long)SEQ * DM, 128L);

    gemm_bt<<<dim3(4, 64, 1), 256, 0, stream>>>(attb, wot, bo, hg, nullptr,
        DM, DM, DM, DM, 2, 0, 0, 0, 1, 0, 0);
  }

  // ---- FFN, 4 groups ----
  for (int g = 0; g < NGROUP; g++) {
    float* hg = h + (long)g * GROUPROWS * DM;
    ln_kernel<<<GROUPROWS / 4, 256, 0, stream>>>(hg, g2, be2, lnG);
    gemm_bt<<<dim3(16, 64, 1), 256, 0, stream>>>(lnG, wf1t, bf1, nullptr, ff1g,
        DM, DM, DM, DFF, 4, 0, 0, 0, 1, 0, 0);
    gemm_bt<<<dim3(4, 64, 1), 256, 0, stream>>>(ff1g, wf2t, bf2, hg, nullptr,
        DFF, DFF, DFF, DM, 2, 0, 0, 0, 1, 0, 0);
  }

  // ---- out = (h @ W2 + b2)[:, :3000, :] -> d_out fp32 (h staged as bf16) ----
  gemm_bt<<<dim3(1, 256, 1), 256, 0, stream>>>(h, w2t, b2, outp, nullptr,
      DM, DM, DM, 64, 5, 2, 0, 0, 1, 0, 0);
}

// Round 7
// 1355.694 us; speedup vs baseline: 1.7374x; 1.0265x over previous
//
#include <hip/hip_runtime.h>
#include <hip/hip_bf16.h>
#include <math.h>

// ---------------------------------------------------------------------------
// Linear_Transformer on MI355X (gfx950). fp32 I/O, bf16 MFMA internals,
// fp32 residual stream.
// Round 7: BISECT of round-6 correctness regression (absmax 0.121). Round 6 =
// round 5 + (a) dbuf BK=64 async K-loop + (b) split-K/atomicAdd. This round
// keeps ONLY (b) on top of the byte-exact round-5 K-loop (single buffer,
// BK=32, two barriers — known good at 1392us). Pass => (a) was broken.
// Fail => (b) is broken.
// ---------------------------------------------------------------------------

typedef __hip_bfloat16 bf16;
typedef __attribute__((ext_vector_type(8))) short short8;   // 8 bf16 (MFMA A/B frag)
typedef __attribute__((ext_vector_type(4))) float floatx4;  // MFMA C/D frag

#define SEQ   4096
#define NBAT  8
#define DM    512
#define DINP  128
#define DFF   2048
#define NREAL 3000
#define GROUPROWS 8192        // 2 batches per group
#define NGROUP 4
#define CS    40              // ctx_mfma LDS stride (80B, 16B-aligned)

#define MFMA16(a,b,c) __builtin_amdgcn_mfma_f32_16x16x32_bf16((a),(b),(c),0,0,0)

// async global->LDS, 16B per lane, deposits at lds + lane*16
__device__ __forceinline__ void gload_lds16(const void* g, void* l) {
  auto* gp = reinterpret_cast<const __attribute__((address_space(1))) unsigned int*>(
      reinterpret_cast<uintptr_t>(g));
  auto* lp = reinterpret_cast<__attribute__((address_space(3))) unsigned int*>(
      reinterpret_cast<uintptr_t>(l));
  __builtin_amdgcn_global_load_lds(gp, lp, 16, 0, 0);
}

// ---------------- workspace arena (bytes), total 125,245,440 ----------------
#define OFF_H     0L            // h fp32 [32768][512]            67,108,864
#define OFF_LNG   67108864L     // LN out bf16 [8192][512]         8,388,608
#define OFF_Q     75497472L     // q bf16 [8192][512]; ff1g overlays Q..ATT
#define OFF_K     83886080L
#define OFF_V     92274688L
#define OFF_ATT   100663296L
#define OFF_QP    109051904L    // qp bf16 [6][4096][128]          6,291,456
#define OFF_CTXP  115343360L    // ctx partials f32; also kstats parts
#define OFF_CTXT  118489088L    // ctxT bf16 [6][16384]              196,608
#define OFF_KML   118685696L    // k col stats f32 [6][256]            6,144
#define OFF_WT    118691840L    // transposed bf16 weights         6,553,600
#define WS_NEED   125245440L

// ---------------------------------------------------------------------------
__global__ __launch_bounds__(256) void beacon(float* __restrict__ out, long n) {
  long i = (long)blockIdx.x * 256 + threadIdx.x;
  if (i < n) out[i] = 10000.f;
}

// ---------------------------------------------------------------------------
// All 8 weight transposes in one launch. Wt[n][k] = n<N ? (bf16)W[k][n] : 0
// ---------------------------------------------------------------------------
__global__ __launch_bounds__(256) void transpose8(
    const float* __restrict__ W1, const float* __restrict__ Wq,
    const float* __restrict__ Wk, const float* __restrict__ Wv,
    const float* __restrict__ Wo, const float* __restrict__ Wf1,
    const float* __restrict__ Wf2, const float* __restrict__ W2,
    bf16* __restrict__ wt) {
  const int Ks[8]   = {128, 512, 512, 512, 512, 512, 2048, 512};
  const int Ns[8]   = {512, 512, 512, 512, 512, 2048, 512, 64};
  const int Nps[8]  = {512, 512, 512, 512, 512, 2048, 512, 128};
  const long Ofs[8] = {0L, 65536L, 327680L, 589824L, 851968L, 1114112L, 2162688L, 3211264L};
  int zi = blockIdx.z;
  int K = Ks[zi], N = Ns[zi], Npad = Nps[zi];
  int k0 = blockIdx.x * 64, n0 = blockIdx.y * 64;
  if (k0 >= K || n0 >= Npad) return;
  const float* W = zi == 0 ? W1 : zi == 1 ? Wq : zi == 2 ? Wk : zi == 3 ? Wv
                 : zi == 4 ? Wo : zi == 5 ? Wf1 : zi == 6 ? Wf2 : W2;
  bf16* Wt = wt + Ofs[zi];
  __shared__ float t[64][65];
  int r = threadIdx.x >> 2, c = (threadIdx.x & 3) * 16;
#pragma unroll
  for (int i = 0; i < 16; i++) {
    int n = n0 + c + i;
    t[r][c + i] = (n < N) ? W[(long)(k0 + r) * N + n] : 0.f;
  }
  __syncthreads();
#pragma unroll
  for (int i = 0; i < 16; i++)
    Wt[(long)(n0 + r) * K + k0 + c + i] = (bf16)t[c + i][r];
}

// ---------------------------------------------------------------------------
__device__ inline uint4 pack8(const float* p) {
  union { bf16 h[8]; uint4 u; } r;
  float4 a = *(const float4*)p;
  float4 b = *(const float4*)(p + 4);
  r.h[0] = (bf16)a.x; r.h[1] = (bf16)a.y; r.h[2] = (bf16)a.z; r.h[3] = (bf16)a.w;
  r.h[4] = (bf16)b.x; r.h[5] = (bf16)b.y; r.h[6] = (bf16)b.z; r.h[7] = (bf16)b.w;
  return r.u;
}

// ---------------------------------------------------------------------------
// Generic MFMA GEMM: C[M x N] = epi(A[M x K] @ Bt[N x K]^T + bias)
// 128x128 tile, BK=32, 256 threads (4 waves, 2x2), z = batch*splitK.
// AMODE 0: bf16 A, async global_load_lds staging (round-5 known-good loop).
// AMODE 1: fp32 x (8,3000,128) zero-padded rows; register staging.
// AMODE 2: fp32 A converted in register staging.
// EPI: 0 tanh->Cf  1 bf16->Cb  2 Cf+=  4 gelu->Cb
//      5 row-remap -> Cf (d_out)  6 atomicAdd into Cf (split-K)
// ---------------------------------------------------------------------------
__global__ __launch_bounds__(256) void gemm_bt(
    const void* __restrict__ Avoid, const bf16* __restrict__ Bt,
    const float* __restrict__ bias, float* __restrict__ Cf, bf16* __restrict__ Cb,
    int K, int lda, int ldb, int ldc, int EPI, int AMODE, int splitK,
    long aBatch, long bBatch, int zdiv, long cOuter, long cInner) {
  __shared__ __align__(16) bf16 As[128 * 32];
  __shared__ __align__(16) bf16 Bs[128 * 32];
  const int tid = threadIdx.x;
  int bz = blockIdx.z;
  const int ks = bz % splitK; bz /= splitK;
  const int Kc = K / splitK;
  Bt += (long)bz * bBatch + (long)ks * Kc;
  const long cOff = (long)(bz / zdiv) * cOuter + (long)(bz % zdiv) * cInner;
  const int row0 = blockIdx.y * 128;
  const int col0 = blockIdx.x * 128;
  const int lane = tid & 63, wid = tid >> 6;
  const int wm = (wid & 1) * 64, wn = (wid >> 1) * 64;
  const int lr = lane & 15, lk = (lane >> 4) * 8;

  floatx4 acc[4][4];
#pragma unroll
  for (int i = 0; i < 4; i++)
#pragma unroll
    for (int j = 0; j < 4; j++) acc[i][j] = {0.f, 0.f, 0.f, 0.f};

  if (AMODE == 0) {
    // ---- round-5 async staging path (known good) ----
    const bf16* A = (const bf16*)Avoid + (long)bz * aBatch + (long)ks * Kc;
    const bf16* pAa = A + (long)(row0 + wid * 16 + (lane >> 2)) * lda + (lane & 3) * 8;
    const bf16* pBa = Bt + (long)(col0 + wid * 16 + (lane >> 2)) * ldb + (lane & 3) * 8;
    bf16* ldsA = &As[wid * 16 * 32];
    bf16* ldsB = &Bs[wid * 16 * 32];
    const long a64 = (long)64 * lda, b64 = (long)64 * ldb;
    for (int k0 = 0; k0 < Kc; k0 += 32) {
      __syncthreads();
      gload_lds16(pAa, ldsA);
      gload_lds16(pAa + a64, ldsA + 64 * 32);
      gload_lds16(pBa, ldsB);
      gload_lds16(pBa + b64, ldsB + 64 * 32);
      pAa += 32; pBa += 32;
      __syncthreads();
      short8 af[4], bfr[4];
#pragma unroll
      for (int mt = 0; mt < 4; mt++) af[mt] = *(const short8*)(&As[(wm + mt * 16 + lr) * 32 + lk]);
#pragma unroll
      for (int nt = 0; nt < 4; nt++) bfr[nt] = *(const short8*)(&Bs[(wn + nt * 16 + lr) * 32 + lk]);
#pragma unroll
      for (int mt = 0; mt < 4; mt++)
#pragma unroll
        for (int nt = 0; nt < 4; nt++)
          acc[mt][nt] = MFMA16(af[mt], bfr[nt], acc[mt][nt]);
    }
  } else {
    // ---- round-5 register staging path (fp32 A sources) ----
    const float* Af = (const float*)Avoid;
    const int srow = tid >> 2;
    const int skcol = (tid & 3) * 8;
    const long r0 = row0 + srow, r1 = r0 + 64;
    const bf16* pB = Bt + (long)(col0 + srow) * ldb + skcol;
    const int ldsOff = srow * 32 + skcol;
    const float* pF0; const float* pF1;
    bool v0 = true, v1 = true;
    if (AMODE == 1) {
      int t0 = (int)(r0 & (SEQ - 1)), t1 = (int)(r1 & (SEQ - 1));
      v0 = t0 < NREAL; v1 = t1 < NREAL;
      if (!v0) t0 = 0;
      if (!v1) t1 = 0;
      pF0 = Af + ((r0 >> 12) * NREAL + t0) * DINP + skcol;
      pF1 = Af + ((r1 >> 12) * NREAL + t1) * DINP + skcol;
    } else {
      pF0 = Af + r0 * lda + skcol;
      pF1 = Af + r1 * lda + skcol;
    }
    for (int k0 = 0; k0 < Kc; k0 += 32) {
      uint4 b0 = *(const uint4*)(pB);
      uint4 b1 = *(const uint4*)(pB + (long)64 * ldb);
      pB += 32;
      uint4 a0 = {0, 0, 0, 0}, a1 = {0, 0, 0, 0};
      if (v0) a0 = pack8(pF0);
      if (v1) a1 = pack8(pF1);
      pF0 += 32; pF1 += 32;
      __syncthreads();
      *(uint4*)(&As[ldsOff]) = a0;
      *(uint4*)(&As[ldsOff + 64 * 32]) = a1;
      *(uint4*)(&Bs[ldsOff]) = b0;
      *(uint4*)(&Bs[ldsOff + 64 * 32]) = b1;
      __syncthreads();
      short8 af[4], bfr[4];
#pragma unroll
      for (int mt = 0; mt < 4; mt++) af[mt] = *(const short8*)(&As[(wm + mt * 16 + lr) * 32 + lk]);
#pragma unroll
      for (int nt = 0; nt < 4; nt++) bfr[nt] = *(const short8*)(&Bs[(wn + nt * 16 + lr) * 32 + lk]);
#pragma unroll
      for (int mt = 0; mt < 4; mt++)
#pragma unroll
        for (int nt = 0; nt < 4; nt++)
          acc[mt][nt] = MFMA16(af[mt], bfr[nt], acc[mt][nt]);
    }
  }

  // D element (mt,nt,reg): row=(lane>>4)*4+reg, col=lane&15 within 16x16 tile
#pragma unroll
  for (int nt = 0; nt < 4; nt++) {
    int c = col0 + wn + nt * 16 + lr;
    float bv = 0.f;
    if (bias && ks == 0) {
      if (EPI == 5) { if (c < 64) bv = bias[c]; }
      else bv = bias[c];
    }
#pragma unroll
    for (int mt = 0; mt < 4; mt++) {
      long rb = row0 + wm + mt * 16 + (lane >> 4) * 4;
#pragma unroll
      for (int reg = 0; reg < 4; reg++) {
        float v = acc[mt][nt][reg] + bv;
        long ri = rb + reg;
        long idx = cOff + ri * (long)ldc + c;
        if (EPI == 0) Cf[idx] = tanhf(v);
        else if (EPI == 1) Cb[idx] = (bf16)v;
        else if (EPI == 2) Cf[idx] += v;
        else if (EPI == 4) { float g = 0.5f * v * (1.f + erff(v * 0.70710678118654752f)); Cb[idx] = (bf16)g; }
        else if (EPI == 5) {
          int bb = (int)(ri >> 12); int tt = (int)(ri & (SEQ - 1));
          if (tt < NREAL && c < 64) Cf[((long)bb * NREAL + tt) * 64 + c] = v;
        }
        else if (EPI == 6) atomicAdd(&Cf[idx], v);
      }
    }
  }
}

// ---------------------------------------------------------------------------
// LayerNorm over 512 fp32 -> bf16. One wave per row, 4 rows per block.
// ---------------------------------------------------------------------------
__global__ __launch_bounds__(256) void ln_kernel(const float* __restrict__ h,
                                                 const float* __restrict__ g,
                                                 const float* __restrict__ bta,
                                                 bf16* __restrict__ out) {
  int wid = threadIdx.x >> 6, lane = threadIdx.x & 63;
  long row = (long)blockIdx.x * 4 + wid;
  const float* src = h + row * DM + lane * 8;
  float4 a = *(const float4*)(src);
  float4 b = *(const float4*)(src + 4);
  float x[8] = {a.x, a.y, a.z, a.w, b.x, b.y, b.z, b.w};
  float s = 0.f, sq = 0.f;
#pragma unroll
  for (int i = 0; i < 8; i++) { s += x[i]; sq += x[i] * x[i]; }
#pragma unroll
  for (int m = 32; m >= 1; m >>= 1) { s += __shfl_xor(s, m, 64); sq += __shfl_xor(sq, m, 64); }
  float mu = s * (1.f / DM);
  float var = sq * (1.f / DM) - mu * mu;
  float rstd = rsqrtf(var + 1e-5f);
  const float* gp = g + lane * 8;
  const float* bp = bta + lane * 8;
  bf16* dst = out + row * DM + lane * 8;
#pragma unroll
  for (int i = 0; i < 8; i++)
    dst[i] = (bf16)((x[i] - mu) * rstd * gp[i] + bp[i]);
}

// ---------------------------------------------------------------------------
// Local attention, head 0. Grid (2 halves, 32 windows, 2 local batches).
// ---------------------------------------------------------------------------
__global__ __launch_bounds__(256) void local_attn(const bf16* __restrict__ q,
                                                  const bf16* __restrict__ k,
                                                  const bf16* __restrict__ v,
                                                  bf16* __restrict__ att) {
  int half = blockIdx.x, w = blockIdx.y, b = blockIdx.z;
  int tid = threadIdx.x, wid = tid >> 6, lane = tid & 63;
  int lr = lane & 15, lq4 = lane >> 4;
  __shared__ __align__(16) bf16 Ks[32 * 128];   // [j][d]
  __shared__ __align__(16) bf16 Vts[128 * 32];  // [d][j]
  __shared__ __align__(16) bf16 Ps[4][16 * 32]; // per-wave P scratch

  int t0 = w * 128 + half * 64 + wid * 16;
  long qbase = ((long)b * SEQ + t0 + lr) * DM;
  short8 qf[4];
#pragma unroll
  for (int ks = 0; ks < 4; ks++) qf[ks] = *(const short8*)(q + qbase + ks * 32 + lq4 * 8);

  floatx4 Oacc[8];
#pragma unroll
  for (int i = 0; i < 8; i++) Oacc[i] = {0.f, 0.f, 0.f, 0.f};
  float rs[4] = {0.f, 0.f, 0.f, 0.f};

  int keystart = w * 128 - 128;
  for (int ch = 0; ch < 12; ch++) {
    int kb = keystart + ch * 32;
    if (kb < 0 || kb >= SEQ) continue;  // uniform per block
    {
      int j = tid >> 3, d = (tid & 7) * 16;
      const bf16* ksrc = k + ((long)b * SEQ + kb + j) * DM + d;
      *(uint4*)(&Ks[j * 128 + d]) = *(const uint4*)(ksrc);
      *(uint4*)(&Ks[j * 128 + d + 8]) = *(const uint4*)(ksrc + 8);
      const bf16* vsrc = v + ((long)b * SEQ + kb + j) * DM + d;
#pragma unroll
      for (int e = 0; e < 16; e++) Vts[(d + e) * 32 + j] = vsrc[e];
    }
    __syncthreads();
    floatx4 s0 = {0.f, 0.f, 0.f, 0.f}, s1 = {0.f, 0.f, 0.f, 0.f};
#pragma unroll
    for (int ks = 0; ks < 4; ks++) {
      short8 kf0 = *(const short8*)(&Ks[(0 + lr) * 128 + ks * 32 + lq4 * 8]);
      short8 kf1 = *(const short8*)(&Ks[(16 + lr) * 128 + ks * 32 + lq4 * 8]);
      s0 = MFMA16(qf[ks], kf0, s0);
      s1 = MFMA16(qf[ks], kf1, s1);
    }
#pragma unroll
    for (int reg = 0; reg < 4; reg++) {
      float e0 = __expf(s0[reg] * 0.08838834764831845f);
      float e1 = __expf(s1[reg] * 0.08838834764831845f);
      rs[reg] += e0 + e1;
      Ps[wid][(lq4 * 4 + reg) * 32 + lr] = (bf16)e0;
      Ps[wid][(lq4 * 4 + reg) * 32 + 16 + lr] = (bf16)e1;
    }
    __syncthreads();
    short8 pf = *(const short8*)(&Ps[wid][lr * 32 + lq4 * 8]);
#pragma unroll
    for (int nt = 0; nt < 8; nt++) {
      short8 vf = *(const short8*)(&Vts[(nt * 16 + lr) * 32 + lq4 * 8]);
      Oacc[nt] = MFMA16(pf, vf, Oacc[nt]);
    }
    __syncthreads();
  }
#pragma unroll
  for (int m = 1; m < 16; m <<= 1)
#pragma unroll
    for (int reg = 0; reg < 4; reg++) rs[reg] += __shfl_xor(rs[reg], m, 64);
  long obase = ((long)b * SEQ + t0 + lq4 * 4) * DM;
#pragma unroll
  for (int nt = 0; nt < 8; nt++)
#pragma unroll
    for (int reg = 0; reg < 4; reg++)
      att[obase + (long)reg * DM + nt * 16 + lr] = (bf16)(Oacc[nt][reg] / rs[reg]);
}

// ---------------------------------------------------------------------------
// Linear-attn q-softmax: qp[z6][t][128] = softmax(q_head)*d^-0.5
// ---------------------------------------------------------------------------
__global__ __launch_bounds__(256) void qp_softmax(const bf16* __restrict__ q, bf16* __restrict__ qp) {
  int wid = threadIdx.x >> 6, lane = threadIdx.x & 63;
  long task = (long)blockIdx.x * 4 + wid;  // < 24576
  int tt = (int)(task & (SEQ - 1));
  int z6 = (int)(task >> 12);
  int lb = z6 / 3, h2 = z6 % 3;
  const bf16* src = q + ((long)lb * SEQ + tt) * DM + (h2 + 1) * 128 + lane * 2;
  float x0 = (float)src[0], x1 = (float)src[1];
  float m = fmaxf(x0, x1);
#pragma unroll
  for (int s = 32; s >= 1; s >>= 1) m = fmaxf(m, __shfl_xor(m, s, 64));
  float e0 = __expf(x0 - m), e1 = __expf(x1 - m);
  float sm = e0 + e1;
#pragma unroll
  for (int s = 32; s >= 1; s >>= 1) sm += __shfl_xor(sm, s, 64);
  float inv = 0.08838834764831845f / sm;
  bf16* dst = qp + task * 128 + lane * 2;
  dst[0] = (bf16)(e0 * inv);
  dst[1] = (bf16)(e1 * inv);
}

// ---------------------------------------------------------------------------
// k column stats, phase 1: per-(z, 128-row chunk) column max and exp-sum.
// ---------------------------------------------------------------------------
__global__ __launch_bounds__(128) void kstats_part(const bf16* __restrict__ k,
                                                   float* __restrict__ part) {
  int chunk = blockIdx.x, z = blockIdx.y;
  int lb = z / 3, h2 = z % 3, ch = (h2 + 1) * 128;
  int d = threadIdx.x;
  const bf16* base = k + ((long)lb * SEQ + chunk * 128) * DM + ch + d;
  float m = -1e30f;
#pragma unroll 4
  for (int t = 0; t < 128; t++) m = fmaxf(m, (float)base[(long)t * DM]);
  float l = 0.f;
#pragma unroll 4
  for (int t = 0; t < 128; t++) l += __expf((float)base[(long)t * DM] - m);
  int idx = (z * 32 + chunk) * 128 + d;
  part[idx] = m;
  part[24576 + idx] = l;
}

// phase 2: combine 32 chunk stats -> kml[z*256+d]=M, +128=L
__global__ __launch_bounds__(128) void kstats_comb(const float* __restrict__ part,
                                                   float* __restrict__ kml) {
  int z = blockIdx.x, d = threadIdx.x;
  float M = -1e30f;
#pragma unroll 4
  for (int c = 0; c < 32; c++) M = fmaxf(M, part[(z * 32 + c) * 128 + d]);
  float L = 0.f;
#pragma unroll 4
  for (int c = 0; c < 32; c++) {
    int i = (z * 32 + c) * 128 + d;
    L += part[24576 + i] * __expf(part[i] - M);
  }
  kml[z * 256 + d] = M;
  kml[z * 256 + 128 + d] = L;
}

// ---------------------------------------------------------------------------
// ctx via MFMA: part[z][chunk][e*128+d] = sum_{t in 512-chunk} v[t][e]*k'[t][d]
// ---------------------------------------------------------------------------
__global__ __launch_bounds__(256) void ctx_mfma(const bf16* __restrict__ k,
                                                const bf16* __restrict__ v,
                                                const float* __restrict__ kml,
                                                float* __restrict__ part) {
  int chunk = blockIdx.x, z = blockIdx.y;
  int lb = z / 3, h2 = z % 3, ch = (h2 + 1) * 128;
  int tid = threadIdx.x, lane = tid & 63, wid = tid >> 6;
  const int wm = (wid & 1) * 64, wn = (wid >> 1) * 64;
  const int lr = lane & 15, lk = (lane >> 4) * 8;
  __shared__ float ml2[128];
  __shared__ __align__(16) bf16 Vt[128 * CS];
  __shared__ __align__(16) bf16 Kt[128 * CS];
  if (tid < 128)
    ml2[tid] = kml[z * 256 + tid] + logf(kml[z * 256 + 128 + tid]);

  int j = tid >> 3, d0 = (tid & 7) * 16;
  const bf16* vsrc = v + ((long)lb * SEQ + chunk * 512 + j) * DM + ch + d0;
  const bf16* ksrc = k + ((long)lb * SEQ + chunk * 512 + j) * DM + ch + d0;

  floatx4 acc[4][4];
#pragma unroll
  for (int i = 0; i < 4; i++)
#pragma unroll
    for (int jj = 0; jj < 4; jj++) acc[i][jj] = {0.f, 0.f, 0.f, 0.f};

  for (int s = 0; s < 16; s++) {
    union { bf16 h[16]; uint4 u[2]; } va, ka;
    va.u[0] = *(const uint4*)(vsrc); va.u[1] = *(const uint4*)(vsrc + 8);
    ka.u[0] = *(const uint4*)(ksrc); ka.u[1] = *(const uint4*)(ksrc + 8);
    vsrc += (long)32 * DM; ksrc += (long)32 * DM;
    __syncthreads();
#pragma unroll
    for (int e = 0; e < 16; e++) {
      Vt[(d0 + e) * CS + j] = va.h[e];
      Kt[(d0 + e) * CS + j] = (bf16)__expf((float)ka.h[e] - ml2[d0 + e]);
    }
    __syncthreads();
    short8 af[4], bfr[4];
#pragma unroll
    for (int mt = 0; mt < 4; mt++) af[mt] = *(const short8*)(&Vt[(wm + mt * 16 + lr) * CS + lk]);
#pragma unroll
    for (int nt = 0; nt < 4; nt++) bfr[nt] = *(const short8*)(&Kt[(wn + nt * 16 + lr) * CS + lk]);
#pragma unroll
    for (int mt = 0; mt < 4; mt++)
#pragma unroll
      for (int nt = 0; nt < 4; nt++)
        acc[mt][nt] = MFMA16(af[mt], bfr[nt], acc[mt][nt]);
  }

  float* dst = part + ((long)z * 8 + chunk) * 16384;
#pragma unroll
  for (int nt = 0; nt < 4; nt++) {
    int c = wn + nt * 16 + lr;
#pragma unroll
    for (int mt = 0; mt < 4; mt++) {
      int rb = wm + mt * 16 + (lane >> 4) * 4;
#pragma unroll
      for (int reg = 0; reg < 4; reg++)
        dst[(rb + reg) * 128 + c] = acc[mt][nt][reg];
    }
  }
}

__global__ __launch_bounds__(256) void ctx_reduce(const float* __restrict__ part, bf16* __restrict__ ctxT) {
  long i = (long)blockIdx.x * 256 + threadIdx.x;  // < 98304
  int z = (int)(i >> 14);
  int off = (int)(i & 16383);
  float s = 0.f;
#pragma unroll
  for (int c = 0; c < 8; c++) s += part[(((long)z * 8 + c) << 14) + off];
  ctxT[i] = (bf16)s;
}

// ---------------------------------------------------------------------------
extern "C" void kernel_launch(void* const* d_in, const int* in_sizes, int n_in,
                              void* d_out, int out_size, void* d_ws, size_t ws_size,
                              hipStream_t stream) {
  float* outp = (float*)d_out;
  if (ws_size < (size_t)WS_NEED) {
    beacon<<<(out_size + 255) / 256, 256, 0, stream>>>(outp, out_size);
    return;
  }

  const float* x   = (const float*)d_in[0];
  const float* W1  = (const float*)d_in[1];
  const float* b1  = (const float*)d_in[2];
  const float* g1  = (const float*)d_in[3];
  const float* be1 = (const float*)d_in[4];
  const float* Wq  = (const float*)d_in[5];
  const float* Wk  = (const float*)d_in[6];
  const float* Wv  = (const float*)d_in[7];
  const float* Wo  = (const float*)d_in[8];
  const float* bo  = (const float*)d_in[9];
  const float* g2  = (const float*)d_in[10];
  const float* be2 = (const float*)d_in[11];
  const float* Wf1 = (const float*)d_in[12];
  const float* bf1 = (const float*)d_in[13];
  const float* Wf2 = (const float*)d_in[14];
  const float* bf2 = (const float*)d_in[15];
  const float* W2  = (const float*)d_in[16];
  const float* b2  = (const float*)d_in[17];

  char* ws = (char*)d_ws;
  float* h   = (float*)(ws + OFF_H);
  bf16* lnG  = (bf16*)(ws + OFF_LNG);
  bf16* qb   = (bf16*)(ws + OFF_Q);
  bf16* kb   = (bf16*)(ws + OFF_K);
  bf16* vb   = (bf16*)(ws + OFF_V);
  bf16* attb = (bf16*)(ws + OFF_ATT);
  bf16* ff1g = (bf16*)(ws + OFF_Q);    // overlays Q..ATT (dead in FFN phase)
  bf16* qp   = (bf16*)(ws + OFF_QP);
  float* ctxp= (float*)(ws + OFF_CTXP);
  bf16* ctxT = (bf16*)(ws + OFF_CTXT);
  float* kml = (float*)(ws + OFF_KML);
  bf16* wt   = (bf16*)(ws + OFF_WT);
  bf16* wqt  = wt + 65536;
  bf16* wot  = wt + 851968;
  bf16* wf1t = wt + 1114112;
  bf16* wf2t = wt + 2162688;
  bf16* w2t  = wt + 3211264;

  // ---- all weight transposes (fp32 -> bf16, [Npad][K] K-contiguous) ----
  transpose8<<<dim3(32, 32, 8), 256, 0, stream>>>(W1, Wq, Wk, Wv, Wo, Wf1, Wf2, W2, wt);

  // ---- h = tanh(xpad @ W1 + b1) fp32; pad rows handled in A staging ----
  gemm_bt<<<dim3(4, 256, 1), 256, 0, stream>>>(x, wt, b1, h, nullptr,
      DINP, DINP, DINP, DM, 0, 1, 1, 0, 0, 1, 0, 0);

  // ---- attention, 4 groups of 2 batches ----
  for (int g = 0; g < NGROUP; g++) {
    float* hg = h + (long)g * GROUPROWS * DM;
    ln_kernel<<<GROUPROWS / 4, 256, 0, stream>>>(hg, g1, be1, lnG);
    // Q,K,V in one z=3 batched launch
    gemm_bt<<<dim3(4, 64, 3), 256, 0, stream>>>(lnG, wqt, nullptr, nullptr, qb,
        DM, DM, DM, DM, 1, 0, 1,
        0L, 262144L, 3, 0L, 4194304L);

    local_attn<<<dim3(2, 32, 2), 256, 0, stream>>>(qb, kb, vb, attb);

    qp_softmax<<<6144, 256, 0, stream>>>(qb, qp);
    kstats_part<<<dim3(32, 6), 128, 0, stream>>>(kb, ctxp);
    kstats_comb<<<6, 128, 0, stream>>>(ctxp, kml);
    ctx_mfma<<<dim3(8, 6), 256, 0, stream>>>(kb, vb, kml, ctxp);
    ctx_reduce<<<384, 256, 0, stream>>>(ctxp, ctxT);
    gemm_bt<<<dim3(1, 32, 6), 256, 0, stream>>>(qp, ctxT, nullptr, nullptr, attb + 128,
        128, 128, 128, DM, 1, 0, 1,
        (long)SEQ * 128, 16384L, 3, (long)SEQ * DM, 128L);

    // h += attn @ Wo + bo : split-K=2 (atomicAdd epilogue, 512 blocks)
    gemm_bt<<<dim3(4, 64, 2), 256, 0, stream>>>(attb, wot, bo, hg, nullptr,
        DM, DM, DM, DM, 6, 0, 2, 0, 0, 1, 0, 0);
  }

  // ---- FFN, 4 groups ----
  for (int g = 0; g < NGROUP; g++) {
    float* hg = h + (long)g * GROUPROWS * DM;
    ln_kernel<<<GROUPROWS / 4, 256, 0, stream>>>(hg, g2, be2, lnG);
    gemm_bt<<<dim3(16, 64, 1), 256, 0, stream>>>(lnG, wf1t, bf1, nullptr, ff1g,
        DM, DM, DM, DFF, 4, 0, 1, 0, 0, 1, 0, 0);
    // h += gelu(ff1) @ Wf2 + bf2 : split-K=2
    gemm_bt<<<dim3(4, 64, 2), 256, 0, stream>>>(ff1g, wf2t, bf2, hg, nullptr,
        DFF, DFF, DFF, DM, 6, 0, 2, 0, 0, 1, 0, 0);
  }

  // ---- out = (h @ W2 + b2)[:, :3000, :] -> d_out fp32 (h staged as bf16) ----
  gemm_bt<<<dim3(1, 256, 1), 256, 0, stream>>>(h, w2t, b2, outp, nullptr,
      DM, DM, DM, 64, 5, 2, 1, 0, 0, 1, 0, 0);
}

// Round 8
// 1277.135 us; speedup vs baseline: 1.8443x; 1.0615x over previous
//
#include <hip/hip_runtime.h>
#include <hip/hip_bf16.h>
#include <math.h>

// ---------------------------------------------------------------------------
// Linear_Transformer on MI355X (gfx950). fp32 I/O, bf16 MFMA internals,
// fp32 residual stream.
// Round 8: round-7 bisect cleared split-K math but showed atomicAdd write
// amplification (WRITE 87MB vs 16.8MB output, ~47us of the 62us FF2 dispatch).
// Replace split-K+atomics for FF2/attn-out with gemm_bt64: 64x128 tile ->
// 512 blocks (2/CU), block owns its rows, plain += epilogue, full K.
// K-loop stays the round-5 known-good two-barrier async structure.
// ---------------------------------------------------------------------------

typedef __hip_bfloat16 bf16;
typedef __attribute__((ext_vector_type(8))) short short8;   // 8 bf16 (MFMA A/B frag)
typedef __attribute__((ext_vector_type(4))) float floatx4;  // MFMA C/D frag

#define SEQ   4096
#define NBAT  8
#define DM    512
#define DINP  128
#define DFF   2048
#define NREAL 3000
#define GROUPROWS 8192        // 2 batches per group
#define NGROUP 4
#define CS    40              // ctx_mfma LDS stride (80B, 16B-aligned)

#define MFMA16(a,b,c) __builtin_amdgcn_mfma_f32_16x16x32_bf16((a),(b),(c),0,0,0)

// async global->LDS, 16B per lane, deposits at lds + lane*16
__device__ __forceinline__ void gload_lds16(const void* g, void* l) {
  auto* gp = reinterpret_cast<const __attribute__((address_space(1))) unsigned int*>(
      reinterpret_cast<uintptr_t>(g));
  auto* lp = reinterpret_cast<__attribute__((address_space(3))) unsigned int*>(
      reinterpret_cast<uintptr_t>(l));
  __builtin_amdgcn_global_load_lds(gp, lp, 16, 0, 0);
}

// ---------------- workspace arena (bytes), total 125,245,440 ----------------
#define OFF_H     0L            // h fp32 [32768][512]            67,108,864
#define OFF_LNG   67108864L     // LN out bf16 [8192][512]         8,388,608
#define OFF_Q     75497472L     // q bf16 [8192][512]; ff1g overlays Q..ATT
#define OFF_K     83886080L
#define OFF_V     92274688L
#define OFF_ATT   100663296L
#define OFF_QP    109051904L    // qp bf16 [6][4096][128]          6,291,456
#define OFF_CTXP  115343360L    // ctx partials f32; also kstats parts
#define OFF_CTXT  118489088L    // ctxT bf16 [6][16384]              196,608
#define OFF_KML   118685696L    // k col stats f32 [6][256]            6,144
#define OFF_WT    118691840L    // transposed bf16 weights         6,553,600
#define WS_NEED   125245440L

// ---------------------------------------------------------------------------
__global__ __launch_bounds__(256) void beacon(float* __restrict__ out, long n) {
  long i = (long)blockIdx.x * 256 + threadIdx.x;
  if (i < n) out[i] = 10000.f;
}

// ---------------------------------------------------------------------------
// All 8 weight transposes in one launch. Wt[n][k] = n<N ? (bf16)W[k][n] : 0
// ---------------------------------------------------------------------------
__global__ __launch_bounds__(256) void transpose8(
    const float* __restrict__ W1, const float* __restrict__ Wq,
    const float* __restrict__ Wk, const float* __restrict__ Wv,
    const float* __restrict__ Wo, const float* __restrict__ Wf1,
    const float* __restrict__ Wf2, const float* __restrict__ W2,
    bf16* __restrict__ wt) {
  const int Ks[8]   = {128, 512, 512, 512, 512, 512, 2048, 512};
  const int Ns[8]   = {512, 512, 512, 512, 512, 2048, 512, 64};
  const int Nps[8]  = {512, 512, 512, 512, 512, 2048, 512, 128};
  const long Ofs[8] = {0L, 65536L, 327680L, 589824L, 851968L, 1114112L, 2162688L, 3211264L};
  int zi = blockIdx.z;
  int K = Ks[zi], N = Ns[zi], Npad = Nps[zi];
  int k0 = blockIdx.x * 64, n0 = blockIdx.y * 64;
  if (k0 >= K || n0 >= Npad) return;
  const float* W = zi == 0 ? W1 : zi == 1 ? Wq : zi == 2 ? Wk : zi == 3 ? Wv
                 : zi == 4 ? Wo : zi == 5 ? Wf1 : zi == 6 ? Wf2 : W2;
  bf16* Wt = wt + Ofs[zi];
  __shared__ float t[64][65];
  int r = threadIdx.x >> 2, c = (threadIdx.x & 3) * 16;
#pragma unroll
  for (int i = 0; i < 16; i++) {
    int n = n0 + c + i;
    t[r][c + i] = (n < N) ? W[(long)(k0 + r) * N + n] : 0.f;
  }
  __syncthreads();
#pragma unroll
  for (int i = 0; i < 16; i++)
    Wt[(long)(n0 + r) * K + k0 + c + i] = (bf16)t[c + i][r];
}

// ---------------------------------------------------------------------------
__device__ inline uint4 pack8(const float* p) {
  union { bf16 h[8]; uint4 u; } r;
  float4 a = *(const float4*)p;
  float4 b = *(const float4*)(p + 4);
  r.h[0] = (bf16)a.x; r.h[1] = (bf16)a.y; r.h[2] = (bf16)a.z; r.h[3] = (bf16)a.w;
  r.h[4] = (bf16)b.x; r.h[5] = (bf16)b.y; r.h[6] = (bf16)b.z; r.h[7] = (bf16)b.w;
  return r.u;
}

// ---------------------------------------------------------------------------
// Generic MFMA GEMM: C[M x N] = epi(A[M x K] @ Bt[N x K]^T + bias)
// 128x128 tile, BK=32, 256 threads (4 waves, 2x2), z-batched.
// AMODE 0: bf16 A, async global_load_lds staging (round-5 known-good loop).
// AMODE 1: fp32 x (8,3000,128) zero-padded rows; register staging.
// AMODE 2: fp32 A converted in register staging.
// EPI: 0 tanh->Cf  1 bf16->Cb  2 Cf+=  4 gelu->Cb  5 row-remap -> Cf (d_out)
// ---------------------------------------------------------------------------
__global__ __launch_bounds__(256) void gemm_bt(
    const void* __restrict__ Avoid, const bf16* __restrict__ Bt,
    const float* __restrict__ bias, float* __restrict__ Cf, bf16* __restrict__ Cb,
    int K, int lda, int ldb, int ldc, int EPI, int AMODE,
    long aBatch, long bBatch, int zdiv, long cOuter, long cInner) {
  __shared__ __align__(16) bf16 As[128 * 32];
  __shared__ __align__(16) bf16 Bs[128 * 32];
  const int tid = threadIdx.x;
  const int bz = blockIdx.z;
  Bt += (long)bz * bBatch;
  const long cOff = (long)(bz / zdiv) * cOuter + (long)(bz % zdiv) * cInner;
  const int row0 = blockIdx.y * 128;
  const int col0 = blockIdx.x * 128;
  const int lane = tid & 63, wid = tid >> 6;
  const int wm = (wid & 1) * 64, wn = (wid >> 1) * 64;
  const int lr = lane & 15, lk = (lane >> 4) * 8;

  floatx4 acc[4][4];
#pragma unroll
  for (int i = 0; i < 4; i++)
#pragma unroll
    for (int j = 0; j < 4; j++) acc[i][j] = {0.f, 0.f, 0.f, 0.f};

  if (AMODE == 0) {
    // ---- round-5 async staging path (known good) ----
    const bf16* A = (const bf16*)Avoid + (long)bz * aBatch;
    const bf16* pAa = A + (long)(row0 + wid * 16 + (lane >> 2)) * lda + (lane & 3) * 8;
    const bf16* pBa = Bt + (long)(col0 + wid * 16 + (lane >> 2)) * ldb + (lane & 3) * 8;
    bf16* ldsA = &As[wid * 16 * 32];
    bf16* ldsB = &Bs[wid * 16 * 32];
    const long a64 = (long)64 * lda, b64 = (long)64 * ldb;
    for (int k0 = 0; k0 < K; k0 += 32) {
      __syncthreads();
      gload_lds16(pAa, ldsA);
      gload_lds16(pAa + a64, ldsA + 64 * 32);
      gload_lds16(pBa, ldsB);
      gload_lds16(pBa + b64, ldsB + 64 * 32);
      pAa += 32; pBa += 32;
      __syncthreads();
      short8 af[4], bfr[4];
#pragma unroll
      for (int mt = 0; mt < 4; mt++) af[mt] = *(const short8*)(&As[(wm + mt * 16 + lr) * 32 + lk]);
#pragma unroll
      for (int nt = 0; nt < 4; nt++) bfr[nt] = *(const short8*)(&Bs[(wn + nt * 16 + lr) * 32 + lk]);
#pragma unroll
      for (int mt = 0; mt < 4; mt++)
#pragma unroll
        for (int nt = 0; nt < 4; nt++)
          acc[mt][nt] = MFMA16(af[mt], bfr[nt], acc[mt][nt]);
    }
  } else {
    // ---- register staging path (fp32 A sources) ----
    const float* Af = (const float*)Avoid;
    const int srow = tid >> 2;
    const int skcol = (tid & 3) * 8;
    const long r0 = row0 + srow, r1 = r0 + 64;
    const bf16* pB = Bt + (long)(col0 + srow) * ldb + skcol;
    const int ldsOff = srow * 32 + skcol;
    const float* pF0; const float* pF1;
    bool v0 = true, v1 = true;
    if (AMODE == 1) {
      int t0 = (int)(r0 & (SEQ - 1)), t1 = (int)(r1 & (SEQ - 1));
      v0 = t0 < NREAL; v1 = t1 < NREAL;
      if (!v0) t0 = 0;
      if (!v1) t1 = 0;
      pF0 = Af + ((r0 >> 12) * NREAL + t0) * DINP + skcol;
      pF1 = Af + ((r1 >> 12) * NREAL + t1) * DINP + skcol;
    } else {
      pF0 = Af + r0 * lda + skcol;
      pF1 = Af + r1 * lda + skcol;
    }
    for (int k0 = 0; k0 < K; k0 += 32) {
      uint4 b0 = *(const uint4*)(pB);
      uint4 b1 = *(const uint4*)(pB + (long)64 * ldb);
      pB += 32;
      uint4 a0 = {0, 0, 0, 0}, a1 = {0, 0, 0, 0};
      if (v0) a0 = pack8(pF0);
      if (v1) a1 = pack8(pF1);
      pF0 += 32; pF1 += 32;
      __syncthreads();
      *(uint4*)(&As[ldsOff]) = a0;
      *(uint4*)(&As[ldsOff + 64 * 32]) = a1;
      *(uint4*)(&Bs[ldsOff]) = b0;
      *(uint4*)(&Bs[ldsOff + 64 * 32]) = b1;
      __syncthreads();
      short8 af[4], bfr[4];
#pragma unroll
      for (int mt = 0; mt < 4; mt++) af[mt] = *(const short8*)(&As[(wm + mt * 16 + lr) * 32 + lk]);
#pragma unroll
      for (int nt = 0; nt < 4; nt++) bfr[nt] = *(const short8*)(&Bs[(wn + nt * 16 + lr) * 32 + lk]);
#pragma unroll
      for (int mt = 0; mt < 4; mt++)
#pragma unroll
        for (int nt = 0; nt < 4; nt++)
          acc[mt][nt] = MFMA16(af[mt], bfr[nt], acc[mt][nt]);
    }
  }

  // D element (mt,nt,reg): row=(lane>>4)*4+reg, col=lane&15 within 16x16 tile
#pragma unroll
  for (int nt = 0; nt < 4; nt++) {
    int c = col0 + wn + nt * 16 + lr;
    float bv = 0.f;
    if (bias) {
      if (EPI == 5) { if (c < 64) bv = bias[c]; }
      else bv = bias[c];
    }
#pragma unroll
    for (int mt = 0; mt < 4; mt++) {
      long rb = row0 + wm + mt * 16 + (lane >> 4) * 4;
#pragma unroll
      for (int reg = 0; reg < 4; reg++) {
        float v = acc[mt][nt][reg] + bv;
        long ri = rb + reg;
        long idx = cOff + ri * (long)ldc + c;
        if (EPI == 0) Cf[idx] = tanhf(v);
        else if (EPI == 1) Cb[idx] = (bf16)v;
        else if (EPI == 2) Cf[idx] += v;
        else if (EPI == 4) { float g = 0.5f * v * (1.f + erff(v * 0.70710678118654752f)); Cb[idx] = (bf16)g; }
        else if (EPI == 5) {
          int bb = (int)(ri >> 12); int tt = (int)(ri & (SEQ - 1));
          if (tt < NREAL && c < 64) Cf[((long)bb * NREAL + tt) * 64 + c] = v;
        }
      }
    }
  }
}

// ---------------------------------------------------------------------------
// 64x128-tile MFMA GEMM, residual accumulate: Cf[M x N] += A @ Bt^T + bias.
// 512 blocks for M=8192,N=512 (2 blocks/CU), no atomics (block owns rows).
// 4 waves as 2x2 over (64 rows, 128 cols); wave tile 32x64 = 2x4 frags.
// Same two-barrier async K-loop as gemm_bt AMODE 0 (known good).
// ---------------------------------------------------------------------------
__global__ __launch_bounds__(256) void gemm_bt64(
    const bf16* __restrict__ A, const bf16* __restrict__ Bt,
    const float* __restrict__ bias, float* __restrict__ Cf,
    int K, int lda, int ldb, int ldc) {
  __shared__ __align__(16) bf16 As[64 * 32];
  __shared__ __align__(16) bf16 Bs[128 * 32];
  const int tid = threadIdx.x;
  const int row0 = blockIdx.y * 64;
  const int col0 = blockIdx.x * 128;
  const int lane = tid & 63, wid = tid >> 6;
  const int wm = (wid & 1) * 32, wn = (wid >> 1) * 64;
  const int lr = lane & 15, lk = (lane >> 4) * 8;

  floatx4 acc[2][4];
#pragma unroll
  for (int i = 0; i < 2; i++)
#pragma unroll
    for (int j = 0; j < 4; j++) acc[i][j] = {0.f, 0.f, 0.f, 0.f};

  // staging: wave w covers A rows [w*16, w*16+16) and B rows [w*16,..)+[w*16+64,..)
  const bf16* pAa = A + (long)(row0 + wid * 16 + (lane >> 2)) * lda + (lane & 3) * 8;
  const bf16* pBa = Bt + (long)(col0 + wid * 16 + (lane >> 2)) * ldb + (lane & 3) * 8;
  bf16* ldsA = &As[wid * 16 * 32];
  bf16* ldsB = &Bs[wid * 16 * 32];
  const long b64 = (long)64 * ldb;
  for (int k0 = 0; k0 < K; k0 += 32) {
    __syncthreads();
    gload_lds16(pAa, ldsA);
    gload_lds16(pBa, ldsB);
    gload_lds16(pBa + b64, ldsB + 64 * 32);
    pAa += 32; pBa += 32;
    __syncthreads();
    short8 af[2], bfr[4];
#pragma unroll
    for (int mt = 0; mt < 2; mt++) af[mt] = *(const short8*)(&As[(wm + mt * 16 + lr) * 32 + lk]);
#pragma unroll
    for (int nt = 0; nt < 4; nt++) bfr[nt] = *(const short8*)(&Bs[(wn + nt * 16 + lr) * 32 + lk]);
#pragma unroll
    for (int mt = 0; mt < 2; mt++)
#pragma unroll
      for (int nt = 0; nt < 4; nt++)
        acc[mt][nt] = MFMA16(af[mt], bfr[nt], acc[mt][nt]);
  }

#pragma unroll
  for (int nt = 0; nt < 4; nt++) {
    int c = col0 + wn + nt * 16 + lr;
    float bv = bias ? bias[c] : 0.f;
#pragma unroll
    for (int mt = 0; mt < 2; mt++) {
      long rb = row0 + wm + mt * 16 + (lane >> 4) * 4;
#pragma unroll
      for (int reg = 0; reg < 4; reg++)
        Cf[(rb + reg) * (long)ldc + c] += acc[mt][nt][reg] + bv;
    }
  }
}

// ---------------------------------------------------------------------------
// LayerNorm over 512 fp32 -> bf16. One wave per row, 4 rows per block.
// ---------------------------------------------------------------------------
__global__ __launch_bounds__(256) void ln_kernel(const float* __restrict__ h,
                                                 const float* __restrict__ g,
                                                 const float* __restrict__ bta,
                                                 bf16* __restrict__ out) {
  int wid = threadIdx.x >> 6, lane = threadIdx.x & 63;
  long row = (long)blockIdx.x * 4 + wid;
  const float* src = h + row * DM + lane * 8;
  float4 a = *(const float4*)(src);
  float4 b = *(const float4*)(src + 4);
  float x[8] = {a.x, a.y, a.z, a.w, b.x, b.y, b.z, b.w};
  float s = 0.f, sq = 0.f;
#pragma unroll
  for (int i = 0; i < 8; i++) { s += x[i]; sq += x[i] * x[i]; }
#pragma unroll
  for (int m = 32; m >= 1; m >>= 1) { s += __shfl_xor(s, m, 64); sq += __shfl_xor(sq, m, 64); }
  float mu = s * (1.f / DM);
  float var = sq * (1.f / DM) - mu * mu;
  float rstd = rsqrtf(var + 1e-5f);
  const float* gp = g + lane * 8;
  const float* bp = bta + lane * 8;
  bf16* dst = out + row * DM + lane * 8;
#pragma unroll
  for (int i = 0; i < 8; i++)
    dst[i] = (bf16)((x[i] - mu) * rstd * gp[i] + bp[i]);
}

// ---------------------------------------------------------------------------
// Local attention, head 0. Grid (2 halves, 32 windows, 2 local batches).
// ---------------------------------------------------------------------------
__global__ __launch_bounds__(256) void local_attn(const bf16* __restrict__ q,
                                                  const bf16* __restrict__ k,
                                                  const bf16* __restrict__ v,
                                                  bf16* __restrict__ att) {
  int half = blockIdx.x, w = blockIdx.y, b = blockIdx.z;
  int tid = threadIdx.x, wid = tid >> 6, lane = tid & 63;
  int lr = lane & 15, lq4 = lane >> 4;
  __shared__ __align__(16) bf16 Ks[32 * 128];   // [j][d]
  __shared__ __align__(16) bf16 Vts[128 * 32];  // [d][j]
  __shared__ __align__(16) bf16 Ps[4][16 * 32]; // per-wave P scratch

  int t0 = w * 128 + half * 64 + wid * 16;
  long qbase = ((long)b * SEQ + t0 + lr) * DM;
  short8 qf[4];
#pragma unroll
  for (int ks = 0; ks < 4; ks++) qf[ks] = *(const short8*)(q + qbase + ks * 32 + lq4 * 8);

  floatx4 Oacc[8];
#pragma unroll
  for (int i = 0; i < 8; i++) Oacc[i] = {0.f, 0.f, 0.f, 0.f};
  float rs[4] = {0.f, 0.f, 0.f, 0.f};

  int keystart = w * 128 - 128;
  for (int ch = 0; ch < 12; ch++) {
    int kb = keystart + ch * 32;
    if (kb < 0 || kb >= SEQ) continue;  // uniform per block
    {
      int j = tid >> 3, d = (tid & 7) * 16;
      const bf16* ksrc = k + ((long)b * SEQ + kb + j) * DM + d;
      *(uint4*)(&Ks[j * 128 + d]) = *(const uint4*)(ksrc);
      *(uint4*)(&Ks[j * 128 + d + 8]) = *(const uint4*)(ksrc + 8);
      const bf16* vsrc = v + ((long)b * SEQ + kb + j) * DM + d;
#pragma unroll
      for (int e = 0; e < 16; e++) Vts[(d + e) * 32 + j] = vsrc[e];
    }
    __syncthreads();
    floatx4 s0 = {0.f, 0.f, 0.f, 0.f}, s1 = {0.f, 0.f, 0.f, 0.f};
#pragma unroll
    for (int ks = 0; ks < 4; ks++) {
      short8 kf0 = *(const short8*)(&Ks[(0 + lr) * 128 + ks * 32 + lq4 * 8]);
      short8 kf1 = *(const short8*)(&Ks[(16 + lr) * 128 + ks * 32 + lq4 * 8]);
      s0 = MFMA16(qf[ks], kf0, s0);
      s1 = MFMA16(qf[ks], kf1, s1);
    }
#pragma unroll
    for (int reg = 0; reg < 4; reg++) {
      float e0 = __expf(s0[reg] * 0.08838834764831845f);
      float e1 = __expf(s1[reg] * 0.08838834764831845f);
      rs[reg] += e0 + e1;
      Ps[wid][(lq4 * 4 + reg) * 32 + lr] = (bf16)e0;
      Ps[wid][(lq4 * 4 + reg) * 32 + 16 + lr] = (bf16)e1;
    }
    __syncthreads();
    short8 pf = *(const short8*)(&Ps[wid][lr * 32 + lq4 * 8]);
#pragma unroll
    for (int nt = 0; nt < 8; nt++) {
      short8 vf = *(const short8*)(&Vts[(nt * 16 + lr) * 32 + lq4 * 8]);
      Oacc[nt] = MFMA16(pf, vf, Oacc[nt]);
    }
    __syncthreads();
  }
#pragma unroll
  for (int m = 1; m < 16; m <<= 1)
#pragma unroll
    for (int reg = 0; reg < 4; reg++) rs[reg] += __shfl_xor(rs[reg], m, 64);
  long obase = ((long)b * SEQ + t0 + lq4 * 4) * DM;
#pragma unroll
  for (int nt = 0; nt < 8; nt++)
#pragma unroll
    for (int reg = 0; reg < 4; reg++)
      att[obase + (long)reg * DM + nt * 16 + lr] = (bf16)(Oacc[nt][reg] / rs[reg]);
}

// ---------------------------------------------------------------------------
// Linear-attn q-softmax: qp[z6][t][128] = softmax(q_head)*d^-0.5
// ---------------------------------------------------------------------------
__global__ __launch_bounds__(256) void qp_softmax(const bf16* __restrict__ q, bf16* __restrict__ qp) {
  int wid = threadIdx.x >> 6, lane = threadIdx.x & 63;
  long task = (long)blockIdx.x * 4 + wid;  // < 24576
  int tt = (int)(task & (SEQ - 1));
  int z6 = (int)(task >> 12);
  int lb = z6 / 3, h2 = z6 % 3;
  const bf16* src = q + ((long)lb * SEQ + tt) * DM + (h2 + 1) * 128 + lane * 2;
  float x0 = (float)src[0], x1 = (float)src[1];
  float m = fmaxf(x0, x1);
#pragma unroll
  for (int s = 32; s >= 1; s >>= 1) m = fmaxf(m, __shfl_xor(m, s, 64));
  float e0 = __expf(x0 - m), e1 = __expf(x1 - m);
  float sm = e0 + e1;
#pragma unroll
  for (int s = 32; s >= 1; s >>= 1) sm += __shfl_xor(sm, s, 64);
  float inv = 0.08838834764831845f / sm;
  bf16* dst = qp + task * 128 + lane * 2;
  dst[0] = (bf16)(e0 * inv);
  dst[1] = (bf16)(e1 * inv);
}

// ---------------------------------------------------------------------------
// k column stats, phase 1: per-(z, 128-row chunk) column max and exp-sum.
// ---------------------------------------------------------------------------
__global__ __launch_bounds__(128) void kstats_part(const bf16* __restrict__ k,
                                                   float* __restrict__ part) {
  int chunk = blockIdx.x, z = blockIdx.y;
  int lb = z / 3, h2 = z % 3, ch = (h2 + 1) * 128;
  int d = threadIdx.x;
  const bf16* base = k + ((long)lb * SEQ + chunk * 128) * DM + ch + d;
  float m = -1e30f;
#pragma unroll 4
  for (int t = 0; t < 128; t++) m = fmaxf(m, (float)base[(long)t * DM]);
  float l = 0.f;
#pragma unroll 4
  for (int t = 0; t < 128; t++) l += __expf((float)base[(long)t * DM] - m);
  int idx = (z * 32 + chunk) * 128 + d;
  part[idx] = m;
  part[24576 + idx] = l;
}

// phase 2: combine 32 chunk stats -> kml[z*256+d]=M, +128=L
__global__ __launch_bounds__(128) void kstats_comb(const float* __restrict__ part,
                                                   float* __restrict__ kml) {
  int z = blockIdx.x, d = threadIdx.x;
  float M = -1e30f;
#pragma unroll 4
  for (int c = 0; c < 32; c++) M = fmaxf(M, part[(z * 32 + c) * 128 + d]);
  float L = 0.f;
#pragma unroll 4
  for (int c = 0; c < 32; c++) {
    int i = (z * 32 + c) * 128 + d;
    L += part[24576 + i] * __expf(part[i] - M);
  }
  kml[z * 256 + d] = M;
  kml[z * 256 + 128 + d] = L;
}

// ---------------------------------------------------------------------------
// ctx via MFMA: part[z][chunk][e*128+d] = sum_{t in 512-chunk} v[t][e]*k'[t][d]
// ---------------------------------------------------------------------------
__global__ __launch_bounds__(256) void ctx_mfma(const bf16* __restrict__ k,
                                                const bf16* __restrict__ v,
                                                const float* __restrict__ kml,
                                                float* __restrict__ part) {
  int chunk = blockIdx.x, z = blockIdx.y;
  int lb = z / 3, h2 = z % 3, ch = (h2 + 1) * 128;
  int tid = threadIdx.x, lane = tid & 63, wid = tid >> 6;
  const int wm = (wid & 1) * 64, wn = (wid >> 1) * 64;
  const int lr = lane & 15, lk = (lane >> 4) * 8;
  __shared__ float ml2[128];
  __shared__ __align__(16) bf16 Vt[128 * CS];
  __shared__ __align__(16) bf16 Kt[128 * CS];
  if (tid < 128)
    ml2[tid] = kml[z * 256 + tid] + logf(kml[z * 256 + 128 + tid]);

  int j = tid >> 3, d0 = (tid & 7) * 16;
  const bf16* vsrc = v + ((long)lb * SEQ + chunk * 512 + j) * DM + ch + d0;
  const bf16* ksrc = k + ((long)lb * SEQ + chunk * 512 + j) * DM + ch + d0;

  floatx4 acc[4][4];
#pragma unroll
  for (int i = 0; i < 4; i++)
#pragma unroll
    for (int jj = 0; jj < 4; jj++) acc[i][jj] = {0.f, 0.f, 0.f, 0.f};

  for (int s = 0; s < 16; s++) {
    union { bf16 h[16]; uint4 u[2]; } va, ka;
    va.u[0] = *(const uint4*)(vsrc); va.u[1] = *(const uint4*)(vsrc + 8);
    ka.u[0] = *(const uint4*)(ksrc); ka.u[1] = *(const uint4*)(ksrc + 8);
    vsrc += (long)32 * DM; ksrc += (long)32 * DM;
    __syncthreads();
#pragma unroll
    for (int e = 0; e < 16; e++) {
      Vt[(d0 + e) * CS + j] = va.h[e];
      Kt[(d0 + e) * CS + j] = (bf16)__expf((float)ka.h[e] - ml2[d0 + e]);
    }
    __syncthreads();
    short8 af[4], bfr[4];
#pragma unroll
    for (int mt = 0; mt < 4; mt++) af[mt] = *(const short8*)(&Vt[(wm + mt * 16 + lr) * CS + lk]);
#pragma unroll
    for (int nt = 0; nt < 4; nt++) bfr[nt] = *(const short8*)(&Kt[(wn + nt * 16 + lr) * CS + lk]);
#pragma unroll
    for (int mt = 0; mt < 4; mt++)
#pragma unroll
      for (int nt = 0; nt < 4; nt++)
        acc[mt][nt] = MFMA16(af[mt], bfr[nt], acc[mt][nt]);
  }

  float* dst = part + ((long)z * 8 + chunk) * 16384;
#pragma unroll
  for (int nt = 0; nt < 4; nt++) {
    int c = wn + nt * 16 + lr;
#pragma unroll
    for (int mt = 0; mt < 4; mt++) {
      int rb = wm + mt * 16 + (lane >> 4) * 4;
#pragma unroll
      for (int reg = 0; reg < 4; reg++)
        dst[(rb + reg) * 128 + c] = acc[mt][nt][reg];
    }
  }
}

__global__ __launch_bounds__(256) void ctx_reduce(const float* __restrict__ part, bf16* __restrict__ ctxT) {
  long i = (long)blockIdx.x * 256 + threadIdx.x;  // < 98304
  int z = (int)(i >> 14);
  int off = (int)(i & 16383);
  float s = 0.f;
#pragma unroll
  for (int c = 0; c < 8; c++) s += part[(((long)z * 8 + c) << 14) + off];
  ctxT[i] = (bf16)s;
}

// ---------------------------------------------------------------------------
extern "C" void kernel_launch(void* const* d_in, const int* in_sizes, int n_in,
                              void* d_out, int out_size, void* d_ws, size_t ws_size,
                              hipStream_t stream) {
  float* outp = (float*)d_out;
  if (ws_size < (size_t)WS_NEED) {
    beacon<<<(out_size + 255) / 256, 256, 0, stream>>>(outp, out_size);
    return;
  }

  const float* x   = (const float*)d_in[0];
  const float* W1  = (const float*)d_in[1];
  const float* b1  = (const float*)d_in[2];
  const float* g1  = (const float*)d_in[3];
  const float* be1 = (const float*)d_in[4];
  const float* Wq  = (const float*)d_in[5];
  const float* Wk  = (const float*)d_in[6];
  const float* Wv  = (const float*)d_in[7];
  const float* Wo  = (const float*)d_in[8];
  const float* bo  = (const float*)d_in[9];
  const float* g2  = (const float*)d_in[10];
  const float* be2 = (const float*)d_in[11];
  const float* Wf1 = (const float*)d_in[12];
  const float* bf1 = (const float*)d_in[13];
  const float* Wf2 = (const float*)d_in[14];
  const float* bf2 = (const float*)d_in[15];
  const float* W2  = (const float*)d_in[16];
  const float* b2  = (const float*)d_in[17];

  char* ws = (char*)d_ws;
  float* h   = (float*)(ws + OFF_H);
  bf16* lnG  = (bf16*)(ws + OFF_LNG);
  bf16* qb   = (bf16*)(ws + OFF_Q);
  bf16* kb   = (bf16*)(ws + OFF_K);
  bf16* vb   = (bf16*)(ws + OFF_V);
  bf16* attb = (bf16*)(ws + OFF_ATT);
  bf16* ff1g = (bf16*)(ws + OFF_Q);    // overlays Q..ATT (dead in FFN phase)
  bf16* qp   = (bf16*)(ws + OFF_QP);
  float* ctxp= (float*)(ws + OFF_CTXP);
  bf16* ctxT = (bf16*)(ws + OFF_CTXT);
  float* kml = (float*)(ws + OFF_KML);
  bf16* wt   = (bf16*)(ws + OFF_WT);
  bf16* wqt  = wt + 65536;
  bf16* wot  = wt + 851968;
  bf16* wf1t = wt + 1114112;
  bf16* wf2t = wt + 2162688;
  bf16* w2t  = wt + 3211264;

  // ---- all weight transposes (fp32 -> bf16, [Npad][K] K-contiguous) ----
  transpose8<<<dim3(32, 32, 8), 256, 0, stream>>>(W1, Wq, Wk, Wv, Wo, Wf1, Wf2, W2, wt);

  // ---- h = tanh(xpad @ W1 + b1) fp32; pad rows handled in A staging ----
  gemm_bt<<<dim3(4, 256, 1), 256, 0, stream>>>(x, wt, b1, h, nullptr,
      DINP, DINP, DINP, DM, 0, 1, 0, 0, 1, 0, 0);

  // ---- attention, 4 groups of 2 batches ----
  for (int g = 0; g < NGROUP; g++) {
    float* hg = h + (long)g * GROUPROWS * DM;
    ln_kernel<<<GROUPROWS / 4, 256, 0, stream>>>(hg, g1, be1, lnG);
    // Q,K,V in one z=3 batched launch
    gemm_bt<<<dim3(4, 64, 3), 256, 0, stream>>>(lnG, wqt, nullptr, nullptr, qb,
        DM, DM, DM, DM, 1, 0,
        0L, 262144L, 3, 0L, 4194304L);

    local_attn<<<dim3(2, 32, 2), 256, 0, stream>>>(qb, kb, vb, attb);

    qp_softmax<<<6144, 256, 0, stream>>>(qb, qp);
    kstats_part<<<dim3(32, 6), 128, 0, stream>>>(kb, ctxp);
    kstats_comb<<<6, 128, 0, stream>>>(ctxp, kml);
    ctx_mfma<<<dim3(8, 6), 256, 0, stream>>>(kb, vb, kml, ctxp);
    ctx_reduce<<<384, 256, 0, stream>>>(ctxp, ctxT);
    gemm_bt<<<dim3(1, 32, 6), 256, 0, stream>>>(qp, ctxT, nullptr, nullptr, attb + 128,
        128, 128, 128, DM, 1, 0,
        (long)SEQ * 128, 16384L, 3, (long)SEQ * DM, 128L);

    // h += attn @ Wo + bo : 64-row tiles, 512 blocks, no atomics
    gemm_bt64<<<dim3(4, 128), 256, 0, stream>>>(attb, wot, bo, hg,
        DM, DM, DM, DM);
  }

  // ---- FFN, 4 groups ----
  for (int g = 0; g < NGROUP; g++) {
    float* hg = h + (long)g * GROUPROWS * DM;
    ln_kernel<<<GROUPROWS / 4, 256, 0, stream>>>(hg, g2, be2, lnG);
    gemm_bt<<<dim3(16, 64, 1), 256, 0, stream>>>(lnG, wf1t, bf1, nullptr, ff1g,
        DM, DM, DM, DFF, 4, 0, 0, 0, 1, 0, 0);
    // h += gelu(ff1) @ Wf2 + bf2 : 64-row tiles, 512 blocks, no atomics
    gemm_bt64<<<dim3(4, 128), 256, 0, stream>>>(ff1g, wf2t, bf2, hg,
        DFF, DFF, DFF, DM);
  }

  // ---- out = (h @ W2 + b2)[:, :3000, :] -> d_out fp32 (h staged as bf16) ----
  gemm_bt<<<dim3(1, 256, 1), 256, 0, stream>>>(h, w2t, b2, outp, nullptr,
      DM, DM, DM, 64, 5, 2, 0, 0, 1, 0, 0);
}

// Round 9
// 888.306 us; speedup vs baseline: 2.6515x; 1.4377x over previous
//
#include <hip/hip_runtime.h>
#include <hip/hip_bf16.h>
#include <math.h>

// ---------------------------------------------------------------------------
// Linear_Transformer on MI355X (gfx950). fp32 I/O, bf16 MFMA internals,
// fp32 residual stream.
// Round 9: adaptive group sizing. ws_size is only known to be in
// [125.2MB, 301MB); round-8's 4-group serialization (and its ~40 dispatch
// tails + 3-blocks/CU QKV grids) exists only to fit 125MB. Runtime-pick
// GB in {8,4,2} batches/group (254.8/164.2/119.0 MB arenas; qp overlays lnG,
// ff1 overlays q..attn). Kernels unchanged (all GB-agnostic); launcher only.
// ---------------------------------------------------------------------------

typedef __hip_bfloat16 bf16;
typedef __attribute__((ext_vector_type(8))) short short8;   // 8 bf16 (MFMA A/B frag)
typedef __attribute__((ext_vector_type(4))) float floatx4;  // MFMA C/D frag

#define SEQ   4096
#define NBAT  8
#define DM    512
#define DINP  128
#define DFF   2048
#define NREAL 3000
#define CS    40              // ctx_mfma LDS stride (80B, 16B-aligned)

#define MFMA16(a,b,c) __builtin_amdgcn_mfma_f32_16x16x32_bf16((a),(b),(c),0,0,0)

// async global->LDS, 16B per lane, deposits at lds + lane*16
__device__ __forceinline__ void gload_lds16(const void* g, void* l) {
  auto* gp = reinterpret_cast<const __attribute__((address_space(1))) unsigned int*>(
      reinterpret_cast<uintptr_t>(g));
  auto* lp = reinterpret_cast<__attribute__((address_space(3))) unsigned int*>(
      reinterpret_cast<uintptr_t>(l));
  __builtin_amdgcn_global_load_lds(gp, lp, 16, 0, 0);
}

// ---------------------------------------------------------------------------
__global__ __launch_bounds__(256) void beacon(float* __restrict__ out, long n) {
  long i = (long)blockIdx.x * 256 + threadIdx.x;
  if (i < n) out[i] = 10000.f;
}

// ---------------------------------------------------------------------------
// All 8 weight transposes in one launch. Wt[n][k] = n<N ? (bf16)W[k][n] : 0
// ---------------------------------------------------------------------------
__global__ __launch_bounds__(256) void transpose8(
    const float* __restrict__ W1, const float* __restrict__ Wq,
    const float* __restrict__ Wk, const float* __restrict__ Wv,
    const float* __restrict__ Wo, const float* __restrict__ Wf1,
    const float* __restrict__ Wf2, const float* __restrict__ W2,
    bf16* __restrict__ wt) {
  const int Ks[8]   = {128, 512, 512, 512, 512, 512, 2048, 512};
  const int Ns[8]   = {512, 512, 512, 512, 512, 2048, 512, 64};
  const int Nps[8]  = {512, 512, 512, 512, 512, 2048, 512, 128};
  const long Ofs[8] = {0L, 65536L, 327680L, 589824L, 851968L, 1114112L, 2162688L, 3211264L};
  int zi = blockIdx.z;
  int K = Ks[zi], N = Ns[zi], Npad = Nps[zi];
  int k0 = blockIdx.x * 64, n0 = blockIdx.y * 64;
  if (k0 >= K || n0 >= Npad) return;
  const float* W = zi == 0 ? W1 : zi == 1 ? Wq : zi == 2 ? Wk : zi == 3 ? Wv
                 : zi == 4 ? Wo : zi == 5 ? Wf1 : zi == 6 ? Wf2 : W2;
  bf16* Wt = wt + Ofs[zi];
  __shared__ float t[64][65];
  int r = threadIdx.x >> 2, c = (threadIdx.x & 3) * 16;
#pragma unroll
  for (int i = 0; i < 16; i++) {
    int n = n0 + c + i;
    t[r][c + i] = (n < N) ? W[(long)(k0 + r) * N + n] : 0.f;
  }
  __syncthreads();
#pragma unroll
  for (int i = 0; i < 16; i++)
    Wt[(long)(n0 + r) * K + k0 + c + i] = (bf16)t[c + i][r];
}

// ---------------------------------------------------------------------------
__device__ inline uint4 pack8(const float* p) {
  union { bf16 h[8]; uint4 u; } r;
  float4 a = *(const float4*)p;
  float4 b = *(const float4*)(p + 4);
  r.h[0] = (bf16)a.x; r.h[1] = (bf16)a.y; r.h[2] = (bf16)a.z; r.h[3] = (bf16)a.w;
  r.h[4] = (bf16)b.x; r.h[5] = (bf16)b.y; r.h[6] = (bf16)b.z; r.h[7] = (bf16)b.w;
  return r.u;
}

// ---------------------------------------------------------------------------
// Generic MFMA GEMM: C[M x N] = epi(A[M x K] @ Bt[N x K]^T + bias)
// 128x128 tile, BK=32, 256 threads (4 waves, 2x2), z-batched.
// AMODE 0: bf16 A, async global_load_lds staging (known-good loop).
// AMODE 1: fp32 x (8,3000,128) zero-padded rows; register staging.
// AMODE 2: fp32 A converted in register staging.
// EPI: 0 tanh->Cf  1 bf16->Cb  2 Cf+=  4 gelu->Cb  5 row-remap -> Cf (d_out)
// ---------------------------------------------------------------------------
__global__ __launch_bounds__(256) void gemm_bt(
    const void* __restrict__ Avoid, const bf16* __restrict__ Bt,
    const float* __restrict__ bias, float* __restrict__ Cf, bf16* __restrict__ Cb,
    int K, int lda, int ldb, int ldc, int EPI, int AMODE,
    long aBatch, long bBatch, int zdiv, long cOuter, long cInner) {
  __shared__ __align__(16) bf16 As[128 * 32];
  __shared__ __align__(16) bf16 Bs[128 * 32];
  const int tid = threadIdx.x;
  const int bz = blockIdx.z;
  Bt += (long)bz * bBatch;
  const long cOff = (long)(bz / zdiv) * cOuter + (long)(bz % zdiv) * cInner;
  const int row0 = blockIdx.y * 128;
  const int col0 = blockIdx.x * 128;
  const int lane = tid & 63, wid = tid >> 6;
  const int wm = (wid & 1) * 64, wn = (wid >> 1) * 64;
  const int lr = lane & 15, lk = (lane >> 4) * 8;

  floatx4 acc[4][4];
#pragma unroll
  for (int i = 0; i < 4; i++)
#pragma unroll
    for (int j = 0; j < 4; j++) acc[i][j] = {0.f, 0.f, 0.f, 0.f};

  if (AMODE == 0) {
    const bf16* A = (const bf16*)Avoid + (long)bz * aBatch;
    const bf16* pAa = A + (long)(row0 + wid * 16 + (lane >> 2)) * lda + (lane & 3) * 8;
    const bf16* pBa = Bt + (long)(col0 + wid * 16 + (lane >> 2)) * ldb + (lane & 3) * 8;
    bf16* ldsA = &As[wid * 16 * 32];
    bf16* ldsB = &Bs[wid * 16 * 32];
    const long a64 = (long)64 * lda, b64 = (long)64 * ldb;
    for (int k0 = 0; k0 < K; k0 += 32) {
      __syncthreads();
      gload_lds16(pAa, ldsA);
      gload_lds16(pAa + a64, ldsA + 64 * 32);
      gload_lds16(pBa, ldsB);
      gload_lds16(pBa + b64, ldsB + 64 * 32);
      pAa += 32; pBa += 32;
      __syncthreads();
      short8 af[4], bfr[4];
#pragma unroll
      for (int mt = 0; mt < 4; mt++) af[mt] = *(const short8*)(&As[(wm + mt * 16 + lr) * 32 + lk]);
#pragma unroll
      for (int nt = 0; nt < 4; nt++) bfr[nt] = *(const short8*)(&Bs[(wn + nt * 16 + lr) * 32 + lk]);
#pragma unroll
      for (int mt = 0; mt < 4; mt++)
#pragma unroll
        for (int nt = 0; nt < 4; nt++)
          acc[mt][nt] = MFMA16(af[mt], bfr[nt], acc[mt][nt]);
    }
  } else {
    const float* Af = (const float*)Avoid;
    const int srow = tid >> 2;
    const int skcol = (tid & 3) * 8;
    const long r0 = row0 + srow, r1 = r0 + 64;
    const bf16* pB = Bt + (long)(col0 + srow) * ldb + skcol;
    const int ldsOff = srow * 32 + skcol;
    const float* pF0; const float* pF1;
    bool v0 = true, v1 = true;
    if (AMODE == 1) {
      int t0 = (int)(r0 & (SEQ - 1)), t1 = (int)(r1 & (SEQ - 1));
      v0 = t0 < NREAL; v1 = t1 < NREAL;
      if (!v0) t0 = 0;
      if (!v1) t1 = 0;
      pF0 = Af + ((r0 >> 12) * NREAL + t0) * DINP + skcol;
      pF1 = Af + ((r1 >> 12) * NREAL + t1) * DINP + skcol;
    } else {
      pF0 = Af + r0 * lda + skcol;
      pF1 = Af + r1 * lda + skcol;
    }
    for (int k0 = 0; k0 < K; k0 += 32) {
      uint4 b0 = *(const uint4*)(pB);
      uint4 b1 = *(const uint4*)(pB + (long)64 * ldb);
      pB += 32;
      uint4 a0 = {0, 0, 0, 0}, a1 = {0, 0, 0, 0};
      if (v0) a0 = pack8(pF0);
      if (v1) a1 = pack8(pF1);
      pF0 += 32; pF1 += 32;
      __syncthreads();
      *(uint4*)(&As[ldsOff]) = a0;
      *(uint4*)(&As[ldsOff + 64 * 32]) = a1;
      *(uint4*)(&Bs[ldsOff]) = b0;
      *(uint4*)(&Bs[ldsOff + 64 * 32]) = b1;
      __syncthreads();
      short8 af[4], bfr[4];
#pragma unroll
      for (int mt = 0; mt < 4; mt++) af[mt] = *(const short8*)(&As[(wm + mt * 16 + lr) * 32 + lk]);
#pragma unroll
      for (int nt = 0; nt < 4; nt++) bfr[nt] = *(const short8*)(&Bs[(wn + nt * 16 + lr) * 32 + lk]);
#pragma unroll
      for (int mt = 0; mt < 4; mt++)
#pragma unroll
        for (int nt = 0; nt < 4; nt++)
          acc[mt][nt] = MFMA16(af[mt], bfr[nt], acc[mt][nt]);
    }
  }

  // D element (mt,nt,reg): row=(lane>>4)*4+reg, col=lane&15 within 16x16 tile
#pragma unroll
  for (int nt = 0; nt < 4; nt++) {
    int c = col0 + wn + nt * 16 + lr;
    float bv = 0.f;
    if (bias) {
      if (EPI == 5) { if (c < 64) bv = bias[c]; }
      else bv = bias[c];
    }
#pragma unroll
    for (int mt = 0; mt < 4; mt++) {
      long rb = row0 + wm + mt * 16 + (lane >> 4) * 4;
#pragma unroll
      for (int reg = 0; reg < 4; reg++) {
        float v = acc[mt][nt][reg] + bv;
        long ri = rb + reg;
        long idx = cOff + ri * (long)ldc + c;
        if (EPI == 0) Cf[idx] = tanhf(v);
        else if (EPI == 1) Cb[idx] = (bf16)v;
        else if (EPI == 2) Cf[idx] += v;
        else if (EPI == 4) { float g = 0.5f * v * (1.f + erff(v * 0.70710678118654752f)); Cb[idx] = (bf16)g; }
        else if (EPI == 5) {
          int bb = (int)(ri >> 12); int tt = (int)(ri & (SEQ - 1));
          if (tt < NREAL && c < 64) Cf[((long)bb * NREAL + tt) * 64 + c] = v;
        }
      }
    }
  }
}

// ---------------------------------------------------------------------------
// 64x128-tile MFMA GEMM, residual accumulate: Cf[M x N] += A @ Bt^T + bias.
// Block owns its 64 rows -> plain += epilogue, no atomics.
// ---------------------------------------------------------------------------
__global__ __launch_bounds__(256) void gemm_bt64(
    const bf16* __restrict__ A, const bf16* __restrict__ Bt,
    const float* __restrict__ bias, float* __restrict__ Cf,
    int K, int lda, int ldb, int ldc) {
  __shared__ __align__(16) bf16 As[64 * 32];
  __shared__ __align__(16) bf16 Bs[128 * 32];
  const int tid = threadIdx.x;
  const int row0 = blockIdx.y * 64;
  const int col0 = blockIdx.x * 128;
  const int lane = tid & 63, wid = tid >> 6;
  const int wm = (wid & 1) * 32, wn = (wid >> 1) * 64;
  const int lr = lane & 15, lk = (lane >> 4) * 8;

  floatx4 acc[2][4];
#pragma unroll
  for (int i = 0; i < 2; i++)
#pragma unroll
    for (int j = 0; j < 4; j++) acc[i][j] = {0.f, 0.f, 0.f, 0.f};

  const bf16* pAa = A + (long)(row0 + wid * 16 + (lane >> 2)) * lda + (lane & 3) * 8;
  const bf16* pBa = Bt + (long)(col0 + wid * 16 + (lane >> 2)) * ldb + (lane & 3) * 8;
  bf16* ldsA = &As[wid * 16 * 32];
  bf16* ldsB = &Bs[wid * 16 * 32];
  const long b64 = (long)64 * ldb;
  for (int k0 = 0; k0 < K; k0 += 32) {
    __syncthreads();
    gload_lds16(pAa, ldsA);
    gload_lds16(pBa, ldsB);
    gload_lds16(pBa + b64, ldsB + 64 * 32);
    pAa += 32; pBa += 32;
    __syncthreads();
    short8 af[2], bfr[4];
#pragma unroll
    for (int mt = 0; mt < 2; mt++) af[mt] = *(const short8*)(&As[(wm + mt * 16 + lr) * 32 + lk]);
#pragma unroll
    for (int nt = 0; nt < 4; nt++) bfr[nt] = *(const short8*)(&Bs[(wn + nt * 16 + lr) * 32 + lk]);
#pragma unroll
    for (int mt = 0; mt < 2; mt++)
#pragma unroll
      for (int nt = 0; nt < 4; nt++)
        acc[mt][nt] = MFMA16(af[mt], bfr[nt], acc[mt][nt]);
  }

#pragma unroll
  for (int nt = 0; nt < 4; nt++) {
    int c = col0 + wn + nt * 16 + lr;
    float bv = bias ? bias[c] : 0.f;
#pragma unroll
    for (int mt = 0; mt < 2; mt++) {
      long rb = row0 + wm + mt * 16 + (lane >> 4) * 4;
#pragma unroll
      for (int reg = 0; reg < 4; reg++)
        Cf[(rb + reg) * (long)ldc + c] += acc[mt][nt][reg] + bv;
    }
  }
}

// ---------------------------------------------------------------------------
// LayerNorm over 512 fp32 -> bf16. One wave per row, 4 rows per block.
// ---------------------------------------------------------------------------
__global__ __launch_bounds__(256) void ln_kernel(const float* __restrict__ h,
                                                 const float* __restrict__ g,
                                                 const float* __restrict__ bta,
                                                 bf16* __restrict__ out) {
  int wid = threadIdx.x >> 6, lane = threadIdx.x & 63;
  long row = (long)blockIdx.x * 4 + wid;
  const float* src = h + row * DM + lane * 8;
  float4 a = *(const float4*)(src);
  float4 b = *(const float4*)(src + 4);
  float x[8] = {a.x, a.y, a.z, a.w, b.x, b.y, b.z, b.w};
  float s = 0.f, sq = 0.f;
#pragma unroll
  for (int i = 0; i < 8; i++) { s += x[i]; sq += x[i] * x[i]; }
#pragma unroll
  for (int m = 32; m >= 1; m >>= 1) { s += __shfl_xor(s, m, 64); sq += __shfl_xor(sq, m, 64); }
  float mu = s * (1.f / DM);
  float var = sq * (1.f / DM) - mu * mu;
  float rstd = rsqrtf(var + 1e-5f);
  const float* gp = g + lane * 8;
  const float* bp = bta + lane * 8;
  bf16* dst = out + row * DM + lane * 8;
#pragma unroll
  for (int i = 0; i < 8; i++)
    dst[i] = (bf16)((x[i] - mu) * rstd * gp[i] + bp[i]);
}

// ---------------------------------------------------------------------------
// Local attention, head 0. Grid (2 halves, 32 windows, GB batches).
// ---------------------------------------------------------------------------
__global__ __launch_bounds__(256) void local_attn(const bf16* __restrict__ q,
                                                  const bf16* __restrict__ k,
                                                  const bf16* __restrict__ v,
                                                  bf16* __restrict__ att) {
  int half = blockIdx.x, w = blockIdx.y, b = blockIdx.z;
  int tid = threadIdx.x, wid = tid >> 6, lane = tid & 63;
  int lr = lane & 15, lq4 = lane >> 4;
  __shared__ __align__(16) bf16 Ks[32 * 128];   // [j][d]
  __shared__ __align__(16) bf16 Vts[128 * 32];  // [d][j]
  __shared__ __align__(16) bf16 Ps[4][16 * 32]; // per-wave P scratch

  int t0 = w * 128 + half * 64 + wid * 16;
  long qbase = ((long)b * SEQ + t0 + lr) * DM;
  short8 qf[4];
#pragma unroll
  for (int ks = 0; ks < 4; ks++) qf[ks] = *(const short8*)(q + qbase + ks * 32 + lq4 * 8);

  floatx4 Oacc[8];
#pragma unroll
  for (int i = 0; i < 8; i++) Oacc[i] = {0.f, 0.f, 0.f, 0.f};
  float rs[4] = {0.f, 0.f, 0.f, 0.f};

  int keystart = w * 128 - 128;
  for (int ch = 0; ch < 12; ch++) {
    int kb = keystart + ch * 32;
    if (kb < 0 || kb >= SEQ) continue;  // uniform per block
    {
      int j = tid >> 3, d = (tid & 7) * 16;
      const bf16* ksrc = k + ((long)b * SEQ + kb + j) * DM + d;
      *(uint4*)(&Ks[j * 128 + d]) = *(const uint4*)(ksrc);
      *(uint4*)(&Ks[j * 128 + d + 8]) = *(const uint4*)(ksrc + 8);
      const bf16* vsrc = v + ((long)b * SEQ + kb + j) * DM + d;
#pragma unroll
      for (int e = 0; e < 16; e++) Vts[(d + e) * 32 + j] = vsrc[e];
    }
    __syncthreads();
    floatx4 s0 = {0.f, 0.f, 0.f, 0.f}, s1 = {0.f, 0.f, 0.f, 0.f};
#pragma unroll
    for (int ks = 0; ks < 4; ks++) {
      short8 kf0 = *(const short8*)(&Ks[(0 + lr) * 128 + ks * 32 + lq4 * 8]);
      short8 kf1 = *(const short8*)(&Ks[(16 + lr) * 128 + ks * 32 + lq4 * 8]);
      s0 = MFMA16(qf[ks], kf0, s0);
      s1 = MFMA16(qf[ks], kf1, s1);
    }
#pragma unroll
    for (int reg = 0; reg < 4; reg++) {
      float e0 = __expf(s0[reg] * 0.08838834764831845f);
      float e1 = __expf(s1[reg] * 0.08838834764831845f);
      rs[reg] += e0 + e1;
      Ps[wid][(lq4 * 4 + reg) * 32 + lr] = (bf16)e0;
      Ps[wid][(lq4 * 4 + reg) * 32 + 16 + lr] = (bf16)e1;
    }
    __syncthreads();
    short8 pf = *(const short8*)(&Ps[wid][lr * 32 + lq4 * 8]);
#pragma unroll
    for (int nt = 0; nt < 8; nt++) {
      short8 vf = *(const short8*)(&Vts[(nt * 16 + lr) * 32 + lq4 * 8]);
      Oacc[nt] = MFMA16(pf, vf, Oacc[nt]);
    }
    __syncthreads();
  }
#pragma unroll
  for (int m = 1; m < 16; m <<= 1)
#pragma unroll
    for (int reg = 0; reg < 4; reg++) rs[reg] += __shfl_xor(rs[reg], m, 64);
  long obase = ((long)b * SEQ + t0 + lq4 * 4) * DM;
#pragma unroll
  for (int nt = 0; nt < 8; nt++)
#pragma unroll
    for (int reg = 0; reg < 4; reg++)
      att[obase + (long)reg * DM + nt * 16 + lr] = (bf16)(Oacc[nt][reg] / rs[reg]);
}

// ---------------------------------------------------------------------------
// Linear-attn q-softmax: qp[z][t][128] = softmax(q_head)*d^-0.5, z=lb*3+h2
// ---------------------------------------------------------------------------
__global__ __launch_bounds__(256) void qp_softmax(const bf16* __restrict__ q, bf16* __restrict__ qp) {
  int wid = threadIdx.x >> 6, lane = threadIdx.x & 63;
  long task = (long)blockIdx.x * 4 + wid;
  int tt = (int)(task & (SEQ - 1));
  int z6 = (int)(task >> 12);
  int lb = z6 / 3, h2 = z6 % 3;
  const bf16* src = q + ((long)lb * SEQ + tt) * DM + (h2 + 1) * 128 + lane * 2;
  float x0 = (float)src[0], x1 = (float)src[1];
  float m = fmaxf(x0, x1);
#pragma unroll
  for (int s = 32; s >= 1; s >>= 1) m = fmaxf(m, __shfl_xor(m, s, 64));
  float e0 = __expf(x0 - m), e1 = __expf(x1 - m);
  float sm = e0 + e1;
#pragma unroll
  for (int s = 32; s >= 1; s >>= 1) sm += __shfl_xor(sm, s, 64);
  float inv = 0.08838834764831845f / sm;
  bf16* dst = qp + task * 128 + lane * 2;
  dst[0] = (bf16)(e0 * inv);
  dst[1] = (bf16)(e1 * inv);
}

// ---------------------------------------------------------------------------
// k column stats, phase 1: per-(z, 128-row chunk) column max and exp-sum.
// part: m at [(z*32+chunk)*128+d], l at [NZ*32*128 + same] — NZ passed in.
// ---------------------------------------------------------------------------
__global__ __launch_bounds__(128) void kstats_part(const bf16* __restrict__ k,
                                                   float* __restrict__ part, int lOff) {
  int chunk = blockIdx.x, z = blockIdx.y;
  int lb = z / 3, h2 = z % 3, ch = (h2 + 1) * 128;
  int d = threadIdx.x;
  const bf16* base = k + ((long)lb * SEQ + chunk * 128) * DM + ch + d;
  float m = -1e30f;
#pragma unroll 4
  for (int t = 0; t < 128; t++) m = fmaxf(m, (float)base[(long)t * DM]);
  float l = 0.f;
#pragma unroll 4
  for (int t = 0; t < 128; t++) l += __expf((float)base[(long)t * DM] - m);
  int idx = (z * 32 + chunk) * 128 + d;
  part[idx] = m;
  part[lOff + idx] = l;
}

// phase 2: combine 32 chunk stats -> kml[z*256+d]=M, +128=L
__global__ __launch_bounds__(128) void kstats_comb(const float* __restrict__ part,
                                                   float* __restrict__ kml, int lOff) {
  int z = blockIdx.x, d = threadIdx.x;
  float M = -1e30f;
#pragma unroll 4
  for (int c = 0; c < 32; c++) M = fmaxf(M, part[(z * 32 + c) * 128 + d]);
  float L = 0.f;
#pragma unroll 4
  for (int c = 0; c < 32; c++) {
    int i = (z * 32 + c) * 128 + d;
    L += part[lOff + i] * __expf(part[i] - M);
  }
  kml[z * 256 + d] = M;
  kml[z * 256 + 128 + d] = L;
}

// ---------------------------------------------------------------------------
// ctx via MFMA: part[z][chunk][e*128+d] = sum_{t in 512-chunk} v[t][e]*k'[t][d]
// ---------------------------------------------------------------------------
__global__ __launch_bounds__(256) void ctx_mfma(const bf16* __restrict__ k,
                                                const bf16* __restrict__ v,
                                                const float* __restrict__ kml,
                                                float* __restrict__ part) {
  int chunk = blockIdx.x, z = blockIdx.y;
  int lb = z / 3, h2 = z % 3, ch = (h2 + 1) * 128;
  int tid = threadIdx.x, lane = tid & 63, wid = tid >> 6;
  const int wm = (wid & 1) * 64, wn = (wid >> 1) * 64;
  const int lr = lane & 15, lk = (lane >> 4) * 8;
  __shared__ float ml2[128];
  __shared__ __align__(16) bf16 Vt[128 * CS];
  __shared__ __align__(16) bf16 Kt[128 * CS];
  if (tid < 128)
    ml2[tid] = kml[z * 256 + tid] + logf(kml[z * 256 + 128 + tid]);

  int j = tid >> 3, d0 = (tid & 7) * 16;
  const bf16* vsrc = v + ((long)lb * SEQ + chunk * 512 + j) * DM + ch + d0;
  const bf16* ksrc = k + ((long)lb * SEQ + chunk * 512 + j) * DM + ch + d0;

  floatx4 acc[4][4];
#pragma unroll
  for (int i = 0; i < 4; i++)
#pragma unroll
    for (int jj = 0; jj < 4; jj++) acc[i][jj] = {0.f, 0.f, 0.f, 0.f};

  for (int s = 0; s < 16; s++) {
    union { bf16 h[16]; uint4 u[2]; } va, ka;
    va.u[0] = *(const uint4*)(vsrc); va.u[1] = *(const uint4*)(vsrc + 8);
    ka.u[0] = *(const uint4*)(ksrc); ka.u[1] = *(const uint4*)(ksrc + 8);
    vsrc += (long)32 * DM; ksrc += (long)32 * DM;
    __syncthreads();
#pragma unroll
    for (int e = 0; e < 16; e++) {
      Vt[(d0 + e) * CS + j] = va.h[e];
      Kt[(d0 + e) * CS + j] = (bf16)__expf((float)ka.h[e] - ml2[d0 + e]);
    }
    __syncthreads();
    short8 af[4], bfr[4];
#pragma unroll
    for (int mt = 0; mt < 4; mt++) af[mt] = *(const short8*)(&Vt[(wm + mt * 16 + lr) * CS + lk]);
#pragma unroll
    for (int nt = 0; nt < 4; nt++) bfr[nt] = *(const short8*)(&Kt[(wn + nt * 16 + lr) * CS + lk]);
#pragma unroll
    for (int mt = 0; mt < 4; mt++)
#pragma unroll
      for (int nt = 0; nt < 4; nt++)
        acc[mt][nt] = MFMA16(af[mt], bfr[nt], acc[mt][nt]);
  }

  float* dst = part + ((long)z * 8 + chunk) * 16384;
#pragma unroll
  for (int nt = 0; nt < 4; nt++) {
    int c = wn + nt * 16 + lr;
#pragma unroll
    for (int mt = 0; mt < 4; mt++) {
      int rb = wm + mt * 16 + (lane >> 4) * 4;
#pragma unroll
      for (int reg = 0; reg < 4; reg++)
        dst[(rb + reg) * 128 + c] = acc[mt][nt][reg];
    }
  }
}

__global__ __launch_bounds__(256) void ctx_reduce(const float* __restrict__ part, bf16* __restrict__ ctxT) {
  long i = (long)blockIdx.x * 256 + threadIdx.x;
  int z = (int)(i >> 14);
  int off = (int)(i & 16383);
  float s = 0.f;
#pragma unroll
  for (int c = 0; c < 8; c++) s += part[(((long)z * 8 + c) << 14) + off];
  ctxT[i] = (bf16)s;
}

// ---------------------------------------------------------------------------
extern "C" void kernel_launch(void* const* d_in, const int* in_sizes, int n_in,
                              void* d_out, int out_size, void* d_ws, size_t ws_size,
                              hipStream_t stream) {
  float* outp = (float*)d_out;

  // ---- adaptive arena: pick largest GB in {8,4,2} that fits ws_size ----
  // layout(GB): h 67.1MB | lnG (qp overlays) GB*4.19MB | q,k,v,attn 4x |
  //             ctxp GB*1.57MB | ctxT GB*96KB | kml GB*3KB | wt 6.55MB
  long offH = 0;
  int GB = 0;
  long offLNG, offQ, offK, offV, offATT, offCTXP, offCTXT, offKML, offWT, need;
  for (int gb = 8; gb >= 2; gb >>= 1) {
    long sLN = (long)gb * 4194304;
    offLNG = 67108864L;
    offQ   = offLNG + sLN;
    offK   = offQ + sLN;
    offV   = offK + sLN;
    offATT = offV + sLN;
    offCTXP= offATT + sLN;
    offCTXT= offCTXP + (long)gb * 1572864;
    offKML = offCTXT + (long)gb * 98304;
    offWT  = offKML + (long)gb * 3072;
    need   = offWT + 6553600L;
    if ((size_t)need <= ws_size) { GB = gb; break; }
  }
  if (GB == 0) {
    beacon<<<(out_size + 255) / 256, 256, 0, stream>>>(outp, out_size);
    return;
  }
  const int NG = NBAT / GB;            // groups
  const long GR = (long)GB * SEQ;      // rows per group
  const int NZ = GB * 3;               // linear-attn (batch,head) pairs per group

  const float* x   = (const float*)d_in[0];
  const float* W1  = (const float*)d_in[1];
  const float* b1  = (const float*)d_in[2];
  const float* g1  = (const float*)d_in[3];
  const float* be1 = (const float*)d_in[4];
  const float* Wq  = (const float*)d_in[5];
  const float* Wk  = (const float*)d_in[6];
  const float* Wv  = (const float*)d_in[7];
  const float* Wo  = (const float*)d_in[8];
  const float* bo  = (const float*)d_in[9];
  const float* g2  = (const float*)d_in[10];
  const float* be2 = (const float*)d_in[11];
  const float* Wf1 = (const float*)d_in[12];
  const float* bf1 = (const float*)d_in[13];
  const float* Wf2 = (const float*)d_in[14];
  const float* bf2 = (const float*)d_in[15];
  const float* W2  = (const float*)d_in[16];
  const float* b2  = (const float*)d_in[17];

  char* ws = (char*)d_ws;
  float* h   = (float*)(ws + offH);
  bf16* lnG  = (bf16*)(ws + offLNG);
  bf16* qp   = (bf16*)(ws + offLNG);   // overlays lnG (lnG dead after QKV; qp dead in FFN)
  bf16* qb   = (bf16*)(ws + offQ);
  bf16* kb   = (bf16*)(ws + offK);
  bf16* vb   = (bf16*)(ws + offV);
  bf16* attb = (bf16*)(ws + offATT);
  bf16* ff1g = (bf16*)(ws + offQ);     // overlays q..attn (dead in FFN phase)
  float* ctxp= (float*)(ws + offCTXP);
  bf16* ctxT = (bf16*)(ws + offCTXT);
  float* kml = (float*)(ws + offKML);
  bf16* wt   = (bf16*)(ws + offWT);
  bf16* wqt  = wt + 65536;
  bf16* wot  = wt + 851968;
  bf16* wf1t = wt + 1114112;
  bf16* wf2t = wt + 2162688;
  bf16* w2t  = wt + 3211264;
  const int lOff = NZ * 32 * 128;      // kstats l-plane offset within ctxp

  // ---- all weight transposes (fp32 -> bf16, [Npad][K] K-contiguous) ----
  transpose8<<<dim3(32, 32, 8), 256, 0, stream>>>(W1, Wq, Wk, Wv, Wo, Wf1, Wf2, W2, wt);

  // ---- h = tanh(xpad @ W1 + b1) fp32; pad rows handled in A staging ----
  gemm_bt<<<dim3(4, 256, 1), 256, 0, stream>>>(x, wt, b1, h, nullptr,
      DINP, DINP, DINP, DM, 0, 1, 0, 0, 1, 0, 0);

  // ---- attention, NG groups of GB batches ----
  for (int g = 0; g < NG; g++) {
    float* hg = h + (long)g * GR * DM;
    ln_kernel<<<(int)(GR / 4), 256, 0, stream>>>(hg, g1, be1, lnG);
    // Q,K,V in one z=3 batched launch (outputs land in qb,kb,vb = contiguous)
    gemm_bt<<<dim3(4, (int)(GR / 128), 3), 256, 0, stream>>>(lnG, wqt, nullptr, nullptr, qb,
        DM, DM, DM, DM, 1, 0,
        0L, 262144L, 3, 0L, GR * DM);

    local_attn<<<dim3(2, 32, GB), 256, 0, stream>>>(qb, kb, vb, attb);

    qp_softmax<<<NZ * 1024, 256, 0, stream>>>(qb, qp);
    kstats_part<<<dim3(32, NZ), 128, 0, stream>>>(kb, ctxp, lOff);
    kstats_comb<<<NZ, 128, 0, stream>>>(ctxp, kml, lOff);
    ctx_mfma<<<dim3(8, NZ), 256, 0, stream>>>(kb, vb, kml, ctxp);
    ctx_reduce<<<NZ * 64, 256, 0, stream>>>(ctxp, ctxT);
    gemm_bt<<<dim3(1, 32, NZ), 256, 0, stream>>>(qp, ctxT, nullptr, nullptr, attb + 128,
        128, 128, 128, DM, 1, 0,
        (long)SEQ * 128, 16384L, 3, (long)SEQ * DM, 128L);

    // h += attn @ Wo + bo : 64-row tiles, no atomics
    gemm_bt64<<<dim3(4, (int)(GR / 64)), 256, 0, stream>>>(attb, wot, bo, hg,
        DM, DM, DM, DM);
  }

  // ---- FFN, NG groups ----
  for (int g = 0; g < NG; g++) {
    float* hg = h + (long)g * GR * DM;
    ln_kernel<<<(int)(GR / 4), 256, 0, stream>>>(hg, g2, be2, lnG);
    gemm_bt<<<dim3(16, (int)(GR / 128), 1), 256, 0, stream>>>(lnG, wf1t, bf1, nullptr, ff1g,
        DM, DM, DM, DFF, 4, 0, 0, 0, 1, 0, 0);
    // h += gelu(ff1) @ Wf2 + bf2 : 64-row tiles, no atomics
    gemm_bt64<<<dim3(4, (int)(GR / 64)), 256, 0, stream>>>(ff1g, wf2t, bf2, hg,
        DFF, DFF, DFF, DM);
  }

  // ---- out = (h @ W2 + b2)[:, :3000, :] -> d_out fp32 (h staged as bf16) ----
  gemm_bt<<<dim3(1, 256, 1), 256, 0, stream>>>(h, w2t, b2, outp, nullptr,
      DM, DM, DM, 64, 5, 2, 0, 0, 1, 0, 0);
}

// Round 10
// 854.560 us; speedup vs baseline: 2.7562x; 1.0395x over previous
//
#include <hip/hip_runtime.h>
#include <hip/hip_bf16.h>
#include <math.h>

// ---------------------------------------------------------------------------
// Linear_Transformer on MI355X (gfx950). fp32 I/O, bf16 MFMA internals,
// fp32 residual stream.
// Round 10: (1) gemm_bt AMODE-0 K-loop widened to BK=64 via twin 32-col
// half-buffers (keeps the proven round-5 global_load_lds deposit pattern and
// stride-32 LDS bank behavior; same two-barrier semantics; halves the number
// of vmcnt(0) barrier drains -> 32 MFMA per drain). (2) gemm_bt64 retired:
// at GB=8, FF2/attn-out have 1024 blocks at 128-tiles (4/CU) -> gemm_bt
// EPI=2 (+=, block-owned rows, no atomics).
// ---------------------------------------------------------------------------

typedef __hip_bfloat16 bf16;
typedef __attribute__((ext_vector_type(8))) short short8;   // 8 bf16 (MFMA A/B frag)
typedef __attribute__((ext_vector_type(4))) float floatx4;  // MFMA C/D frag

#define SEQ   4096
#define NBAT  8
#define DM    512
#define DINP  128
#define DFF   2048
#define NREAL 3000
#define CS    40              // ctx_mfma LDS stride (80B, 16B-aligned)

#define MFMA16(a,b,c) __builtin_amdgcn_mfma_f32_16x16x32_bf16((a),(b),(c),0,0,0)

// async global->LDS, 16B per lane, deposits at lds + lane*16
__device__ __forceinline__ void gload_lds16(const void* g, void* l) {
  auto* gp = reinterpret_cast<const __attribute__((address_space(1))) unsigned int*>(
      reinterpret_cast<uintptr_t>(g));
  auto* lp = reinterpret_cast<__attribute__((address_space(3))) unsigned int*>(
      reinterpret_cast<uintptr_t>(l));
  __builtin_amdgcn_global_load_lds(gp, lp, 16, 0, 0);
}

// ---------------------------------------------------------------------------
__global__ __launch_bounds__(256) void beacon(float* __restrict__ out, long n) {
  long i = (long)blockIdx.x * 256 + threadIdx.x;
  if (i < n) out[i] = 10000.f;
}

// ---------------------------------------------------------------------------
// All 8 weight transposes in one launch. Wt[n][k] = n<N ? (bf16)W[k][n] : 0
// ---------------------------------------------------------------------------
__global__ __launch_bounds__(256) void transpose8(
    const float* __restrict__ W1, const float* __restrict__ Wq,
    const float* __restrict__ Wk, const float* __restrict__ Wv,
    const float* __restrict__ Wo, const float* __restrict__ Wf1,
    const float* __restrict__ Wf2, const float* __restrict__ W2,
    bf16* __restrict__ wt) {
  const int Ks[8]   = {128, 512, 512, 512, 512, 512, 2048, 512};
  const int Ns[8]   = {512, 512, 512, 512, 512, 2048, 512, 64};
  const int Nps[8]  = {512, 512, 512, 512, 512, 2048, 512, 128};
  const long Ofs[8] = {0L, 65536L, 327680L, 589824L, 851968L, 1114112L, 2162688L, 3211264L};
  int zi = blockIdx.z;
  int K = Ks[zi], N = Ns[zi], Npad = Nps[zi];
  int k0 = blockIdx.x * 64, n0 = blockIdx.y * 64;
  if (k0 >= K || n0 >= Npad) return;
  const float* W = zi == 0 ? W1 : zi == 1 ? Wq : zi == 2 ? Wk : zi == 3 ? Wv
                 : zi == 4 ? Wo : zi == 5 ? Wf1 : zi == 6 ? Wf2 : W2;
  bf16* Wt = wt + Ofs[zi];
  __shared__ float t[64][65];
  int r = threadIdx.x >> 2, c = (threadIdx.x & 3) * 16;
#pragma unroll
  for (int i = 0; i < 16; i++) {
    int n = n0 + c + i;
    t[r][c + i] = (n < N) ? W[(long)(k0 + r) * N + n] : 0.f;
  }
  __syncthreads();
#pragma unroll
  for (int i = 0; i < 16; i++)
    Wt[(long)(n0 + r) * K + k0 + c + i] = (bf16)t[c + i][r];
}

// ---------------------------------------------------------------------------
__device__ inline uint4 pack8(const float* p) {
  union { bf16 h[8]; uint4 u; } r;
  float4 a = *(const float4*)p;
  float4 b = *(const float4*)(p + 4);
  r.h[0] = (bf16)a.x; r.h[1] = (bf16)a.y; r.h[2] = (bf16)a.z; r.h[3] = (bf16)a.w;
  r.h[4] = (bf16)b.x; r.h[5] = (bf16)b.y; r.h[6] = (bf16)b.z; r.h[7] = (bf16)b.w;
  return r.u;
}

// ---------------------------------------------------------------------------
// Generic MFMA GEMM: C[M x N] = epi(A[M x K] @ Bt[N x K]^T + bias)
// 128x128 tile, 256 threads (4 waves, 2x2), z-batched.
// AMODE 0: bf16 A, async global_load_lds, BK=64 twin half-buffers.
// AMODE 1: fp32 x (8,3000,128) zero-padded rows; register staging BK=32.
// AMODE 2: fp32 A converted in register staging BK=32.
// EPI: 0 tanh->Cf  1 bf16->Cb  2 Cf+=  4 gelu->Cb  5 row-remap -> Cf (d_out)
// ---------------------------------------------------------------------------
__global__ __launch_bounds__(256) void gemm_bt(
    const void* __restrict__ Avoid, const bf16* __restrict__ Bt,
    const float* __restrict__ bias, float* __restrict__ Cf, bf16* __restrict__ Cb,
    int K, int lda, int ldb, int ldc, int EPI, int AMODE,
    long aBatch, long bBatch, int zdiv, long cOuter, long cInner) {
  __shared__ __align__(16) bf16 As0[128 * 32];
  __shared__ __align__(16) bf16 As1[128 * 32];
  __shared__ __align__(16) bf16 Bs0[128 * 32];
  __shared__ __align__(16) bf16 Bs1[128 * 32];
  const int tid = threadIdx.x;
  const int bz = blockIdx.z;
  Bt += (long)bz * bBatch;
  const long cOff = (long)(bz / zdiv) * cOuter + (long)(bz % zdiv) * cInner;
  const int row0 = blockIdx.y * 128;
  const int col0 = blockIdx.x * 128;
  const int lane = tid & 63, wid = tid >> 6;
  const int wm = (wid & 1) * 64, wn = (wid >> 1) * 64;
  const int lr = lane & 15, lk = (lane >> 4) * 8;

  floatx4 acc[4][4];
#pragma unroll
  for (int i = 0; i < 4; i++)
#pragma unroll
    for (int j = 0; j < 4; j++) acc[i][j] = {0.f, 0.f, 0.f, 0.f};

  if (AMODE == 0) {
    // ---- async staging, BK=64: two 32-col half-tiles per iteration ----
    const bf16* A = (const bf16*)Avoid + (long)bz * aBatch;
    const bf16* pAa = A + (long)(row0 + wid * 16 + (lane >> 2)) * lda + (lane & 3) * 8;
    const bf16* pBa = Bt + (long)(col0 + wid * 16 + (lane >> 2)) * ldb + (lane & 3) * 8;
    bf16* ldsA0 = &As0[wid * 16 * 32];
    bf16* ldsA1 = &As1[wid * 16 * 32];
    bf16* ldsB0 = &Bs0[wid * 16 * 32];
    bf16* ldsB1 = &Bs1[wid * 16 * 32];
    const long a64 = (long)64 * lda, b64 = (long)64 * ldb;
    for (int k0 = 0; k0 < K; k0 += 64) {
      __syncthreads();
      gload_lds16(pAa, ldsA0);
      gload_lds16(pAa + a64, ldsA0 + 64 * 32);
      gload_lds16(pAa + 32, ldsA1);
      gload_lds16(pAa + a64 + 32, ldsA1 + 64 * 32);
      gload_lds16(pBa, ldsB0);
      gload_lds16(pBa + b64, ldsB0 + 64 * 32);
      gload_lds16(pBa + 32, ldsB1);
      gload_lds16(pBa + b64 + 32, ldsB1 + 64 * 32);
      pAa += 64; pBa += 64;
      __syncthreads();
      short8 af[4], bfr[4];
#pragma unroll
      for (int mt = 0; mt < 4; mt++) af[mt] = *(const short8*)(&As0[(wm + mt * 16 + lr) * 32 + lk]);
#pragma unroll
      for (int nt = 0; nt < 4; nt++) bfr[nt] = *(const short8*)(&Bs0[(wn + nt * 16 + lr) * 32 + lk]);
#pragma unroll
      for (int mt = 0; mt < 4; mt++)
#pragma unroll
        for (int nt = 0; nt < 4; nt++)
          acc[mt][nt] = MFMA16(af[mt], bfr[nt], acc[mt][nt]);
#pragma unroll
      for (int mt = 0; mt < 4; mt++) af[mt] = *(const short8*)(&As1[(wm + mt * 16 + lr) * 32 + lk]);
#pragma unroll
      for (int nt = 0; nt < 4; nt++) bfr[nt] = *(const short8*)(&Bs1[(wn + nt * 16 + lr) * 32 + lk]);
#pragma unroll
      for (int mt = 0; mt < 4; mt++)
#pragma unroll
        for (int nt = 0; nt < 4; nt++)
          acc[mt][nt] = MFMA16(af[mt], bfr[nt], acc[mt][nt]);
    }
  } else {
    // ---- register staging path (fp32 A sources), BK=32 ----
    const float* Af = (const float*)Avoid;
    const int srow = tid >> 2;
    const int skcol = (tid & 3) * 8;
    const long r0 = row0 + srow, r1 = r0 + 64;
    const bf16* pB = Bt + (long)(col0 + srow) * ldb + skcol;
    const int ldsOff = srow * 32 + skcol;
    const float* pF0; const float* pF1;
    bool v0 = true, v1 = true;
    if (AMODE == 1) {
      int t0 = (int)(r0 & (SEQ - 1)), t1 = (int)(r1 & (SEQ - 1));
      v0 = t0 < NREAL; v1 = t1 < NREAL;
      if (!v0) t0 = 0;
      if (!v1) t1 = 0;
      pF0 = Af + ((r0 >> 12) * NREAL + t0) * DINP + skcol;
      pF1 = Af + ((r1 >> 12) * NREAL + t1) * DINP + skcol;
    } else {
      pF0 = Af + r0 * lda + skcol;
      pF1 = Af + r1 * lda + skcol;
    }
    for (int k0 = 0; k0 < K; k0 += 32) {
      uint4 b0 = *(const uint4*)(pB);
      uint4 b1 = *(const uint4*)(pB + (long)64 * ldb);
      pB += 32;
      uint4 a0 = {0, 0, 0, 0}, a1 = {0, 0, 0, 0};
      if (v0) a0 = pack8(pF0);
      if (v1) a1 = pack8(pF1);
      pF0 += 32; pF1 += 32;
      __syncthreads();
      *(uint4*)(&As0[ldsOff]) = a0;
      *(uint4*)(&As0[ldsOff + 64 * 32]) = a1;
      *(uint4*)(&Bs0[ldsOff]) = b0;
      *(uint4*)(&Bs0[ldsOff + 64 * 32]) = b1;
      __syncthreads();
      short8 af[4], bfr[4];
#pragma unroll
      for (int mt = 0; mt < 4; mt++) af[mt] = *(const short8*)(&As0[(wm + mt * 16 + lr) * 32 + lk]);
#pragma unroll
      for (int nt = 0; nt < 4; nt++) bfr[nt] = *(const short8*)(&Bs0[(wn + nt * 16 + lr) * 32 + lk]);
#pragma unroll
      for (int mt = 0; mt < 4; mt++)
#pragma unroll
        for (int nt = 0; nt < 4; nt++)
          acc[mt][nt] = MFMA16(af[mt], bfr[nt], acc[mt][nt]);
    }
  }

  // D element (mt,nt,reg): row=(lane>>4)*4+reg, col=lane&15 within 16x16 tile
#pragma unroll
  for (int nt = 0; nt < 4; nt++) {
    int c = col0 + wn + nt * 16 + lr;
    float bv = 0.f;
    if (bias) {
      if (EPI == 5) { if (c < 64) bv = bias[c]; }
      else bv = bias[c];
    }
#pragma unroll
    for (int mt = 0; mt < 4; mt++) {
      long rb = row0 + wm + mt * 16 + (lane >> 4) * 4;
#pragma unroll
      for (int reg = 0; reg < 4; reg++) {
        float v = acc[mt][nt][reg] + bv;
        long ri = rb + reg;
        long idx = cOff + ri * (long)ldc + c;
        if (EPI == 0) Cf[idx] = tanhf(v);
        else if (EPI == 1) Cb[idx] = (bf16)v;
        else if (EPI == 2) Cf[idx] += v;
        else if (EPI == 4) { float g = 0.5f * v * (1.f + erff(v * 0.70710678118654752f)); Cb[idx] = (bf16)g; }
        else if (EPI == 5) {
          int bb = (int)(ri >> 12); int tt = (int)(ri & (SEQ - 1));
          if (tt < NREAL && c < 64) Cf[((long)bb * NREAL + tt) * 64 + c] = v;
        }
      }
    }
  }
}

// ---------------------------------------------------------------------------
// LayerNorm over 512 fp32 -> bf16. One wave per row, 4 rows per block.
// ---------------------------------------------------------------------------
__global__ __launch_bounds__(256) void ln_kernel(const float* __restrict__ h,
                                                 const float* __restrict__ g,
                                                 const float* __restrict__ bta,
                                                 bf16* __restrict__ out) {
  int wid = threadIdx.x >> 6, lane = threadIdx.x & 63;
  long row = (long)blockIdx.x * 4 + wid;
  const float* src = h + row * DM + lane * 8;
  float4 a = *(const float4*)(src);
  float4 b = *(const float4*)(src + 4);
  float x[8] = {a.x, a.y, a.z, a.w, b.x, b.y, b.z, b.w};
  float s = 0.f, sq = 0.f;
#pragma unroll
  for (int i = 0; i < 8; i++) { s += x[i]; sq += x[i] * x[i]; }
#pragma unroll
  for (int m = 32; m >= 1; m >>= 1) { s += __shfl_xor(s, m, 64); sq += __shfl_xor(sq, m, 64); }
  float mu = s * (1.f / DM);
  float var = sq * (1.f / DM) - mu * mu;
  float rstd = rsqrtf(var + 1e-5f);
  const float* gp = g + lane * 8;
  const float* bp = bta + lane * 8;
  bf16* dst = out + row * DM + lane * 8;
#pragma unroll
  for (int i = 0; i < 8; i++)
    dst[i] = (bf16)((x[i] - mu) * rstd * gp[i] + bp[i]);
}

// ---------------------------------------------------------------------------
// Local attention, head 0. Grid (2 halves, 32 windows, GB batches).
// ---------------------------------------------------------------------------
__global__ __launch_bounds__(256) void local_attn(const bf16* __restrict__ q,
                                                  const bf16* __restrict__ k,
                                                  const bf16* __restrict__ v,
                                                  bf16* __restrict__ att) {
  int half = blockIdx.x, w = blockIdx.y, b = blockIdx.z;
  int tid = threadIdx.x, wid = tid >> 6, lane = tid & 63;
  int lr = lane & 15, lq4 = lane >> 4;
  __shared__ __align__(16) bf16 Ks[32 * 128];   // [j][d]
  __shared__ __align__(16) bf16 Vts[128 * 32];  // [d][j]
  __shared__ __align__(16) bf16 Ps[4][16 * 32]; // per-wave P scratch

  int t0 = w * 128 + half * 64 + wid * 16;
  long qbase = ((long)b * SEQ + t0 + lr) * DM;
  short8 qf[4];
#pragma unroll
  for (int ks = 0; ks < 4; ks++) qf[ks] = *(const short8*)(q + qbase + ks * 32 + lq4 * 8);

  floatx4 Oacc[8];
#pragma unroll
  for (int i = 0; i < 8; i++) Oacc[i] = {0.f, 0.f, 0.f, 0.f};
  float rs[4] = {0.f, 0.f, 0.f, 0.f};

  int keystart = w * 128 - 128;
  for (int ch = 0; ch < 12; ch++) {
    int kb = keystart + ch * 32;
    if (kb < 0 || kb >= SEQ) continue;  // uniform per block
    {
      int j = tid >> 3, d = (tid & 7) * 16;
      const bf16* ksrc = k + ((long)b * SEQ + kb + j) * DM + d;
      *(uint4*)(&Ks[j * 128 + d]) = *(const uint4*)(ksrc);
      *(uint4*)(&Ks[j * 128 + d + 8]) = *(const uint4*)(ksrc + 8);
      const bf16* vsrc = v + ((long)b * SEQ + kb + j) * DM + d;
#pragma unroll
      for (int e = 0; e < 16; e++) Vts[(d + e) * 32 + j] = vsrc[e];
    }
    __syncthreads();
    floatx4 s0 = {0.f, 0.f, 0.f, 0.f}, s1 = {0.f, 0.f, 0.f, 0.f};
#pragma unroll
    for (int ks = 0; ks < 4; ks++) {
      short8 kf0 = *(const short8*)(&Ks[(0 + lr) * 128 + ks * 32 + lq4 * 8]);
      short8 kf1 = *(const short8*)(&Ks[(16 + lr) * 128 + ks * 32 + lq4 * 8]);
      s0 = MFMA16(qf[ks], kf0, s0);
      s1 = MFMA16(qf[ks], kf1, s1);
    }
#pragma unroll
    for (int reg = 0; reg < 4; reg++) {
      float e0 = __expf(s0[reg] * 0.08838834764831845f);
      float e1 = __expf(s1[reg] * 0.08838834764831845f);
      rs[reg] += e0 + e1;
      Ps[wid][(lq4 * 4 + reg) * 32 + lr] = (bf16)e0;
      Ps[wid][(lq4 * 4 + reg) * 32 + 16 + lr] = (bf16)e1;
    }
    __syncthreads();
    short8 pf = *(const short8*)(&Ps[wid][lr * 32 + lq4 * 8]);
#pragma unroll
    for (int nt = 0; nt < 8; nt++) {
      short8 vf = *(const short8*)(&Vts[(nt * 16 + lr) * 32 + lq4 * 8]);
      Oacc[nt] = MFMA16(pf, vf, Oacc[nt]);
    }
    __syncthreads();
  }
#pragma unroll
  for (int m = 1; m < 16; m <<= 1)
#pragma unroll
    for (int reg = 0; reg < 4; reg++) rs[reg] += __shfl_xor(rs[reg], m, 64);
  long obase = ((long)b * SEQ + t0 + lq4 * 4) * DM;
#pragma unroll
  for (int nt = 0; nt < 8; nt++)
#pragma unroll
    for (int reg = 0; reg < 4; reg++)
      att[obase + (long)reg * DM + nt * 16 + lr] = (bf16)(Oacc[nt][reg] / rs[reg]);
}

// ---------------------------------------------------------------------------
// Linear-attn q-softmax: qp[z][t][128] = softmax(q_head)*d^-0.5, z=lb*3+h2
// ---------------------------------------------------------------------------
__global__ __launch_bounds__(256) void qp_softmax(const bf16* __restrict__ q, bf16* __restrict__ qp) {
  int wid = threadIdx.x >> 6, lane = threadIdx.x & 63;
  long task = (long)blockIdx.x * 4 + wid;
  int tt = (int)(task & (SEQ - 1));
  int z6 = (int)(task >> 12);
  int lb = z6 / 3, h2 = z6 % 3;
  const bf16* src = q + ((long)lb * SEQ + tt) * DM + (h2 + 1) * 128 + lane * 2;
  float x0 = (float)src[0], x1 = (float)src[1];
  float m = fmaxf(x0, x1);
#pragma unroll
  for (int s = 32; s >= 1; s >>= 1) m = fmaxf(m, __shfl_xor(m, s, 64));
  float e0 = __expf(x0 - m), e1 = __expf(x1 - m);
  float sm = e0 + e1;
#pragma unroll
  for (int s = 32; s >= 1; s >>= 1) sm += __shfl_xor(sm, s, 64);
  float inv = 0.08838834764831845f / sm;
  bf16* dst = qp + task * 128 + lane * 2;
  dst[0] = (bf16)(e0 * inv);
  dst[1] = (bf16)(e1 * inv);
}

// ---------------------------------------------------------------------------
// k column stats, phase 1: per-(z, 128-row chunk) column max and exp-sum.
// ---------------------------------------------------------------------------
__global__ __launch_bounds__(128) void kstats_part(const bf16* __restrict__ k,
                                                   float* __restrict__ part, int lOff) {
  int chunk = blockIdx.x, z = blockIdx.y;
  int lb = z / 3, h2 = z % 3, ch = (h2 + 1) * 128;
  int d = threadIdx.x;
  const bf16* base = k + ((long)lb * SEQ + chunk * 128) * DM + ch + d;
  float m = -1e30f;
#pragma unroll 4
  for (int t = 0; t < 128; t++) m = fmaxf(m, (float)base[(long)t * DM]);
  float l = 0.f;
#pragma unroll 4
  for (int t = 0; t < 128; t++) l += __expf((float)base[(long)t * DM] - m);
  int idx = (z * 32 + chunk) * 128 + d;
  part[idx] = m;
  part[lOff + idx] = l;
}

// phase 2: combine 32 chunk stats -> kml[z*256+d]=M, +128=L
__global__ __launch_bounds__(128) void kstats_comb(const float* __restrict__ part,
                                                   float* __restrict__ kml, int lOff) {
  int z = blockIdx.x, d = threadIdx.x;
  float M = -1e30f;
#pragma unroll 4
  for (int c = 0; c < 32; c++) M = fmaxf(M, part[(z * 32 + c) * 128 + d]);
  float L = 0.f;
#pragma unroll 4
  for (int c = 0; c < 32; c++) {
    int i = (z * 32 + c) * 128 + d;
    L += part[lOff + i] * __expf(part[i] - M);
  }
  kml[z * 256 + d] = M;
  kml[z * 256 + 128 + d] = L;
}

// ---------------------------------------------------------------------------
// ctx via MFMA: part[z][chunk][e*128+d] = sum_{t in 512-chunk} v[t][e]*k'[t][d]
// ---------------------------------------------------------------------------
__global__ __launch_bounds__(256) void ctx_mfma(const bf16* __restrict__ k,
                                                const bf16* __restrict__ v,
                                                const float* __restrict__ kml,
                                                float* __restrict__ part) {
  int chunk = blockIdx.x, z = blockIdx.y;
  int lb = z / 3, h2 = z % 3, ch = (h2 + 1) * 128;
  int tid = threadIdx.x, lane = tid & 63, wid = tid >> 6;
  const int wm = (wid & 1) * 64, wn = (wid >> 1) * 64;
  const int lr = lane & 15, lk = (lane >> 4) * 8;
  __shared__ float ml2[128];
  __shared__ __align__(16) bf16 Vt[128 * CS];
  __shared__ __align__(16) bf16 Kt[128 * CS];
  if (tid < 128)
    ml2[tid] = kml[z * 256 + tid] + logf(kml[z * 256 + 128 + tid]);

  int j = tid >> 3, d0 = (tid & 7) * 16;
  const bf16* vsrc = v + ((long)lb * SEQ + chunk * 512 + j) * DM + ch + d0;
  const bf16* ksrc = k + ((long)lb * SEQ + chunk * 512 + j) * DM + ch + d0;

  floatx4 acc[4][4];
#pragma unroll
  for (int i = 0; i < 4; i++)
#pragma unroll
    for (int jj = 0; jj < 4; jj++) acc[i][jj] = {0.f, 0.f, 0.f, 0.f};

  for (int s = 0; s < 16; s++) {
    union { bf16 h[16]; uint4 u[2]; } va, ka;
    va.u[0] = *(const uint4*)(vsrc); va.u[1] = *(const uint4*)(vsrc + 8);
    ka.u[0] = *(const uint4*)(ksrc); ka.u[1] = *(const uint4*)(ksrc + 8);
    vsrc += (long)32 * DM; ksrc += (long)32 * DM;
    __syncthreads();
#pragma unroll
    for (int e = 0; e < 16; e++) {
      Vt[(d0 + e) * CS + j] = va.h[e];
      Kt[(d0 + e) * CS + j] = (bf16)__expf((float)ka.h[e] - ml2[d0 + e]);
    }
    __syncthreads();
    short8 af[4], bfr[4];
#pragma unroll
    for (int mt = 0; mt < 4; mt++) af[mt] = *(const short8*)(&Vt[(wm + mt * 16 + lr) * CS + lk]);
#pragma unroll
    for (int nt = 0; nt < 4; nt++) bfr[nt] = *(const short8*)(&Kt[(wn + nt * 16 + lr) * CS + lk]);
#pragma unroll
    for (int mt = 0; mt < 4; mt++)
#pragma unroll
      for (int nt = 0; nt < 4; nt++)
        acc[mt][nt] = MFMA16(af[mt], bfr[nt], acc[mt][nt]);
  }

  float* dst = part + ((long)z * 8 + chunk) * 16384;
#pragma unroll
  for (int nt = 0; nt < 4; nt++) {
    int c = wn + nt * 16 + lr;
#pragma unroll
    for (int mt = 0; mt < 4; mt++) {
      int rb = wm + mt * 16 + (lane >> 4) * 4;
#pragma unroll
      for (int reg = 0; reg < 4; reg++)
        dst[(rb + reg) * 128 + c] = acc[mt][nt][reg];
    }
  }
}

__global__ __launch_bounds__(256) void ctx_reduce(const float* __restrict__ part, bf16* __restrict__ ctxT) {
  long i = (long)blockIdx.x * 256 + threadIdx.x;
  int z = (int)(i >> 14);
  int off = (int)(i & 16383);
  float s = 0.f;
#pragma unroll
  for (int c = 0; c < 8; c++) s += part[(((long)z * 8 + c) << 14) + off];
  ctxT[i] = (bf16)s;
}

// ---------------------------------------------------------------------------
extern "C" void kernel_launch(void* const* d_in, const int* in_sizes, int n_in,
                              void* d_out, int out_size, void* d_ws, size_t ws_size,
                              hipStream_t stream) {
  float* outp = (float*)d_out;

  // ---- adaptive arena: pick largest GB in {8,4,2} that fits ws_size ----
  long offH = 0;
  int GB = 0;
  long offLNG, offQ, offK, offV, offATT, offCTXP, offCTXT, offKML, offWT, need;
  for (int gb = 8; gb >= 2; gb >>= 1) {
    long sLN = (long)gb * 4194304;
    offLNG = 67108864L;
    offQ   = offLNG + sLN;
    offK   = offQ + sLN;
    offV   = offK + sLN;
    offATT = offV + sLN;
    offCTXP= offATT + sLN;
    offCTXT= offCTXP + (long)gb * 1572864;
    offKML = offCTXT + (long)gb * 98304;
    offWT  = offKML + (long)gb * 3072;
    need   = offWT + 6553600L;
    if ((size_t)need <= ws_size) { GB = gb; break; }
  }
  if (GB == 0) {
    beacon<<<(out_size + 255) / 256, 256, 0, stream>>>(outp, out_size);
    return;
  }
  const int NG = NBAT / GB;            // groups
  const long GR = (long)GB * SEQ;      // rows per group
  const int NZ = GB * 3;               // linear-attn (batch,head) pairs per group

  const float* x   = (const float*)d_in[0];
  const float* W1  = (const float*)d_in[1];
  const float* b1  = (const float*)d_in[2];
  const float* g1  = (const float*)d_in[3];
  const float* be1 = (const float*)d_in[4];
  const float* Wq  = (const float*)d_in[5];
  const float* Wk  = (const float*)d_in[6];
  const float* Wv  = (const float*)d_in[7];
  const float* Wo  = (const float*)d_in[8];
  const float* bo  = (const float*)d_in[9];
  const float* g2  = (const float*)d_in[10];
  const float* be2 = (const float*)d_in[11];
  const float* Wf1 = (const float*)d_in[12];
  const float* bf1 = (const float*)d_in[13];
  const float* Wf2 = (const float*)d_in[14];
  const float* bf2 = (const float*)d_in[15];
  const float* W2  = (const float*)d_in[16];
  const float* b2  = (const float*)d_in[17];

  char* ws = (char*)d_ws;
  float* h   = (float*)(ws + offH);
  bf16* lnG  = (bf16*)(ws + offLNG);
  bf16* qp   = (bf16*)(ws + offLNG);   // overlays lnG (lnG dead after QKV; qp dead in FFN)
  bf16* qb   = (bf16*)(ws + offQ);
  bf16* kb   = (bf16*)(ws + offK);
  bf16* vb   = (bf16*)(ws + offV);
  bf16* attb = (bf16*)(ws + offATT);
  bf16* ff1g = (bf16*)(ws + offQ);     // overlays q..attn (dead in FFN phase)
  float* ctxp= (float*)(ws + offCTXP);
  bf16* ctxT = (bf16*)(ws + offCTXT);
  float* kml = (float*)(ws + offKML);
  bf16* wt   = (bf16*)(ws + offWT);
  bf16* wqt  = wt + 65536;
  bf16* wot  = wt + 851968;
  bf16* wf1t = wt + 1114112;
  bf16* wf2t = wt + 2162688;
  bf16* w2t  = wt + 3211264;
  const int lOff = NZ * 32 * 128;      // kstats l-plane offset within ctxp

  // ---- all weight transposes (fp32 -> bf16, [Npad][K] K-contiguous) ----
  transpose8<<<dim3(32, 32, 8), 256, 0, stream>>>(W1, Wq, Wk, Wv, Wo, Wf1, Wf2, W2, wt);

  // ---- h = tanh(xpad @ W1 + b1) fp32; pad rows handled in A staging ----
  gemm_bt<<<dim3(4, 256, 1), 256, 0, stream>>>(x, wt, b1, h, nullptr,
      DINP, DINP, DINP, DM, 0, 1, 0, 0, 1, 0, 0);

  // ---- attention, NG groups of GB batches ----
  for (int g = 0; g < NG; g++) {
    float* hg = h + (long)g * GR * DM;
    ln_kernel<<<(int)(GR / 4), 256, 0, stream>>>(hg, g1, be1, lnG);
    // Q,K,V in one z=3 batched launch (outputs land in qb,kb,vb = contiguous)
    gemm_bt<<<dim3(4, (int)(GR / 128), 3), 256, 0, stream>>>(lnG, wqt, nullptr, nullptr, qb,
        DM, DM, DM, DM, 1, 0,
        0L, 262144L, 3, 0L, GR * DM);

    local_attn<<<dim3(2, 32, GB), 256, 0, stream>>>(qb, kb, vb, attb);

    qp_softmax<<<NZ * 1024, 256, 0, stream>>>(qb, qp);
    kstats_part<<<dim3(32, NZ), 128, 0, stream>>>(kb, ctxp, lOff);
    kstats_comb<<<NZ, 128, 0, stream>>>(ctxp, kml, lOff);
    ctx_mfma<<<dim3(8, NZ), 256, 0, stream>>>(kb, vb, kml, ctxp);
    ctx_reduce<<<NZ * 64, 256, 0, stream>>>(ctxp, ctxT);
    gemm_bt<<<dim3(1, 32, NZ), 256, 0, stream>>>(qp, ctxT, nullptr, nullptr, attb + 128,
        128, 128, 128, DM, 1, 0,
        (long)SEQ * 128, 16384L, 3, (long)SEQ * DM, 128L);

    // h += attn @ Wo + bo : 128-tile, GR/128 * 4 blocks, block-owned +=
    gemm_bt<<<dim3(4, (int)(GR / 128), 1), 256, 0, stream>>>(attb, wot, bo, hg, nullptr,
        DM, DM, DM, DM, 2, 0, 0, 0, 1, 0, 0);
  }

  // ---- FFN, NG groups ----
  for (int g = 0; g < NG; g++) {
    float* hg = h + (long)g * GR * DM;
    ln_kernel<<<(int)(GR / 4), 256, 0, stream>>>(hg, g2, be2, lnG);
    gemm_bt<<<dim3(16, (int)(GR / 128), 1), 256, 0, stream>>>(lnG, wf1t, bf1, nullptr, ff1g,
        DM, DM, DM, DFF, 4, 0, 0, 0, 1, 0, 0);
    // h += gelu(ff1) @ Wf2 + bf2 : 128-tile, block-owned +=
    gemm_bt<<<dim3(4, (int)(GR / 128), 1), 256, 0, stream>>>(ff1g, wf2t, bf2, hg, nullptr,
        DFF, DFF, DFF, DM, 2, 0, 0, 0, 1, 0, 0);
  }

  // ---- out = (h @ W2 + b2)[:, :3000, :] -> d_out fp32 (h staged as bf16) ----
  gemm_bt<<<dim3(1, 256, 1), 256, 0, stream>>>(h, w2t, b2, outp, nullptr,
      DM, DM, DM, 64, 5, 2, 0, 0, 1, 0, 0);
}